// Round 4
// baseline (594.256 us; speedup 1.0000x reference)
//
#include <hip/hip_runtime.h>
#include <hip/hip_fp8.h>

#define NN 131072      // nodes per side
#define NE 524288      // edges per side
#define NB 4096        // graphs per side
#define CAP 16         // slot capacity = one 64B line/node
#define NEG_SLOPE 0.2f
#define LN_EPS 1e-5f
#define LOG2E 1.44269504088896f

// edge-partition geometry (atomic-free slot build)
#define NBKT 1024      // buckets of 256 nodes (2NN/256)
#define NBLK1 256      // phase-1 blocks
#define CELL_CAP 24    // per-(bucket,block) cell capacity (avg 4, Poisson tail ~1e-13)

typedef unsigned short bf16;
typedef __attribute__((ext_vector_type(8))) short short8;
typedef __attribute__((ext_vector_type(4))) float floatx4;
typedef __attribute__((ext_vector_type(2))) float floatx2;

#if __has_builtin(__builtin_amdgcn_exp2f)
#define EXP2(x) __builtin_amdgcn_exp2f(x)
#else
#define EXP2(x) exp2f(x)
#endif

__device__ __forceinline__ float bf2f(bf16 h) {
    return __uint_as_float((unsigned)h << 16);
}
__device__ __forceinline__ bf16 f2bf(float f) {
    unsigned u = __float_as_uint(f);
    unsigned r = (u + 0x7FFFu + ((u >> 16) & 1u)) >> 16;
    return (bf16)r;
}
// HW packed bf16 pair encode (RNE, same unit the compiler uses for bf16 casts)
__device__ __forceinline__ unsigned pkbf(float lo, float hi) {
    unsigned r;
    asm("v_cvt_pk_bf16_f32 %0, %1, %2" : "=v"(r) : "v"(lo), "v"(hi));
    return r;
}
// HW packed fp8(e4m3) encode
__device__ __forceinline__ unsigned char ftofp8(float f) {
    return (unsigned char)(__builtin_amdgcn_cvt_pk_fp8_f32(f, f, 0, false) & 0xFF);
}
__device__ __forceinline__ float leaky(float x) {
    return fmaxf(x, 0.f) + NEG_SLOPE * fminf(x, 0.f);
}

// ---------------- atomic-free slot build (two-phase partition) ----------------
// Phase 1: bin edges into block-private cells via LDS histogram (no global atomics;
//          cell lines are block-private -> no cross-XCD ping-pong).
__global__ __launch_bounds__(256) void part_edges_kernel(
        const int* __restrict__ s0, const int* __restrict__ d0,
        const int* __restrict__ s1, const int* __restrict__ d1,
        unsigned* __restrict__ cells, int* __restrict__ counts) {
    __shared__ int lcnt[NBKT];       // 4 KB
    int blk = blockIdx.x, t = threadIdx.x;
    for (int i = t; i < NBKT; i += 256) lcnt[i] = 0;
    __syncthreads();
    int side = blk >= (NBLK1 / 2);               // 128 blocks per side
    const int4* dp = (const int4*)(side ? d1 : d0);
    const int4* sp = (const int4*)(side ? s1 : s0);
    int base4 = (blk - side * (NBLK1 / 2)) * 1024;
    int gbase = side * NN;
#pragma unroll
    for (int it = 0; it < 4; it++) {
        int e4 = base4 + it * 256 + t;           // [0, NE/4)
        int4 dd = dp[e4];
        int4 ss = sp[e4];
        int d[4] = {gbase + dd.x, gbase + dd.y, gbase + dd.z, gbase + dd.w};
        int s[4] = {gbase + ss.x, gbase + ss.y, gbase + ss.z, gbase + ss.w};
#pragma unroll
        for (int k = 0; k < 4; k++) {
            int b = d[k] >> 8;
            int r = atomicAdd(&lcnt[b], 1);      // LDS atomic
            if (r < CELL_CAP)
                cells[((size_t)b * NBLK1 + blk) * CELL_CAP + r] =
                    ((unsigned)s[k] << 8) | (unsigned)(d[k] & 255);
        }
    }
    __syncthreads();
    for (int i = t; i < NBKT; i += 256) {
        int c = lcnt[i];
        counts[i * NBLK1 + blk] = (c > CELL_CAP) ? CELL_CAP : c;
    }
}

// Phase 2: one block per bucket; build deg/slots for 256 nodes in LDS, write coalesced.
__global__ __launch_bounds__(256) void build_slots_kernel(
        const unsigned* __restrict__ cells, const int* __restrict__ counts,
        int* __restrict__ deg, int* __restrict__ slots) {
    __shared__ int ldeg[256];                    // 1 KB
    __shared__ int lslot[256 * CAP];             // 16 KB
    int b = blockIdx.x, t = threadIdx.x;
    ldeg[t] = 0;
    for (int i = t; i < 256 * CAP; i += 256) lslot[i] = 0;
    __syncthreads();
    // thread t consumes cell t of this bucket
    int cnt = counts[b * NBLK1 + t];
    const unsigned* cp = cells + ((size_t)b * NBLK1 + t) * CELL_CAP;
    for (int i = 0; i < cnt; i++) {
        unsigned v = cp[i];
        int d = v & 255;
        int s = (int)(v >> 8);
        int p = atomicAdd(&ldeg[d], 1);          // LDS atomic
        if (p < CAP) lslot[d * CAP + p] = s;
    }
    __syncthreads();
    int node0 = b * 256;
    deg[node0 + t] = ldeg[t];
    for (int i = t; i < 256 * CAP; i += 256)
        slots[(size_t)node0 * CAP + i] = lslot[i];
}

// ---------------- merged weight prep ----------------
// W2t + W3t + Wplt + Wc1t + Ff2 + Ff3 + F1 + W1f
#define PREP_TOTAL (16384 + 32768 + 524288 + 131072 + 2048 + 2048 + 48 + 4096)

__global__ void prep_all_kernel(const float* __restrict__ W2, const float* __restrict__ W3,
                                const float* __restrict__ Wpl, const float* __restrict__ Wc1,
                                const float* __restrict__ W1,
                                const float* __restrict__ al1, const float* __restrict__ ar1,
                                const float* __restrict__ al2, const float* __restrict__ ar2,
                                const float* __restrict__ al3, const float* __restrict__ ar3,
                                const float* __restrict__ b1v,
                                bf16* __restrict__ W2t, bf16* __restrict__ W3t,
                                bf16* __restrict__ Wplt, bf16* __restrict__ Wc1t,
                                bf16* __restrict__ Ff2, bf16* __restrict__ Ff3,
                                float* __restrict__ F1, bf16* __restrict__ W1f) {
    int i = blockIdx.x * blockDim.x + threadIdx.x;
    if (i < 16384) {  // W2t: K=128,C=128
        int c = i >> 7, k = i & 127;
        W2t[i] = f2bf(W2[k * 128 + c]);
        return;
    }
    i -= 16384;
    if (i < 32768) {  // W3t: K=128,C=256
        int c = i >> 7, k = i & 127;
        W3t[i] = f2bf(W3[k * 256 + c]);
        return;
    }
    i -= 32768;
    if (i < 524288) {  // Wplt: K=1024,C=512
        int c = i >> 10, k = i & 1023;
        Wplt[i] = f2bf(Wpl[k * 512 + c]);
        return;
    }
    i -= 524288;
    if (i < 131072) {  // Wc1t: K=512,C=256
        int c = i >> 9, k = i & 511;
        Wc1t[i] = f2bf(Wc1[k * 256 + c]);
        return;
    }
    i -= 131072;
    if (i < 2048) {  // Ff2: Kin=128, Dh=32
        int c = i >> 7, k = i & 127;
        float s = 0.f;
        if (c < 8) {
            const float* a = (c < 4) ? al2 : ar2;
            int hh = c & 3;
            for (int d = 0; d < 32; d++) s += W2[k * 128 + hh * 32 + d] * a[hh * 32 + d];
        }
        Ff2[i] = f2bf(s);
        return;
    }
    i -= 2048;
    if (i < 2048) {  // Ff3: Kin=128, Dh=64
        int c = i >> 7, k = i & 127;
        float s = 0.f;
        if (c < 8) {
            const float* a = (c < 4) ? al3 : ar3;
            int hh = c & 3;
            for (int d = 0; d < 64; d++) s += W3[k * 256 + hh * 64 + d] * a[hh * 64 + d];
        }
        Ff3[i] = f2bf(s);
        return;
    }
    i -= 2048;
    if (i < 48) {  // F1: layer-1 fold (fp32, K=6), pre-scaled by log2(e) so agg1 uses exp2
        int k = i >> 3, c = i & 7;
        const float* a = (c < 4) ? al1 : ar1;
        int hh = c & 3;
        float s = 0.f;
        for (int d = 0; d < 32; d++) s += W1[k * 128 + hh * 32 + d] * a[hh * 32 + d];
        F1[k * 8 + c] = s * LOG2E;
        return;
    }
    i -= 48;
    if (i < 4096) {  // W1f: [C=128][K=32], k = h*8+d; slot d==6 carries bias (pairs with 1.0)
        int c = i >> 5, k = i & 31;
        int h = c >> 5, d = k & 7;
        float v = 0.f;
        if ((k >> 3) == h) {
            if (d < 6) v = W1[d * 128 + c];
            else if (d == 6) v = b1v[c];
        }
        W1f[i] = f2bf(v);
    }
}

__global__ void f2bf_kernel(const float* __restrict__ x, bf16* __restrict__ y) {
    int i = blockIdx.x * blockDim.x + threadIdx.x;
    float4 v = ((const float4*)x)[i];
    ushort4 u;
    u.x = f2bf(v.x); u.y = f2bf(v.y); u.z = f2bf(v.z); u.w = f2bf(v.w);
    ((ushort4*)y)[i] = u;
}

__global__ void wt_kernel(const float* __restrict__ W, bf16* __restrict__ Wt, int K, int C) {
    int i = blockIdx.x * blockDim.x + threadIdx.x;
    if (i >= K * C) return;
    int c = i / K, k = i - c * K;
    Wt[i] = f2bf(W[(size_t)k * C + c]);
}

// ---------------- layer-1 front end ----------------

// Fused: pack raw feats into padded [2NN][8] fp32 rows + compute el/er (log2e-scaled F1).
__global__ void featelr_kernel(const float* __restrict__ f0, const float* __restrict__ f1,
                               const float* __restrict__ F1, float* __restrict__ fpk,
                               float* __restrict__ el, float* __restrict__ er) {
    int n = blockIdx.x * blockDim.x + threadIdx.x;  // [0, 2*NN)
    const float* x = (n < NN) ? (f0 + (size_t)n * 6) : (f1 + (size_t)(n - NN) * 6);
    float xv[6];
#pragma unroll
    for (int k = 0; k < 6; k++) xv[k] = x[k];
    float4* o = (float4*)(fpk + (size_t)n * 8);
    o[0] = make_float4(xv[0], xv[1], xv[2], xv[3]);
    o[1] = make_float4(xv[4], xv[5], 0.f, 0.f);
    float4 elv, erv;
    float* ep = (float*)&elv;
    float* rp = (float*)&erv;
#pragma unroll
    for (int c = 0; c < 4; c++) {
        float sl = 0.f, sr = 0.f;
#pragma unroll
        for (int k = 0; k < 6; k++) {
            sl += xv[k] * F1[k * 8 + c];
            sr += xv[k] * F1[k * 8 + c + 4];
        }
        ep[c] = sl;
        rp[c] = sr;
    }
    *(float4*)(el + (size_t)n * 4) = elv;
    *(float4*)(er + (size_t)n * 4) = erv;
}

// Fused layer-1: one lane per node gathers + softmax-aggregates the 6-dim feats
// (vector el float4 + packed-feat float4x2, exp2 weights), then per-wave MFMA does the
// 32->128 W1 transform (bias folded via the 1.0 slot in sagg / b1 row in W1f).
__global__ __launch_bounds__(256) void agg1mfma_kernel(
        const float* __restrict__ fpk, const float* __restrict__ el,
        const float* __restrict__ er, const int* __restrict__ deg,
        const int* __restrict__ slots, const bf16* __restrict__ W1fg,
        bf16* __restrict__ xb) {
    __shared__ bf16 sW[128 * 40];     // [128 ch][32 k] padded to 40 (bank-conflict break)
    __shared__ bf16 sagg[256 * 40];   // [256 node][32 k] padded to 40
    int t = threadIdx.x;
    // stage W1f into padded LDS (one row = 64B = 4x uint4)
    if (t < 128) {
        const uint4* src = (const uint4*)(W1fg + t * 32);
        uint4* dstp = (uint4*)(sW + t * 40);
        dstp[0] = src[0]; dstp[1] = src[1]; dstp[2] = src[2]; dstp[3] = src[3];
    }

    // ---- phase 1: per-lane gather softmax-aggregate ----
    int node = blockIdx.x * 256 + t;
    int dg = deg[node];
    dg = (dg > CAP) ? CAP : dg;
    float4 er4 = *(const float4*)(er + (size_t)node * 4);
    const int* sp = slots + (size_t)node * CAP;
    float a0[4], a1[4], a2[4], a3[4], a4[4], a5[4], ss[4];
#pragma unroll
    for (int h = 0; h < 4; h++) {
        a0[h] = a1[h] = a2[h] = a3[h] = a4[h] = a5[h] = ss[h] = 0.f;
    }
    for (int p = 0; p < dg; p += 4) {
        int4 s4 = *(const int4*)(sp + p);
        int sarr[4] = {s4.x, s4.y, s4.z, s4.w};
#pragma unroll
        for (int k = 0; k < 4; k++) {
            bool vld = (p + k) < dg;
            int g = vld ? sarr[k] : s4.x;       // clamp: unread slots may be garbage
            float4 e4 = *(const float4*)(el + (size_t)g * 4);
            float4 xa = *(const float4*)(fpk + (size_t)g * 8);
            float4 xc = *(const float4*)(fpk + (size_t)g * 8 + 4);
            float eh[4] = {e4.x, e4.y, e4.z, e4.w};
            float rh[4] = {er4.x, er4.y, er4.z, er4.w};
#pragma unroll
            for (int h = 0; h < 4; h++) {
                float z = eh[h] + rh[h];
                float w = EXP2(fmaxf(z, 0.f) + NEG_SLOPE * fminf(z, 0.f));
                w = vld ? w : 0.f;
                ss[h] += w;
                a0[h] += w * xa.x; a1[h] += w * xa.y; a2[h] += w * xa.z;
                a3[h] += w * xa.w; a4[h] += w * xc.x; a5[h] += w * xc.y;
            }
        }
    }
#pragma unroll
    for (int h = 0; h < 4; h++) {
        float rs = (dg > 0) ? 1.f / ss[h] : 0.f;
        uint4 o;
        o.x = pkbf(a0[h] * rs, a1[h] * rs);
        o.y = pkbf(a2[h] * rs, a3[h] * rs);
        o.z = pkbf(a4[h] * rs, a5[h] * rs);
        o.w = 0x00003F80u;  // (1.0bf16, 0.0): bias slot k=h*8+6
        *(uint4*)(sagg + t * 40 + h * 8) = o;
    }
    __syncthreads();

    // ---- phase 2: per-wave MFMA, 64 nodes x 128 channels ----
    int wave = t >> 6, lane = t & 63;
    int mlane = lane & 15, quad = lane >> 4;
    short8 af[8];
#pragma unroll
    for (int j = 0; j < 8; j++)
        af[j] = *(const short8*)(sW + (j * 16 + mlane) * 40 + quad * 8);
    floatx4 z4 = (floatx4){0.f, 0.f, 0.f, 0.f};
#pragma unroll
    for (int nt = 0; nt < 4; nt++) {
        int lrow = wave * 64 + nt * 16 + mlane;
        short8 bfr = *(const short8*)(sagg + lrow * 40 + quad * 8);
        floatx4 c[8];
#pragma unroll
        for (int j = 0; j < 8; j++)
            c[j] = __builtin_amdgcn_mfma_f32_16x16x32_bf16(af[j], bfr, z4, 0, 0, 0);
        // D: col = mlane -> node, row = quad*4+r -> channel j*16+quad*4+r
        bf16* op = xb + (size_t)(blockIdx.x * 256 + lrow) * 128 + quad * 4;
#pragma unroll
        for (int j = 0; j < 8; j++) {
            uint2 o;
            o.x = pkbf(fmaxf(c[j][0], 0.f), fmaxf(c[j][1], 0.f));
            o.y = pkbf(fmaxf(c[j][2], 0.f), fmaxf(c[j][3], 0.f));
            *(uint2*)(op + j * 16) = o;
        }
    }
}

// ---------------- GAT kernels (merged over 2*NN) ----------------

// Phase-A helper (agg3pool only): lane = h*16+e computes alpha[e][h] + clamped src.
__device__ __forceinline__ void softmax_phaseA(const float* __restrict__ el,
                                               const float* __restrict__ er,
                                               const int* __restrict__ slots,
                                               int wid, int dg, int lane,
                                               float* alpha_out, int* src_out) {
    int e = lane & 15, h = lane >> 4;
    int sA = slots[(size_t)wid * CAP + e];
    int sAc = (e < dg) ? sA : 0;                 // clamp: poisoned slots are unsafe addrs
    float erh = er[wid * 4 + h];
    float elv = el[sAc * 4 + h];
    float w = (e < dg) ? __expf(leaky(elv + erh)) : 0.f;
    float ssum = w;
    ssum += __shfl_xor(ssum, 1, 64);
    ssum += __shfl_xor(ssum, 2, 64);
    ssum += __shfl_xor(ssum, 4, 64);
    ssum += __shfl_xor(ssum, 8, 64);
    *alpha_out = (dg > 0) ? w * (1.f / ssum) : 0.f;   // 0 for e>=dg (w=0)
    *src_out = sAc;
}

// layer-2 agg (R13 structure): 32 lanes/node, inline per-lane-head softmax,
// 4-edge batch (4 loads in flight), 4B fp8 loads, HW cvt.
__global__ void agg2_kernel(const unsigned char* __restrict__ h8, const float* __restrict__ el,
                            const float* __restrict__ er, const int* __restrict__ deg,
                            const int* __restrict__ slots, const float* __restrict__ bias,
                            bf16* __restrict__ out) {
    int t = blockIdx.x * blockDim.x + threadIdx.x;
    int wid = t >> 5;                // [0, 2*NN)
    int gl = threadIdx.x & 31;
    int dg = deg[wid];
    dg = (dg > CAP) ? CAP : dg;
    int head = gl >> 3;
    int fbase = gl * 4;
    float erh = er[wid * 4 + head];
    const int* sp = slots + (size_t)wid * CAP;
    float a0 = 0.f, a1 = 0.f, a2 = 0.f, a3 = 0.f, ssum = 0.f;

    for (int p = 0; p < dg; p += 4) {
        int4 s4 = *(const int4*)(sp + p);
        int s[4]; bool v[4];
        s[0] = s4.x; v[0] = true;
        v[1] = p + 1 < dg; s[1] = v[1] ? s4.y : s4.x;
        v[2] = p + 2 < dg; s[2] = v[2] ? s4.z : s4.x;
        v[3] = p + 3 < dg; s[3] = v[3] ? s4.w : s4.x;
        float elv[4]; unsigned u1[4];
#pragma unroll
        for (int k = 0; k < 4; k++) {
            elv[k] = el[s[k] * 4 + head];
            u1[k] = *(const unsigned*)(h8 + (size_t)s[k] * 128 + fbase);
        }
#pragma unroll
        for (int k = 0; k < 4; k++) {
            float w = v[k] ? __expf(leaky(elv[k] + erh)) : 0.f;
            ssum += w;
            floatx2 lo = __builtin_amdgcn_cvt_pk_f32_fp8((int)u1[k], false);
            floatx2 hi = __builtin_amdgcn_cvt_pk_f32_fp8((int)u1[k], true);
            a0 += w * lo[0]; a1 += w * lo[1];
            a2 += w * hi[0]; a3 += w * hi[1];
        }
    }
    float rs = (dg > 0) ? 1.f / ssum : 0.f;
    float4 bbv = *(const float4*)(bias + fbase);
    float v0 = fmaxf(a0 * rs + bbv.x, 0.f), v1 = fmaxf(a1 * rs + bbv.y, 0.f);
    float v2 = fmaxf(a2 * rs + bbv.z, 0.f), v3 = fmaxf(a3 * rs + bbv.w, 0.f);
    uint2 uo;
    uo.x = (unsigned)f2bf(v0) | ((unsigned)f2bf(v1) << 16);
    uo.y = (unsigned)f2bf(v2) | ((unsigned)f2bf(v3) << 16);
    *(uint2*)(out + (size_t)wid * 128 + fbase) = uo;
}

// layer-3 agg fused with graph mean-pool.
// R3: 4-node batch per 64-lane group + LDS (src,alpha) vectorized broadcast
// (replaces 8 ds_bpermute/quad with 2 ds_read_b128), loads issued in bulk
// before accumulation -> ~16 gather loads in flight per wave.
__global__ void agg3pool_kernel(const unsigned char* __restrict__ h8,
                                const float* __restrict__ el, const float* __restrict__ er,
                                const int* __restrict__ deg, const int* __restrict__ slots,
                                const float* __restrict__ bias, bf16* __restrict__ pair) {
    __shared__ float red[4 * 256];       // 4 KB
    __shared__ float salpha[4][4][64];   // 4 KB  [grp][q][h*16+e]
    __shared__ int   ssrc[4][4][16];     // 1 KB  [grp][q][e]
    int side = blockIdx.x >> 12;         // 8192 blocks: side*4096 + b
    int b = blockIdx.x & 4095;
    int nodebase = side * NN + b * 32;
    int grp = threadIdx.x >> 6, lane = threadIdx.x & 63;
    int e = lane & 15, h = lane >> 4;
    int fbase = lane * 4;                // feature channel block
    float p0 = 0.f, p1 = 0.f, p2 = 0.f, p3 = 0.f;

    for (int nn = 0; nn < 8; nn += 4) {
        int wid0 = nodebase + grp * 8 + nn;
        int dgv[4];
        // ---- phase A: 4 independent softmax chains; publish (alpha, src) to LDS ----
#pragma unroll
        for (int q = 0; q < 4; q++) {
            int wid = wid0 + q;
            int dg = deg[wid];
            dg = (dg > CAP) ? CAP : dg;
            dgv[q] = dg;
            float alpha; int sAc;
            softmax_phaseA(el, er, slots, wid, dg, lane, &alpha, &sAc);
            salpha[grp][q][lane] = alpha;        // [h*16+e]
            if (h == 0) ssrc[grp][q][e] = sAc;   // clamped src (0 for e>=dg)
        }
        // same-wave LDS RAW: ds ops are wave-ordered, no barrier needed
        int dgmax = max(max(dgv[0], dgv[1]), max(dgv[2], dgv[3]));
        for (int p = 0; p < dgmax; p += 4) {
            // gather phase 1: broadcast (src, alpha) quads + issue all 16 loads
            int4 sc4[4]; float4 av4[4];
#pragma unroll
            for (int q = 0; q < 4; q++) {
                sc4[q] = *(const int4*)&ssrc[grp][q][p];
                av4[q] = *(const float4*)&salpha[grp][q][h * 16 + p];
            }
            unsigned u[4][4];
#pragma unroll
            for (int q = 0; q < 4; q++) {
                u[q][0] = *(const unsigned*)(h8 + (size_t)sc4[q].x * 256 + fbase);
                u[q][1] = *(const unsigned*)(h8 + (size_t)sc4[q].y * 256 + fbase);
                u[q][2] = *(const unsigned*)(h8 + (size_t)sc4[q].z * 256 + fbase);
                u[q][3] = *(const unsigned*)(h8 + (size_t)sc4[q].w * 256 + fbase);
            }
            // gather phase 2: accumulate (alpha=0 past dg -> wasted loads add 0)
#pragma unroll
            for (int q = 0; q < 4; q++) {
                float av[4] = {av4[q].x, av4[q].y, av4[q].z, av4[q].w};
#pragma unroll
                for (int k = 0; k < 4; k++) {
                    floatx2 lo = __builtin_amdgcn_cvt_pk_f32_fp8((int)u[q][k], false);
                    floatx2 hi = __builtin_amdgcn_cvt_pk_f32_fp8((int)u[q][k], true);
                    p0 += av[k] * lo[0]; p1 += av[k] * lo[1];
                    p2 += av[k] * hi[0]; p3 += av[k] * hi[1];
                }
            }
        }
    }
    red[grp * 256 + fbase + 0] = p0;
    red[grp * 256 + fbase + 1] = p1;
    red[grp * 256 + fbase + 2] = p2;
    red[grp * 256 + fbase + 3] = p3;
    __syncthreads();
    if (grp == 0) {
        float4 bbv = *(const float4*)(bias + fbase);
        float s0 = 0.f, s1 = 0.f, s2 = 0.f, s3 = 0.f;
#pragma unroll
        for (int g = 0; g < 4; g++) {
            s0 += red[g * 256 + fbase + 0];
            s1 += red[g * 256 + fbase + 1];
            s2 += red[g * 256 + fbase + 2];
            s3 += red[g * 256 + fbase + 3];
        }
        const float inv = 1.0f / 32.0f;
        float v0 = s0 * inv + bbv.x, v1 = s1 * inv + bbv.y;
        float v2 = s2 * inv + bbv.z, v3 = s3 * inv + bbv.w;
        uint2 uo;
        uo.x = (unsigned)f2bf(v0) | ((unsigned)f2bf(v1) << 16);
        uo.y = (unsigned)f2bf(v2) | ((unsigned)f2bf(v3) << 16);
        *(uint2*)(pair + (size_t)b * 512 + side * 256 + fbase) = uo;
    }
}

// ---------------- MFMA bf16 GEMM: out[M,C] = A[M,K] @ Wt[C,K]^T (+bias)(+relu) ----------------
template <bool FOLD, bool OUT8>
__global__ __launch_bounds__(256) void mgemm_kernel(const bf16* __restrict__ A,
                                                    const bf16* __restrict__ Wt,
                                                    const float* __restrict__ bias,
                                                    void* __restrict__ out,
                                                    int K, int C, int relu,
                                                    const bf16* __restrict__ Ff,
                                                    float* __restrict__ el,
                                                    float* __restrict__ er) {
    __shared__ short As[128 * 48];
    __shared__ short Bs[128 * 48];
    int t = threadIdx.x;
    int wave = t >> 6, lane = t & 63;
    int wm = (wave >> 1) * 64, wn = (wave & 1) * 64;
    int bm = blockIdx.x * 128, bn = blockIdx.y * 128;
    int m_lane = lane & 15, quad = lane >> 4;
    bool dofold = FOLD && (blockIdx.y == 0) && (wn == 0);

    floatx4 acc[4][4];
#pragma unroll
    for (int i = 0; i < 4; i++)
#pragma unroll
        for (int j = 0; j < 4; j++) acc[i][j] = (floatx4){0.f, 0.f, 0.f, 0.f};
    floatx4 facc[4];
    if (FOLD) {
#pragma unroll
        for (int i = 0; i < 4; i++) facc[i] = (floatx4){0.f, 0.f, 0.f, 0.f};
    }

    int lrow = t >> 2, lq = t & 3;
    for (int k0 = 0; k0 < K; k0 += 32) {
        __syncthreads();
#pragma unroll
        for (int pass = 0; pass < 2; pass++) {
            int row = lrow + pass * 64;
            *(short8*)&As[row * 48 + lq * 8] =
                *(const short8*)(A + (size_t)(bm + row) * K + k0 + lq * 8);
            *(short8*)&Bs[row * 48 + lq * 8] =
                *(const short8*)(Wt + (size_t)(bn + row) * K + k0 + lq * 8);
        }
        __syncthreads();
        short8 af[4], bf[4];
#pragma unroll
        for (int i = 0; i < 4; i++)
            af[i] = *(const short8*)&As[(wm + i * 16 + m_lane) * 48 + quad * 8];
#pragma unroll
        for (int j = 0; j < 4; j++)
            bf[j] = *(const short8*)&Bs[(wn + j * 16 + m_lane) * 48 + quad * 8];
        if (dofold) {
            short8 fbv = *(const short8*)(Ff + m_lane * K + k0 + quad * 8);
#pragma unroll
            for (int i = 0; i < 4; i++)
                facc[i] = __builtin_amdgcn_mfma_f32_16x16x32_bf16(af[i], fbv, facc[i], 0, 0, 0);
        }
#pragma unroll
        for (int i = 0; i < 4; i++)
#pragma unroll
            for (int j = 0; j < 4; j++)
                acc[i][j] = __builtin_amdgcn_mfma_f32_16x16x32_bf16(af[i], bf[j], acc[i][j], 0, 0, 0);
    }

#pragma unroll
    for (int i = 0; i < 4; i++) {
#pragma unroll
        for (int j = 0; j < 4; j++) {
            int gc = bn + wn + j * 16 + m_lane;
            float bbv = bias ? bias[gc] : 0.f;
#pragma unroll
            for (int r = 0; r < 4; r++) {
                int gr = bm + wm + i * 16 + quad * 4 + r;
                float v = acc[i][j][r] + bbv;
                if (relu) v = fmaxf(v, 0.f);
                if (OUT8) ((unsigned char*)out)[(size_t)gr * C + gc] = ftofp8(v);
                else      ((bf16*)out)[(size_t)gr * C + gc] = f2bf(v);
            }
        }
    }
    if (dofold && m_lane < 8) {
        float* dst = (m_lane < 4) ? el : er;
        int hh = m_lane & 3;
#pragma unroll
        for (int i = 0; i < 4; i++)
#pragma unroll
            for (int r = 0; r < 4; r++) {
                int gr = bm + wm + i * 16 + quad * 4 + r;
                dst[gr * 4 + hh] = facc[i][r];
            }
    }
}

// ---------------- fp32 512x512x512 GEMM (weight combine, prep-time) ----------------
__global__ __launch_bounds__(256) void fgemm512_kernel(const float* __restrict__ A,
                                                       const float* __restrict__ B,
                                                       float* __restrict__ C) {
    const int BK = 16;
    __shared__ float As[BK][68];
    __shared__ float Bs[BK][68];
    int t = threadIdx.x;
    int bm = blockIdx.x * 64, bn = blockIdx.y * 64;
    int tm0 = (t & 15) * 4, tn0 = (t >> 4) * 4;
    float acc[4][4] = {};
    int la_m = t >> 2, la_k = (t & 3) * 4;
    int lb_k = t >> 4, lb_c = (t & 15) * 4;

    for (int k0 = 0; k0 < 512; k0 += BK) {
        float4 a4 = *(const float4*)(A + (size_t)(bm + la_m) * 512 + k0 + la_k);
        float4 b4 = *(const float4*)(B + (size_t)(k0 + lb_k) * 512 + bn + lb_c);
        As[la_k + 0][la_m] = a4.x; As[la_k + 1][la_m] = a4.y;
        As[la_k + 2][la_m] = a4.z; As[la_k + 3][la_m] = a4.w;
        *(float4*)&Bs[lb_k][lb_c] = b4;
        __syncthreads();
#pragma unroll
        for (int k = 0; k < BK; k++) {
            float4 av = *(const float4*)&As[k][tm0];
            float4 bv = *(const float4*)&Bs[k][tn0];
            acc[0][0] += av.x * bv.x; acc[0][1] += av.x * bv.y; acc[0][2] += av.x * bv.z; acc[0][3] += av.x * bv.w;
            acc[1][0] += av.y * bv.x; acc[1][1] += av.y * bv.y; acc[1][2] += av.y * bv.z; acc[1][3] += av.y * bv.w;
            acc[2][0] += av.z * bv.x; acc[2][1] += av.z * bv.y; acc[2][2] += av.z * bv.z; acc[2][3] += av.z * bv.w;
            acc[3][0] += av.w * bv.x; acc[3][1] += av.w * bv.y; acc[3][2] += av.w * bv.z; acc[3][3] += av.w * bv.w;
        }
        __syncthreads();
    }
#pragma unroll
    for (int i = 0; i < 4; i++) {
        float4 o = make_float4(acc[i][0], acc[i][1], acc[i][2], acc[i][3]);
        *(float4*)(C + (size_t)(bm + tm0 + i) * 512 + bn + tn0) = o;
    }
}

__global__ void biasstep_kernel(const float* __restrict__ vin, const float* __restrict__ M,
                                const float* __restrict__ badd, float* __restrict__ vout) {
    int c = blockIdx.x * blockDim.x + threadIdx.x;
    float s = 0.f;
    for (int k = 0; k < 512; k++) s += vin[k] * M[(size_t)k * 512 + c];
    vout[c] = s + badd[c];
}

// ---------------- fusion tail ----------------

__global__ void ln_kernel(const bf16* __restrict__ attn, const bf16* __restrict__ lp,
                          const float* __restrict__ gamma, const float* __restrict__ beta,
                          bf16* __restrict__ out) {
    __shared__ float red[256];
    int b = blockIdx.x, t = threadIdx.x;
    size_t base = (size_t)b * 512;
    float x0 = bf2f(attn[base + t]) + bf2f(lp[base + t]);
    float x1 = bf2f(attn[base + 256 + t]) + bf2f(lp[base + 256 + t]);
    red[t] = x0 + x1; __syncthreads();
    for (int off = 128; off > 0; off >>= 1) { if (t < off) red[t] += red[t + off]; __syncthreads(); }
    float mu = red[0] * (1.0f / 512.0f);
    __syncthreads();
    float d0 = x0 - mu, d1 = x1 - mu;
    red[t] = d0 * d0 + d1 * d1; __syncthreads();
    for (int off = 128; off > 0; off >>= 1) { if (t < off) red[t] += red[t + off]; __syncthreads(); }
    float rstd = rsqrtf(red[0] * (1.0f / 512.0f) + LN_EPS);
    out[base + t]       = f2bf(d0 * rstd * gamma[t] + beta[t]);
    out[base + 256 + t] = f2bf(d1 * rstd * gamma[256 + t] + beta[256 + t]);
}

__global__ void cls2_kernel(const bf16* __restrict__ hc, const float* __restrict__ Wc2,
                            const float* __restrict__ bc2, float* __restrict__ out) {
    int wid = (blockIdx.x * blockDim.x + threadIdx.x) >> 6;
    int lane = threadIdx.x & 63;
    if (wid >= NB) return;
    float s = 0.f;
#pragma unroll
    for (int j = 0; j < 4; j++) {
        int k = lane + 64 * j;
        s += bf2f(hc[(size_t)wid * 256 + k]) * Wc2[k];
    }
    for (int off = 32; off > 0; off >>= 1) s += __shfl_down(s, off);
    if (lane == 0) {
        float v = s + bc2[0];
        out[wid] = 1.0f / (1.0f + __expf(-v));
    }
}

// ---------------- launch ----------------

static inline size_t alup(size_t x) { return (x + 255) & ~(size_t)255; }

extern "C" void kernel_launch(void* const* d_in, const int* in_sizes, int n_in,
                              void* d_out, int out_size, void* d_ws, size_t ws_size,
                              hipStream_t stream) {
    const float* feat0 = (const float*)d_in[0];
    const float* feat1 = (const float*)d_in[1];
    const float* llm = (const float*)d_in[2];
    const int* srcs[2] = {(const int*)d_in[3], (const int*)d_in[5]};
    const int* dsts[2] = {(const int*)d_in[4], (const int*)d_in[6]};
    const float* W1 = (const float*)d_in[8];
    const float* al[3] = {(const float*)d_in[9],  (const float*)d_in[13], (const float*)d_in[17]};
    const float* ar[3] = {(const float*)d_in[10], (const float*)d_in[14], (const float*)d_in[18]};
    const float* bb[3] = {(const float*)d_in[11], (const float*)d_in[15], (const float*)d_in[19]};
    const float* W2 = (const float*)d_in[12];
    const float* W3 = (const float*)d_in[16];
    const float* Wpg = (const float*)d_in[20]; const float* bpg = (const float*)d_in[21];
    const float* Wpl = (const float*)d_in[22]; const float* bpl = (const float*)d_in[23];
    const float* Wv  = (const float*)d_in[24]; const float* bv  = (const float*)d_in[25];
    const float* Wo  = (const float*)d_in[26]; const float* bo  = (const float*)d_in[27];
    const float* gamma = (const float*)d_in[28]; const float* beta = (const float*)d_in[29];
    const float* Wc1 = (const float*)d_in[30]; const float* bc1 = (const float*)d_in[31];
    const float* Wc2 = (const float*)d_in[32]; const float* bc2 = (const float*)d_in[33];
    float* outp = (float*)d_out;

    const size_t N2 = (size_t)2 * NN;

    // workspace carve (~138 MiB)
    char* p = (char*)d_ws;
    auto take = [&](size_t bytes) { char* r = p; p += alup(bytes); return r; };
    bf16*  xb     = (bf16*)take(N2 * 128 * 2);        // A: 64 MiB (layer-1/2 activations)
    char*  regB   = (char*)take(N2 * 256);            // B: 64 MiB (cells+counts / fpk / hb2 / hb3 / tail)
    float* el     = (float*)take(N2 * 4 * 4);         // 4 MiB
    float* er     = (float*)take(N2 * 4 * 4);         // 4 MiB
    int*   deg    = (int*)take(N2 * 4);               // 1 MiB
    int*   slots  = (int*)take(N2 * CAP * 4);         // 16.8 MiB
    bf16*  pair   = (bf16*)take((size_t)NB * 512 * 2);
    bf16*  llm_bf = (bf16*)take((size_t)NB * 1024 * 2); // 8 MiB
    bf16*  W2t  = (bf16*)take(128 * 128 * 2);
    bf16*  W3t  = (bf16*)take(128 * 256 * 2);
    bf16*  Wplt = (bf16*)take(1024 * 512 * 2);
    bf16*  Wc1t = (bf16*)take(512 * 256 * 2);
    bf16*  Wcot = (bf16*)take(512 * 512 * 2);
    float* F1   = (float*)take(6 * 8 * 4);
    bf16*  Ff2  = (bf16*)take(16 * 128 * 2);
    bf16*  Ff3  = (bf16*)take(16 * 128 * 2);
    bf16*  W1fg = (bf16*)take(128 * 32 * 2);          // 8 KiB layer-1 MFMA weight
    float* c1   = (float*)take(512 * 512 * 4);
    float* c2   = (float*)take(512 * 512 * 4);
    float* bias1 = (float*)take(512 * 4);
    float* bco   = (float*)take(512 * 4);
    // region B aliases (sequential lifetimes):
    unsigned* cells = (unsigned*)regB;                // [NBKT][NBLK1][CELL_CAP] 25 MiB (pre-fpk)
    int* counts = (int*)(regB + (size_t)NBKT * NBLK1 * CELL_CAP * 4);  // 1 MiB
    float* fpk          = (float*)regB;               // packed feats [2NN][8] (8.4 MiB, pre-L2)
    unsigned char* hb2  = (unsigned char*)regB;       // layer-2 features fp8 [2NN,128] (32 MiB)
    unsigned char* hb3  = (unsigned char*)regB;       // layer-3 features fp8 [2NN,256] (64 MiB)
    bf16* fbb   = (bf16*)regB;                        // fusion-tail activations
    bf16* lp    = fbb + (size_t)0 * NB * 512;
    bf16* attn  = fbb + (size_t)1 * NB * 512;
    bf16* fused = fbb + (size_t)2 * NB * 512;
    bf16* hc    = fbb + (size_t)3 * NB * 512;
    (void)ws_size; (void)n_in; (void)in_sizes; (void)out_size;

    auto mgemm = [&](const bf16* A, const bf16* Wt, const float* bias, bf16* o,
                     int M, int K, int C, int relu) {
        dim3 g(M / 128, C / 128);
        mgemm_kernel<false, false><<<g, 256, 0, stream>>>(A, Wt, bias, o, K, C, relu,
                                                          nullptr, nullptr, nullptr);
    };

    // ---- slot bucketing first (cells alias region B, consumed before fpk) ----
    part_edges_kernel<<<NBLK1, 256, 0, stream>>>(srcs[0], dsts[0], srcs[1], dsts[1],
                                                 cells, counts);
    build_slots_kernel<<<NBKT, 256, 0, stream>>>(cells, counts, deg, slots);

    // ---- per-call preps ----
    prep_all_kernel<<<(PREP_TOTAL + 255) / 256, 256, 0, stream>>>(
        W2, W3, Wpl, Wc1, W1, al[0], ar[0], al[1], ar[1], al[2], ar[2], bb[0],
        W2t, W3t, Wplt, Wc1t, Ff2, Ff3, F1, W1fg);
    f2bf_kernel<<<NB * 1024 / 4 / 256, 256, 0, stream>>>(llm, llm_bf);
    {
        dim3 g8(8, 8);
        fgemm512_kernel<<<g8, 256, 0, stream>>>(Wpg, Wv, c1);
        fgemm512_kernel<<<g8, 256, 0, stream>>>(c1, Wo, c2);
        wt_kernel<<<(512 * 512 + 255) / 256, 256, 0, stream>>>(c2, Wcot, 512, 512);
        biasstep_kernel<<<2, 256, 0, stream>>>(bpg, Wv, bv, bias1);
        biasstep_kernel<<<2, 256, 0, stream>>>(bias1, Wo, bo, bco);
    }

    // ---- GNN, both sides merged ----
    featelr_kernel<<<2 * NN / 256, 256, 0, stream>>>(feat0, feat1, F1, fpk, el, er);
    agg1mfma_kernel<<<2 * NN / 256, 256, 0, stream>>>(fpk, el, er, deg, slots, W1fg, xb);
    {
        dim3 g(2 * NN / 128, 1);
        mgemm_kernel<true, true><<<g, 256, 0, stream>>>(xb, W2t, nullptr, hb2, 128, 128, 0,
                                                        Ff2, el, er);
    }
    agg2_kernel<<<2 * NN * 32 / 256, 256, 0, stream>>>(hb2, el, er, deg, slots, bb[1], xb);
    {
        dim3 g(2 * NN / 128, 2);
        mgemm_kernel<true, true><<<g, 256, 0, stream>>>(xb, W3t, nullptr, hb3, 128, 256, 0,
                                                        Ff3, el, er);
    }
    agg3pool_kernel<<<2 * NB, 256, 0, stream>>>(hb3, el, er, deg, slots, bb[2], pair);

    // ---- fusion tail (activations alias region B) ----
    mgemm(llm_bf, Wplt, bpl, lp, NB, 1024, 512, 0);
    mgemm(pair, Wcot, bco, attn, NB, 512, 512, 0);
    ln_kernel<<<NB, 256, 0, stream>>>(attn, lp, gamma, beta, fused);
    mgemm(fused, Wc1t, bc1, hc, NB, 512, 256, 1);
    cls2_kernel<<<NB / 4, 256, 0, stream>>>(hc, Wc2, bc2, outp);
}

// Round 5
// 582.726 us; speedup vs baseline: 1.0198x; 1.0198x over previous
//
#include <hip/hip_runtime.h>
#include <hip/hip_fp8.h>

#define NN 131072      // nodes per side
#define NE 524288      // edges per side
#define NB 4096        // graphs per side
#define CAP 16         // slot capacity = one 64B line/node
#define NEG_SLOPE 0.2f
#define LN_EPS 1e-5f
#define LOG2E 1.44269504088896f

// edge-partition geometry (atomic-free slot build)
#define NBKT 1024      // buckets of 256 nodes (2NN/256)
#define NBLK1 256      // phase-1 blocks
#define CELL_CAP 24    // per-(bucket,block) cell capacity (avg 4, Poisson tail ~1e-13)

typedef unsigned short bf16;
typedef __attribute__((ext_vector_type(8))) short short8;
typedef __attribute__((ext_vector_type(4))) float floatx4;
typedef __attribute__((ext_vector_type(2))) float floatx2;

#if __has_builtin(__builtin_amdgcn_exp2f)
#define EXP2(x) __builtin_amdgcn_exp2f(x)
#else
#define EXP2(x) exp2f(x)
#endif

__device__ __forceinline__ float bf2f(bf16 h) {
    return __uint_as_float((unsigned)h << 16);
}
__device__ __forceinline__ bf16 f2bf(float f) {
    unsigned u = __float_as_uint(f);
    unsigned r = (u + 0x7FFFu + ((u >> 16) & 1u)) >> 16;
    return (bf16)r;
}
// HW packed bf16 pair encode (RNE, same unit the compiler uses for bf16 casts)
__device__ __forceinline__ unsigned pkbf(float lo, float hi) {
    unsigned r;
    asm("v_cvt_pk_bf16_f32 %0, %1, %2" : "=v"(r) : "v"(lo), "v"(hi));
    return r;
}
// HW packed fp8(e4m3) encode
__device__ __forceinline__ unsigned char ftofp8(float f) {
    return (unsigned char)(__builtin_amdgcn_cvt_pk_fp8_f32(f, f, 0, false) & 0xFF);
}
__device__ __forceinline__ float leaky(float x) {
    return fmaxf(x, 0.f) + NEG_SLOPE * fminf(x, 0.f);
}

// ---------------- atomic-free slot build (two-phase partition) ----------------
// Phase 1: bin edges into block-private cells via LDS histogram (no global atomics;
//          cell lines are block-private -> no cross-XCD ping-pong).
__global__ __launch_bounds__(256) void part_edges_kernel(
        const int* __restrict__ s0, const int* __restrict__ d0,
        const int* __restrict__ s1, const int* __restrict__ d1,
        unsigned* __restrict__ cells, int* __restrict__ counts) {
    __shared__ int lcnt[NBKT];       // 4 KB
    int blk = blockIdx.x, t = threadIdx.x;
    for (int i = t; i < NBKT; i += 256) lcnt[i] = 0;
    __syncthreads();
    int side = blk >= (NBLK1 / 2);               // 128 blocks per side
    const int4* dp = (const int4*)(side ? d1 : d0);
    const int4* sp = (const int4*)(side ? s1 : s0);
    int base4 = (blk - side * (NBLK1 / 2)) * 1024;
    int gbase = side * NN;
#pragma unroll
    for (int it = 0; it < 4; it++) {
        int e4 = base4 + it * 256 + t;           // [0, NE/4)
        int4 dd = dp[e4];
        int4 ss = sp[e4];
        int d[4] = {gbase + dd.x, gbase + dd.y, gbase + dd.z, gbase + dd.w};
        int s[4] = {gbase + ss.x, gbase + ss.y, gbase + ss.z, gbase + ss.w};
#pragma unroll
        for (int k = 0; k < 4; k++) {
            int b = d[k] >> 8;
            int r = atomicAdd(&lcnt[b], 1);      // LDS atomic
            if (r < CELL_CAP)
                cells[((size_t)b * NBLK1 + blk) * CELL_CAP + r] =
                    ((unsigned)s[k] << 8) | (unsigned)(d[k] & 255);
        }
    }
    __syncthreads();
    for (int i = t; i < NBKT; i += 256) {
        int c = lcnt[i];
        counts[i * NBLK1 + blk] = (c > CELL_CAP) ? CELL_CAP : c;
    }
}

// Phase 2: one block per bucket; build deg/slots for 256 nodes in LDS, write coalesced.
__global__ __launch_bounds__(256) void build_slots_kernel(
        const unsigned* __restrict__ cells, const int* __restrict__ counts,
        int* __restrict__ deg, int* __restrict__ slots) {
    __shared__ int ldeg[256];                    // 1 KB
    __shared__ int lslot[256 * CAP];             // 16 KB
    int b = blockIdx.x, t = threadIdx.x;
    ldeg[t] = 0;
    for (int i = t; i < 256 * CAP; i += 256) lslot[i] = 0;
    __syncthreads();
    // thread t consumes cell t of this bucket
    int cnt = counts[b * NBLK1 + t];
    const unsigned* cp = cells + ((size_t)b * NBLK1 + t) * CELL_CAP;
    for (int i = 0; i < cnt; i++) {
        unsigned v = cp[i];
        int d = v & 255;
        int s = (int)(v >> 8);
        int p = atomicAdd(&ldeg[d], 1);          // LDS atomic
        if (p < CAP) lslot[d * CAP + p] = s;
    }
    __syncthreads();
    int node0 = b * 256;
    deg[node0 + t] = ldeg[t];
    for (int i = t; i < 256 * CAP; i += 256)
        slots[(size_t)node0 * CAP + i] = lslot[i];
}

// ---------------- merged weight prep ----------------
// W2t + W3t + Wplt + Wc1t + Ff2 + Ff3 + F1 + W1f
#define PREP_TOTAL (16384 + 32768 + 524288 + 131072 + 2048 + 2048 + 48 + 4096)

__global__ void prep_all_kernel(const float* __restrict__ W2, const float* __restrict__ W3,
                                const float* __restrict__ Wpl, const float* __restrict__ Wc1,
                                const float* __restrict__ W1,
                                const float* __restrict__ al1, const float* __restrict__ ar1,
                                const float* __restrict__ al2, const float* __restrict__ ar2,
                                const float* __restrict__ al3, const float* __restrict__ ar3,
                                const float* __restrict__ b1v,
                                bf16* __restrict__ W2t, bf16* __restrict__ W3t,
                                bf16* __restrict__ Wplt, bf16* __restrict__ Wc1t,
                                bf16* __restrict__ Ff2, bf16* __restrict__ Ff3,
                                float* __restrict__ F1, bf16* __restrict__ W1f) {
    int i = blockIdx.x * blockDim.x + threadIdx.x;
    if (i < 16384) {  // W2t: K=128,C=128
        int c = i >> 7, k = i & 127;
        W2t[i] = f2bf(W2[k * 128 + c]);
        return;
    }
    i -= 16384;
    if (i < 32768) {  // W3t: K=128,C=256
        int c = i >> 7, k = i & 127;
        W3t[i] = f2bf(W3[k * 256 + c]);
        return;
    }
    i -= 32768;
    if (i < 524288) {  // Wplt: K=1024,C=512
        int c = i >> 10, k = i & 1023;
        Wplt[i] = f2bf(Wpl[k * 512 + c]);
        return;
    }
    i -= 524288;
    if (i < 131072) {  // Wc1t: K=512,C=256
        int c = i >> 9, k = i & 511;
        Wc1t[i] = f2bf(Wc1[k * 256 + c]);
        return;
    }
    i -= 131072;
    if (i < 2048) {  // Ff2: Kin=128, Dh=32
        int c = i >> 7, k = i & 127;
        float s = 0.f;
        if (c < 8) {
            const float* a = (c < 4) ? al2 : ar2;
            int hh = c & 3;
            for (int d = 0; d < 32; d++) s += W2[k * 128 + hh * 32 + d] * a[hh * 32 + d];
        }
        Ff2[i] = f2bf(s);
        return;
    }
    i -= 2048;
    if (i < 2048) {  // Ff3: Kin=128, Dh=64
        int c = i >> 7, k = i & 127;
        float s = 0.f;
        if (c < 8) {
            const float* a = (c < 4) ? al3 : ar3;
            int hh = c & 3;
            for (int d = 0; d < 64; d++) s += W3[k * 256 + hh * 64 + d] * a[hh * 64 + d];
        }
        Ff3[i] = f2bf(s);
        return;
    }
    i -= 2048;
    if (i < 48) {  // F1: layer-1 fold (fp32, K=6), pre-scaled by log2(e) so agg1 uses exp2
        int k = i >> 3, c = i & 7;
        const float* a = (c < 4) ? al1 : ar1;
        int hh = c & 3;
        float s = 0.f;
        for (int d = 0; d < 32; d++) s += W1[k * 128 + hh * 32 + d] * a[hh * 32 + d];
        F1[k * 8 + c] = s * LOG2E;
        return;
    }
    i -= 48;
    if (i < 4096) {  // W1f: [C=128][K=32], k = h*8+d; slot d==6 carries bias (pairs with 1.0)
        int c = i >> 5, k = i & 31;
        int h = c >> 5, d = k & 7;
        float v = 0.f;
        if ((k >> 3) == h) {
            if (d < 6) v = W1[d * 128 + c];
            else if (d == 6) v = b1v[c];
        }
        W1f[i] = f2bf(v);
    }
}

__global__ void f2bf_kernel(const float* __restrict__ x, bf16* __restrict__ y) {
    int i = blockIdx.x * blockDim.x + threadIdx.x;
    float4 v = ((const float4*)x)[i];
    ushort4 u;
    u.x = f2bf(v.x); u.y = f2bf(v.y); u.z = f2bf(v.z); u.w = f2bf(v.w);
    ((ushort4*)y)[i] = u;
}

__global__ void wt_kernel(const float* __restrict__ W, bf16* __restrict__ Wt, int K, int C) {
    int i = blockIdx.x * blockDim.x + threadIdx.x;
    if (i >= K * C) return;
    int c = i / K, k = i - c * K;
    Wt[i] = f2bf(W[(size_t)k * C + c]);
}

// ---------------- layer-1 front end ----------------

// Fused: pack raw feats into padded [2NN][8] fp32 rows + compute el/er (log2e-scaled F1).
__global__ void featelr_kernel(const float* __restrict__ f0, const float* __restrict__ f1,
                               const float* __restrict__ F1, float* __restrict__ fpk,
                               float* __restrict__ el, float* __restrict__ er) {
    int n = blockIdx.x * blockDim.x + threadIdx.x;  // [0, 2*NN)
    const float* x = (n < NN) ? (f0 + (size_t)n * 6) : (f1 + (size_t)(n - NN) * 6);
    float xv[6];
#pragma unroll
    for (int k = 0; k < 6; k++) xv[k] = x[k];
    float4* o = (float4*)(fpk + (size_t)n * 8);
    o[0] = make_float4(xv[0], xv[1], xv[2], xv[3]);
    o[1] = make_float4(xv[4], xv[5], 0.f, 0.f);
    float4 elv, erv;
    float* ep = (float*)&elv;
    float* rp = (float*)&erv;
#pragma unroll
    for (int c = 0; c < 4; c++) {
        float sl = 0.f, sr = 0.f;
#pragma unroll
        for (int k = 0; k < 6; k++) {
            sl += xv[k] * F1[k * 8 + c];
            sr += xv[k] * F1[k * 8 + c + 4];
        }
        ep[c] = sl;
        rp[c] = sr;
    }
    *(float4*)(el + (size_t)n * 4) = elv;
    *(float4*)(er + (size_t)n * 4) = erv;
}

// Fused layer-1: one lane per node gathers + softmax-aggregates the 6-dim feats
// (vector el float4 + packed-feat float4x2, exp2 weights), then per-wave MFMA does the
// 32->128 W1 transform (bias folded via the 1.0 slot in sagg / b1 row in W1f).
__global__ __launch_bounds__(256) void agg1mfma_kernel(
        const float* __restrict__ fpk, const float* __restrict__ el,
        const float* __restrict__ er, const int* __restrict__ deg,
        const int* __restrict__ slots, const bf16* __restrict__ W1fg,
        bf16* __restrict__ xb) {
    __shared__ bf16 sW[128 * 40];     // [128 ch][32 k] padded to 40 (bank-conflict break)
    __shared__ bf16 sagg[256 * 40];   // [256 node][32 k] padded to 40
    int t = threadIdx.x;
    // stage W1f into padded LDS (one row = 64B = 4x uint4)
    if (t < 128) {
        const uint4* src = (const uint4*)(W1fg + t * 32);
        uint4* dstp = (uint4*)(sW + t * 40);
        dstp[0] = src[0]; dstp[1] = src[1]; dstp[2] = src[2]; dstp[3] = src[3];
    }

    // ---- phase 1: per-lane gather softmax-aggregate ----
    int node = blockIdx.x * 256 + t;
    int dg = deg[node];
    dg = (dg > CAP) ? CAP : dg;
    float4 er4 = *(const float4*)(er + (size_t)node * 4);
    const int* sp = slots + (size_t)node * CAP;
    float a0[4], a1[4], a2[4], a3[4], a4[4], a5[4], ss[4];
#pragma unroll
    for (int h = 0; h < 4; h++) {
        a0[h] = a1[h] = a2[h] = a3[h] = a4[h] = a5[h] = ss[h] = 0.f;
    }
    for (int p = 0; p < dg; p += 4) {
        int4 s4 = *(const int4*)(sp + p);
        int sarr[4] = {s4.x, s4.y, s4.z, s4.w};
#pragma unroll
        for (int k = 0; k < 4; k++) {
            bool vld = (p + k) < dg;
            int g = vld ? sarr[k] : s4.x;       // clamp: unread slots may be garbage
            float4 e4 = *(const float4*)(el + (size_t)g * 4);
            float4 xa = *(const float4*)(fpk + (size_t)g * 8);
            float4 xc = *(const float4*)(fpk + (size_t)g * 8 + 4);
            float eh[4] = {e4.x, e4.y, e4.z, e4.w};
            float rh[4] = {er4.x, er4.y, er4.z, er4.w};
#pragma unroll
            for (int h = 0; h < 4; h++) {
                float z = eh[h] + rh[h];
                float w = EXP2(fmaxf(z, 0.f) + NEG_SLOPE * fminf(z, 0.f));
                w = vld ? w : 0.f;
                ss[h] += w;
                a0[h] += w * xa.x; a1[h] += w * xa.y; a2[h] += w * xa.z;
                a3[h] += w * xa.w; a4[h] += w * xc.x; a5[h] += w * xc.y;
            }
        }
    }
#pragma unroll
    for (int h = 0; h < 4; h++) {
        float rs = (dg > 0) ? 1.f / ss[h] : 0.f;
        uint4 o;
        o.x = pkbf(a0[h] * rs, a1[h] * rs);
        o.y = pkbf(a2[h] * rs, a3[h] * rs);
        o.z = pkbf(a4[h] * rs, a5[h] * rs);
        o.w = 0x00003F80u;  // (1.0bf16, 0.0): bias slot k=h*8+6
        *(uint4*)(sagg + t * 40 + h * 8) = o;
    }
    __syncthreads();

    // ---- phase 2: per-wave MFMA, 64 nodes x 128 channels ----
    int wave = t >> 6, lane = t & 63;
    int mlane = lane & 15, quad = lane >> 4;
    short8 af[8];
#pragma unroll
    for (int j = 0; j < 8; j++)
        af[j] = *(const short8*)(sW + (j * 16 + mlane) * 40 + quad * 8);
    floatx4 z4 = (floatx4){0.f, 0.f, 0.f, 0.f};
#pragma unroll
    for (int nt = 0; nt < 4; nt++) {
        int lrow = wave * 64 + nt * 16 + mlane;
        short8 bfr = *(const short8*)(sagg + lrow * 40 + quad * 8);
        floatx4 c[8];
#pragma unroll
        for (int j = 0; j < 8; j++)
            c[j] = __builtin_amdgcn_mfma_f32_16x16x32_bf16(af[j], bfr, z4, 0, 0, 0);
        // D: col = mlane -> node, row = quad*4+r -> channel j*16+quad*4+r
        bf16* op = xb + (size_t)(blockIdx.x * 256 + lrow) * 128 + quad * 4;
#pragma unroll
        for (int j = 0; j < 8; j++) {
            uint2 o;
            o.x = pkbf(fmaxf(c[j][0], 0.f), fmaxf(c[j][1], 0.f));
            o.y = pkbf(fmaxf(c[j][2], 0.f), fmaxf(c[j][3], 0.f));
            *(uint2*)(op + j * 16) = o;
        }
    }
}

// ---------------- GAT kernels (merged over 2*NN) ----------------

// Phase-A helper (agg3pool only): lane = h*16+e computes alpha[e][h] + clamped src.
__device__ __forceinline__ void softmax_phaseA(const float* __restrict__ el,
                                               const float* __restrict__ er,
                                               const int* __restrict__ slots,
                                               int wid, int dg, int lane,
                                               float* alpha_out, int* src_out) {
    int e = lane & 15, h = lane >> 4;
    int sA = slots[(size_t)wid * CAP + e];
    int sAc = (e < dg) ? sA : 0;                 // clamp: poisoned slots are unsafe addrs
    float erh = er[wid * 4 + h];
    float elv = el[sAc * 4 + h];
    float w = (e < dg) ? __expf(leaky(elv + erh)) : 0.f;
    float ssum = w;
    ssum += __shfl_xor(ssum, 1, 64);
    ssum += __shfl_xor(ssum, 2, 64);
    ssum += __shfl_xor(ssum, 4, 64);
    ssum += __shfl_xor(ssum, 8, 64);
    *alpha_out = (dg > 0) ? w * (1.f / ssum) : 0.f;   // 0 for e>=dg (w=0)
    *src_out = sAc;
}

// layer-2 agg (R13 structure): 32 lanes/node, inline per-lane-head softmax,
// 4-edge batch (4 loads in flight), 4B fp8 loads, HW cvt.
__global__ void agg2_kernel(const unsigned char* __restrict__ h8, const float* __restrict__ el,
                            const float* __restrict__ er, const int* __restrict__ deg,
                            const int* __restrict__ slots, const float* __restrict__ bias,
                            bf16* __restrict__ out) {
    int t = blockIdx.x * blockDim.x + threadIdx.x;
    int wid = t >> 5;                // [0, 2*NN)
    int gl = threadIdx.x & 31;
    int dg = deg[wid];
    dg = (dg > CAP) ? CAP : dg;
    int head = gl >> 3;
    int fbase = gl * 4;
    float erh = er[wid * 4 + head];
    const int* sp = slots + (size_t)wid * CAP;
    float a0 = 0.f, a1 = 0.f, a2 = 0.f, a3 = 0.f, ssum = 0.f;

    for (int p = 0; p < dg; p += 4) {
        int4 s4 = *(const int4*)(sp + p);
        int s[4]; bool v[4];
        s[0] = s4.x; v[0] = true;
        v[1] = p + 1 < dg; s[1] = v[1] ? s4.y : s4.x;
        v[2] = p + 2 < dg; s[2] = v[2] ? s4.z : s4.x;
        v[3] = p + 3 < dg; s[3] = v[3] ? s4.w : s4.x;
        float elv[4]; unsigned u1[4];
#pragma unroll
        for (int k = 0; k < 4; k++) {
            elv[k] = el[s[k] * 4 + head];
            u1[k] = *(const unsigned*)(h8 + (size_t)s[k] * 128 + fbase);
        }
#pragma unroll
        for (int k = 0; k < 4; k++) {
            float w = v[k] ? __expf(leaky(elv[k] + erh)) : 0.f;
            ssum += w;
            floatx2 lo = __builtin_amdgcn_cvt_pk_f32_fp8((int)u1[k], false);
            floatx2 hi = __builtin_amdgcn_cvt_pk_f32_fp8((int)u1[k], true);
            a0 += w * lo[0]; a1 += w * lo[1];
            a2 += w * hi[0]; a3 += w * hi[1];
        }
    }
    float rs = (dg > 0) ? 1.f / ssum : 0.f;
    float4 bbv = *(const float4*)(bias + fbase);
    float v0 = fmaxf(a0 * rs + bbv.x, 0.f), v1 = fmaxf(a1 * rs + bbv.y, 0.f);
    float v2 = fmaxf(a2 * rs + bbv.z, 0.f), v3 = fmaxf(a3 * rs + bbv.w, 0.f);
    uint2 uo;
    uo.x = (unsigned)f2bf(v0) | ((unsigned)f2bf(v1) << 16);
    uo.y = (unsigned)f2bf(v2) | ((unsigned)f2bf(v3) << 16);
    *(uint2*)(out + (size_t)wid * 128 + fbase) = uo;
}

// layer-3 agg fused with graph mean-pool (R2 structure: 8 sequential nodes/group,
// high occupancy). R4: per-edge-quad cross-lane broadcast via small-LDS
// (2 ds_read vector broadcasts) instead of 8 ds_bpermute per lane.
__global__ void agg3pool_kernel(const unsigned char* __restrict__ h8,
                                const float* __restrict__ el, const float* __restrict__ er,
                                const int* __restrict__ deg, const int* __restrict__ slots,
                                const float* __restrict__ bias, bf16* __restrict__ pair) {
    __shared__ float red[4 * 256];       // 4 KB
    __shared__ float salpha[4][64];      // 1 KB   [grp][h*16+e]
    __shared__ int   ssrc[4][16];        // 256 B  [grp][e]
    int side = blockIdx.x >> 12;         // 8192 blocks: side*4096 + b
    int b = blockIdx.x & 4095;
    int nodebase = side * NN + b * 32;
    int grp = threadIdx.x >> 6, lane = threadIdx.x & 63;
    int e = lane & 15, h = lane >> 4;
    int fbase = lane * 4;                // feature channel block
    float p0 = 0.f, p1 = 0.f, p2 = 0.f, p3 = 0.f;

    for (int nn = 0; nn < 8; nn++) {
        int wid = nodebase + grp * 8 + nn;
        int dg = deg[wid];
        dg = (dg > CAP) ? CAP : dg;
        float alpha; int sAc;
        softmax_phaseA(el, er, slots, wid, dg, lane, &alpha, &sAc);
        salpha[grp][lane] = alpha;           // per-h alpha vector
        if (h == 0) ssrc[grp][e] = sAc;      // clamped src (0 for e>=dg)
        // same-wave LDS RAW: DS pipe is wave-ordered, no barrier needed
        for (int p = 0; p < dg; p += 4) {
            int4 sc4 = *(const int4*)&ssrc[grp][p];            // broadcast
            float4 av4 = *(const float4*)&salpha[grp][h * 16 + p];
            unsigned u[4];
            u[0] = *(const unsigned*)(h8 + (size_t)sc4.x * 256 + fbase);
            u[1] = *(const unsigned*)(h8 + (size_t)sc4.y * 256 + fbase);
            u[2] = *(const unsigned*)(h8 + (size_t)sc4.z * 256 + fbase);
            u[3] = *(const unsigned*)(h8 + (size_t)sc4.w * 256 + fbase);
            float av[4] = {av4.x, av4.y, av4.z, av4.w};
#pragma unroll
            for (int k = 0; k < 4; k++) {
                floatx2 lo = __builtin_amdgcn_cvt_pk_f32_fp8((int)u[k], false);
                floatx2 hi = __builtin_amdgcn_cvt_pk_f32_fp8((int)u[k], true);
                p0 += av[k] * lo[0]; p1 += av[k] * lo[1];
                p2 += av[k] * hi[0]; p3 += av[k] * hi[1];
            }
        }
    }
    red[grp * 256 + fbase + 0] = p0;
    red[grp * 256 + fbase + 1] = p1;
    red[grp * 256 + fbase + 2] = p2;
    red[grp * 256 + fbase + 3] = p3;
    __syncthreads();
    if (grp == 0) {
        float4 bbv = *(const float4*)(bias + fbase);
        float s0 = 0.f, s1 = 0.f, s2 = 0.f, s3 = 0.f;
#pragma unroll
        for (int g = 0; g < 4; g++) {
            s0 += red[g * 256 + fbase + 0];
            s1 += red[g * 256 + fbase + 1];
            s2 += red[g * 256 + fbase + 2];
            s3 += red[g * 256 + fbase + 3];
        }
        const float inv = 1.0f / 32.0f;
        float v0 = s0 * inv + bbv.x, v1 = s1 * inv + bbv.y;
        float v2 = s2 * inv + bbv.z, v3 = s3 * inv + bbv.w;
        uint2 uo;
        uo.x = (unsigned)f2bf(v0) | ((unsigned)f2bf(v1) << 16);
        uo.y = (unsigned)f2bf(v2) | ((unsigned)f2bf(v3) << 16);
        *(uint2*)(pair + (size_t)b * 512 + side * 256 + fbase) = uo;
    }
}

// ---------------- MFMA bf16 GEMM: out[M,C] = A[M,K] @ Wt[C,K]^T (+bias)(+relu) ----------------
template <bool FOLD, bool OUT8>
__global__ __launch_bounds__(256) void mgemm_kernel(const bf16* __restrict__ A,
                                                    const bf16* __restrict__ Wt,
                                                    const float* __restrict__ bias,
                                                    void* __restrict__ out,
                                                    int K, int C, int relu,
                                                    const bf16* __restrict__ Ff,
                                                    float* __restrict__ el,
                                                    float* __restrict__ er) {
    __shared__ short As[128 * 48];
    __shared__ short Bs[128 * 48];
    int t = threadIdx.x;
    int wave = t >> 6, lane = t & 63;
    int wm = (wave >> 1) * 64, wn = (wave & 1) * 64;
    int bm = blockIdx.x * 128, bn = blockIdx.y * 128;
    int m_lane = lane & 15, quad = lane >> 4;
    bool dofold = FOLD && (blockIdx.y == 0) && (wn == 0);

    floatx4 acc[4][4];
#pragma unroll
    for (int i = 0; i < 4; i++)
#pragma unroll
        for (int j = 0; j < 4; j++) acc[i][j] = (floatx4){0.f, 0.f, 0.f, 0.f};
    floatx4 facc[4];
    if (FOLD) {
#pragma unroll
        for (int i = 0; i < 4; i++) facc[i] = (floatx4){0.f, 0.f, 0.f, 0.f};
    }

    int lrow = t >> 2, lq = t & 3;
    for (int k0 = 0; k0 < K; k0 += 32) {
        __syncthreads();
#pragma unroll
        for (int pass = 0; pass < 2; pass++) {
            int row = lrow + pass * 64;
            *(short8*)&As[row * 48 + lq * 8] =
                *(const short8*)(A + (size_t)(bm + row) * K + k0 + lq * 8);
            *(short8*)&Bs[row * 48 + lq * 8] =
                *(const short8*)(Wt + (size_t)(bn + row) * K + k0 + lq * 8);
        }
        __syncthreads();
        short8 af[4], bf[4];
#pragma unroll
        for (int i = 0; i < 4; i++)
            af[i] = *(const short8*)&As[(wm + i * 16 + m_lane) * 48 + quad * 8];
#pragma unroll
        for (int j = 0; j < 4; j++)
            bf[j] = *(const short8*)&Bs[(wn + j * 16 + m_lane) * 48 + quad * 8];
        if (dofold) {
            short8 fbv = *(const short8*)(Ff + m_lane * K + k0 + quad * 8);
#pragma unroll
            for (int i = 0; i < 4; i++)
                facc[i] = __builtin_amdgcn_mfma_f32_16x16x32_bf16(af[i], fbv, facc[i], 0, 0, 0);
        }
#pragma unroll
        for (int i = 0; i < 4; i++)
#pragma unroll
            for (int j = 0; j < 4; j++)
                acc[i][j] = __builtin_amdgcn_mfma_f32_16x16x32_bf16(af[i], bf[j], acc[i][j], 0, 0, 0);
    }

#pragma unroll
    for (int i = 0; i < 4; i++) {
#pragma unroll
        for (int j = 0; j < 4; j++) {
            int gc = bn + wn + j * 16 + m_lane;
            float bbv = bias ? bias[gc] : 0.f;
#pragma unroll
            for (int r = 0; r < 4; r++) {
                int gr = bm + wm + i * 16 + quad * 4 + r;
                float v = acc[i][j][r] + bbv;
                if (relu) v = fmaxf(v, 0.f);
                if (OUT8) ((unsigned char*)out)[(size_t)gr * C + gc] = ftofp8(v);
                else      ((bf16*)out)[(size_t)gr * C + gc] = f2bf(v);
            }
        }
    }
    if (dofold && m_lane < 8) {
        float* dst = (m_lane < 4) ? el : er;
        int hh = m_lane & 3;
#pragma unroll
        for (int i = 0; i < 4; i++)
#pragma unroll
            for (int r = 0; r < 4; r++) {
                int gr = bm + wm + i * 16 + quad * 4 + r;
                dst[gr * 4 + hh] = facc[i][r];
            }
    }
}

// ---------------- fp32 512x512x512 GEMM (weight combine, prep-time) ----------------
__global__ __launch_bounds__(256) void fgemm512_kernel(const float* __restrict__ A,
                                                       const float* __restrict__ B,
                                                       float* __restrict__ C) {
    const int BK = 16;
    __shared__ float As[BK][68];
    __shared__ float Bs[BK][68];
    int t = threadIdx.x;
    int bm = blockIdx.x * 64, bn = blockIdx.y * 64;
    int tm0 = (t & 15) * 4, tn0 = (t >> 4) * 4;
    float acc[4][4] = {};
    int la_m = t >> 2, la_k = (t & 3) * 4;
    int lb_k = t >> 4, lb_c = (t & 15) * 4;

    for (int k0 = 0; k0 < 512; k0 += BK) {
        float4 a4 = *(const float4*)(A + (size_t)(bm + la_m) * 512 + k0 + la_k);
        float4 b4 = *(const float4*)(B + (size_t)(k0 + lb_k) * 512 + bn + lb_c);
        As[la_k + 0][la_m] = a4.x; As[la_k + 1][la_m] = a4.y;
        As[la_k + 2][la_m] = a4.z; As[la_k + 3][la_m] = a4.w;
        *(float4*)&Bs[lb_k][lb_c] = b4;
        __syncthreads();
#pragma unroll
        for (int k = 0; k < BK; k++) {
            float4 av = *(const float4*)&As[k][tm0];
            float4 bv = *(const float4*)&Bs[k][tn0];
            acc[0][0] += av.x * bv.x; acc[0][1] += av.x * bv.y; acc[0][2] += av.x * bv.z; acc[0][3] += av.x * bv.w;
            acc[1][0] += av.y * bv.x; acc[1][1] += av.y * bv.y; acc[1][2] += av.y * bv.z; acc[1][3] += av.y * bv.w;
            acc[2][0] += av.z * bv.x; acc[2][1] += av.z * bv.y; acc[2][2] += av.z * bv.z; acc[2][3] += av.z * bv.w;
            acc[3][0] += av.w * bv.x; acc[3][1] += av.w * bv.y; acc[3][2] += av.w * bv.z; acc[3][3] += av.w * bv.w;
        }
        __syncthreads();
    }
#pragma unroll
    for (int i = 0; i < 4; i++) {
        float4 o = make_float4(acc[i][0], acc[i][1], acc[i][2], acc[i][3]);
        *(float4*)(C + (size_t)(bm + tm0 + i) * 512 + bn + tn0) = o;
    }
}

__global__ void biasstep_kernel(const float* __restrict__ vin, const float* __restrict__ M,
                                const float* __restrict__ badd, float* __restrict__ vout) {
    int c = blockIdx.x * blockDim.x + threadIdx.x;
    float s = 0.f;
    for (int k = 0; k < 512; k++) s += vin[k] * M[(size_t)k * 512 + c];
    vout[c] = s + badd[c];
}

// ---------------- fusion tail ----------------

__global__ void ln_kernel(const bf16* __restrict__ attn, const bf16* __restrict__ lp,
                          const float* __restrict__ gamma, const float* __restrict__ beta,
                          bf16* __restrict__ out) {
    __shared__ float red[256];
    int b = blockIdx.x, t = threadIdx.x;
    size_t base = (size_t)b * 512;
    float x0 = bf2f(attn[base + t]) + bf2f(lp[base + t]);
    float x1 = bf2f(attn[base + 256 + t]) + bf2f(lp[base + 256 + t]);
    red[t] = x0 + x1; __syncthreads();
    for (int off = 128; off > 0; off >>= 1) { if (t < off) red[t] += red[t + off]; __syncthreads(); }
    float mu = red[0] * (1.0f / 512.0f);
    __syncthreads();
    float d0 = x0 - mu, d1 = x1 - mu;
    red[t] = d0 * d0 + d1 * d1; __syncthreads();
    for (int off = 128; off > 0; off >>= 1) { if (t < off) red[t] += red[t + off]; __syncthreads(); }
    float rstd = rsqrtf(red[0] * (1.0f / 512.0f) + LN_EPS);
    out[base + t]       = f2bf(d0 * rstd * gamma[t] + beta[t]);
    out[base + 256 + t] = f2bf(d1 * rstd * gamma[256 + t] + beta[256 + t]);
}

__global__ void cls2_kernel(const bf16* __restrict__ hc, const float* __restrict__ Wc2,
                            const float* __restrict__ bc2, float* __restrict__ out) {
    int wid = (blockIdx.x * blockDim.x + threadIdx.x) >> 6;
    int lane = threadIdx.x & 63;
    if (wid >= NB) return;
    float s = 0.f;
#pragma unroll
    for (int j = 0; j < 4; j++) {
        int k = lane + 64 * j;
        s += bf2f(hc[(size_t)wid * 256 + k]) * Wc2[k];
    }
    for (int off = 32; off > 0; off >>= 1) s += __shfl_down(s, off);
    if (lane == 0) {
        float v = s + bc2[0];
        out[wid] = 1.0f / (1.0f + __expf(-v));
    }
}

// ---------------- launch ----------------

static inline size_t alup(size_t x) { return (x + 255) & ~(size_t)255; }

extern "C" void kernel_launch(void* const* d_in, const int* in_sizes, int n_in,
                              void* d_out, int out_size, void* d_ws, size_t ws_size,
                              hipStream_t stream) {
    const float* feat0 = (const float*)d_in[0];
    const float* feat1 = (const float*)d_in[1];
    const float* llm = (const float*)d_in[2];
    const int* srcs[2] = {(const int*)d_in[3], (const int*)d_in[5]};
    const int* dsts[2] = {(const int*)d_in[4], (const int*)d_in[6]};
    const float* W1 = (const float*)d_in[8];
    const float* al[3] = {(const float*)d_in[9],  (const float*)d_in[13], (const float*)d_in[17]};
    const float* ar[3] = {(const float*)d_in[10], (const float*)d_in[14], (const float*)d_in[18]};
    const float* bb[3] = {(const float*)d_in[11], (const float*)d_in[15], (const float*)d_in[19]};
    const float* W2 = (const float*)d_in[12];
    const float* W3 = (const float*)d_in[16];
    const float* Wpg = (const float*)d_in[20]; const float* bpg = (const float*)d_in[21];
    const float* Wpl = (const float*)d_in[22]; const float* bpl = (const float*)d_in[23];
    const float* Wv  = (const float*)d_in[24]; const float* bv  = (const float*)d_in[25];
    const float* Wo  = (const float*)d_in[26]; const float* bo  = (const float*)d_in[27];
    const float* gamma = (const float*)d_in[28]; const float* beta = (const float*)d_in[29];
    const float* Wc1 = (const float*)d_in[30]; const float* bc1 = (const float*)d_in[31];
    const float* Wc2 = (const float*)d_in[32]; const float* bc2 = (const float*)d_in[33];
    float* outp = (float*)d_out;

    const size_t N2 = (size_t)2 * NN;

    // workspace carve (~138 MiB)
    char* p = (char*)d_ws;
    auto take = [&](size_t bytes) { char* r = p; p += alup(bytes); return r; };
    bf16*  xb     = (bf16*)take(N2 * 128 * 2);        // A: 64 MiB (layer-1/2 activations)
    char*  regB   = (char*)take(N2 * 256);            // B: 64 MiB (cells+counts / fpk / hb2 / hb3 / tail)
    float* el     = (float*)take(N2 * 4 * 4);         // 4 MiB
    float* er     = (float*)take(N2 * 4 * 4);         // 4 MiB
    int*   deg    = (int*)take(N2 * 4);               // 1 MiB
    int*   slots  = (int*)take(N2 * CAP * 4);         // 16.8 MiB
    bf16*  pair   = (bf16*)take((size_t)NB * 512 * 2);
    bf16*  llm_bf = (bf16*)take((size_t)NB * 1024 * 2); // 8 MiB
    bf16*  W2t  = (bf16*)take(128 * 128 * 2);
    bf16*  W3t  = (bf16*)take(128 * 256 * 2);
    bf16*  Wplt = (bf16*)take(1024 * 512 * 2);
    bf16*  Wc1t = (bf16*)take(512 * 256 * 2);
    bf16*  Wcot = (bf16*)take(512 * 512 * 2);
    float* F1   = (float*)take(6 * 8 * 4);
    bf16*  Ff2  = (bf16*)take(16 * 128 * 2);
    bf16*  Ff3  = (bf16*)take(16 * 128 * 2);
    bf16*  W1fg = (bf16*)take(128 * 32 * 2);          // 8 KiB layer-1 MFMA weight
    float* c1   = (float*)take(512 * 512 * 4);
    float* c2   = (float*)take(512 * 512 * 4);
    float* bias1 = (float*)take(512 * 4);
    float* bco   = (float*)take(512 * 4);
    // region B aliases (sequential lifetimes):
    unsigned* cells = (unsigned*)regB;                // [NBKT][NBLK1][CELL_CAP] 25 MiB (pre-fpk)
    int* counts = (int*)(regB + (size_t)NBKT * NBLK1 * CELL_CAP * 4);  // 1 MiB
    float* fpk          = (float*)regB;               // packed feats [2NN][8] (8.4 MiB, pre-L2)
    unsigned char* hb2  = (unsigned char*)regB;       // layer-2 features fp8 [2NN,128] (32 MiB)
    unsigned char* hb3  = (unsigned char*)regB;       // layer-3 features fp8 [2NN,256] (64 MiB)
    bf16* fbb   = (bf16*)regB;                        // fusion-tail activations
    bf16* lp    = fbb + (size_t)0 * NB * 512;
    bf16* attn  = fbb + (size_t)1 * NB * 512;
    bf16* fused = fbb + (size_t)2 * NB * 512;
    bf16* hc    = fbb + (size_t)3 * NB * 512;
    (void)ws_size; (void)n_in; (void)in_sizes; (void)out_size;

    auto mgemm = [&](const bf16* A, const bf16* Wt, const float* bias, bf16* o,
                     int M, int K, int C, int relu) {
        dim3 g(M / 128, C / 128);
        mgemm_kernel<false, false><<<g, 256, 0, stream>>>(A, Wt, bias, o, K, C, relu,
                                                          nullptr, nullptr, nullptr);
    };

    // ---- slot bucketing first (cells alias region B, consumed before fpk) ----
    part_edges_kernel<<<NBLK1, 256, 0, stream>>>(srcs[0], dsts[0], srcs[1], dsts[1],
                                                 cells, counts);
    build_slots_kernel<<<NBKT, 256, 0, stream>>>(cells, counts, deg, slots);

    // ---- per-call preps ----
    prep_all_kernel<<<(PREP_TOTAL + 255) / 256, 256, 0, stream>>>(
        W2, W3, Wpl, Wc1, W1, al[0], ar[0], al[1], ar[1], al[2], ar[2], bb[0],
        W2t, W3t, Wplt, Wc1t, Ff2, Ff3, F1, W1fg);
    f2bf_kernel<<<NB * 1024 / 4 / 256, 256, 0, stream>>>(llm, llm_bf);
    {
        dim3 g8(8, 8);
        fgemm512_kernel<<<g8, 256, 0, stream>>>(Wpg, Wv, c1);
        fgemm512_kernel<<<g8, 256, 0, stream>>>(c1, Wo, c2);
        wt_kernel<<<(512 * 512 + 255) / 256, 256, 0, stream>>>(c2, Wcot, 512, 512);
        biasstep_kernel<<<2, 256, 0, stream>>>(bpg, Wv, bv, bias1);
        biasstep_kernel<<<2, 256, 0, stream>>>(bias1, Wo, bo, bco);
    }

    // ---- GNN, both sides merged ----
    featelr_kernel<<<2 * NN / 256, 256, 0, stream>>>(feat0, feat1, F1, fpk, el, er);
    agg1mfma_kernel<<<2 * NN / 256, 256, 0, stream>>>(fpk, el, er, deg, slots, W1fg, xb);
    {
        dim3 g(2 * NN / 128, 1);
        mgemm_kernel<true, true><<<g, 256, 0, stream>>>(xb, W2t, nullptr, hb2, 128, 128, 0,
                                                        Ff2, el, er);
    }
    agg2_kernel<<<2 * NN * 32 / 256, 256, 0, stream>>>(hb2, el, er, deg, slots, bb[1], xb);
    {
        dim3 g(2 * NN / 128, 2);
        mgemm_kernel<true, true><<<g, 256, 0, stream>>>(xb, W3t, nullptr, hb3, 128, 256, 0,
                                                        Ff3, el, er);
    }
    agg3pool_kernel<<<2 * NB, 256, 0, stream>>>(hb3, el, er, deg, slots, bb[2], pair);

    // ---- fusion tail (activations alias region B) ----
    mgemm(llm_bf, Wplt, bpl, lp, NB, 1024, 512, 0);
    mgemm(pair, Wcot, bco, attn, NB, 512, 512, 0);
    ln_kernel<<<NB, 256, 0, stream>>>(attn, lp, gamma, beta, fused);
    mgemm(fused, Wc1t, bc1, hc, NB, 512, 256, 1);
    cls2_kernel<<<NB / 4, 256, 0, stream>>>(hc, Wc2, bc2, outp);
}

// Round 6
// 570.941 us; speedup vs baseline: 1.0408x; 1.0206x over previous
//
#include <hip/hip_runtime.h>
#include <hip/hip_fp8.h>

#define NN 131072      // nodes per side
#define NE 524288      // edges per side
#define NB 4096        // graphs per side
#define CAP 16         // slot capacity = one 64B line/node
#define NEG_SLOPE 0.2f
#define LN_EPS 1e-5f
#define LOG2E 1.44269504088896f

// edge-partition geometry (atomic-free slot build)
#define NBKT 1024      // buckets of 256 nodes (2NN/256)
#define NBLK1 256      // phase-1 blocks
#define CELL_CAP 24    // per-(bucket,block) cell capacity (avg 4, Poisson tail ~1e-13)

typedef unsigned short bf16;
typedef __attribute__((ext_vector_type(8))) short short8;
typedef __attribute__((ext_vector_type(4))) float floatx4;
typedef __attribute__((ext_vector_type(2))) float floatx2;

#if __has_builtin(__builtin_amdgcn_exp2f)
#define EXP2(x) __builtin_amdgcn_exp2f(x)
#else
#define EXP2(x) exp2f(x)
#endif

__device__ __forceinline__ float bf2f(bf16 h) {
    return __uint_as_float((unsigned)h << 16);
}
__device__ __forceinline__ bf16 f2bf(float f) {
    unsigned u = __float_as_uint(f);
    unsigned r = (u + 0x7FFFu + ((u >> 16) & 1u)) >> 16;
    return (bf16)r;
}
// HW packed bf16 pair encode (RNE, same unit the compiler uses for bf16 casts)
__device__ __forceinline__ unsigned pkbf(float lo, float hi) {
    unsigned r;
    asm("v_cvt_pk_bf16_f32 %0, %1, %2" : "=v"(r) : "v"(lo), "v"(hi));
    return r;
}
// HW packed fp8(e4m3) encode
__device__ __forceinline__ unsigned char ftofp8(float f) {
    return (unsigned char)(__builtin_amdgcn_cvt_pk_fp8_f32(f, f, 0, false) & 0xFF);
}
__device__ __forceinline__ float leaky(float x) {
    return fmaxf(x, 0.f) + NEG_SLOPE * fminf(x, 0.f);
}

// ---------------- atomic-free slot build (two-phase partition) ----------------
// Phase 1: bin edges into block-private cells via LDS histogram (no global atomics;
//          cell lines are block-private -> no cross-XCD ping-pong).
__global__ __launch_bounds__(256) void part_edges_kernel(
        const int* __restrict__ s0, const int* __restrict__ d0,
        const int* __restrict__ s1, const int* __restrict__ d1,
        unsigned* __restrict__ cells, int* __restrict__ counts) {
    __shared__ int lcnt[NBKT];       // 4 KB
    int blk = blockIdx.x, t = threadIdx.x;
    for (int i = t; i < NBKT; i += 256) lcnt[i] = 0;
    __syncthreads();
    int side = blk >= (NBLK1 / 2);               // 128 blocks per side
    const int4* dp = (const int4*)(side ? d1 : d0);
    const int4* sp = (const int4*)(side ? s1 : s0);
    int base4 = (blk - side * (NBLK1 / 2)) * 1024;
    int gbase = side * NN;
#pragma unroll
    for (int it = 0; it < 4; it++) {
        int e4 = base4 + it * 256 + t;           // [0, NE/4)
        int4 dd = dp[e4];
        int4 ss = sp[e4];
        int d[4] = {gbase + dd.x, gbase + dd.y, gbase + dd.z, gbase + dd.w};
        int s[4] = {gbase + ss.x, gbase + ss.y, gbase + ss.z, gbase + ss.w};
#pragma unroll
        for (int k = 0; k < 4; k++) {
            int b = d[k] >> 8;
            int r = atomicAdd(&lcnt[b], 1);      // LDS atomic
            if (r < CELL_CAP)
                cells[((size_t)b * NBLK1 + blk) * CELL_CAP + r] =
                    ((unsigned)s[k] << 8) | (unsigned)(d[k] & 255);
        }
    }
    __syncthreads();
    for (int i = t; i < NBKT; i += 256) {
        int c = lcnt[i];
        counts[i * NBLK1 + blk] = (c > CELL_CAP) ? CELL_CAP : c;
    }
}

// Phase 2: one block per bucket; build deg/slots for 256 nodes in LDS, write coalesced.
__global__ __launch_bounds__(256) void build_slots_kernel(
        const unsigned* __restrict__ cells, const int* __restrict__ counts,
        int* __restrict__ deg, int* __restrict__ slots) {
    __shared__ int ldeg[256];                    // 1 KB
    __shared__ int lslot[256 * CAP];             // 16 KB
    int b = blockIdx.x, t = threadIdx.x;
    ldeg[t] = 0;
    for (int i = t; i < 256 * CAP; i += 256) lslot[i] = 0;
    __syncthreads();
    // thread t consumes cell t of this bucket
    int cnt = counts[b * NBLK1 + t];
    const unsigned* cp = cells + ((size_t)b * NBLK1 + t) * CELL_CAP;
    for (int i = 0; i < cnt; i++) {
        unsigned v = cp[i];
        int d = v & 255;
        int s = (int)(v >> 8);
        int p = atomicAdd(&ldeg[d], 1);          // LDS atomic
        if (p < CAP) lslot[d * CAP + p] = s;
    }
    __syncthreads();
    int node0 = b * 256;
    deg[node0 + t] = ldeg[t];
    for (int i = t; i < 256 * CAP; i += 256)
        slots[(size_t)node0 * CAP + i] = lslot[i];
}

// ---------------- merged weight prep ----------------
// W2t + Wplt + Wc1t + Ff2 + Ff3 + F1 + W1f + W3bdt
#define PREP_TOTAL (16384 + 524288 + 131072 + 2048 + 2048 + 48 + 4096 + 131072)

__global__ void prep_all_kernel(const float* __restrict__ W2, const float* __restrict__ W3,
                                const float* __restrict__ Wpl, const float* __restrict__ Wc1,
                                const float* __restrict__ W1,
                                const float* __restrict__ al1, const float* __restrict__ ar1,
                                const float* __restrict__ al2, const float* __restrict__ ar2,
                                const float* __restrict__ al3, const float* __restrict__ ar3,
                                const float* __restrict__ b1v,
                                bf16* __restrict__ W2t, bf16* __restrict__ Wplt,
                                bf16* __restrict__ Wc1t,
                                bf16* __restrict__ Ff2, bf16* __restrict__ Ff3,
                                float* __restrict__ F1, bf16* __restrict__ W1f,
                                bf16* __restrict__ W3bdt) {
    int i = blockIdx.x * blockDim.x + threadIdx.x;
    if (i < 16384) {  // W2t: K=128,C=128
        int c = i >> 7, k = i & 127;
        W2t[i] = f2bf(W2[k * 128 + c]);
        return;
    }
    i -= 16384;
    if (i < 524288) {  // Wplt: K=1024,C=512
        int c = i >> 10, k = i & 1023;
        Wplt[i] = f2bf(Wpl[k * 512 + c]);
        return;
    }
    i -= 524288;
    if (i < 131072) {  // Wc1t: K=512,C=256
        int c = i >> 9, k = i & 511;
        Wc1t[i] = f2bf(Wc1[k * 256 + c]);
        return;
    }
    i -= 131072;
    if (i < 2048) {  // Ff2: Kin=128, Dh=32
        int c = i >> 7, k = i & 127;
        float s = 0.f;
        if (c < 8) {
            const float* a = (c < 4) ? al2 : ar2;
            int hh = c & 3;
            for (int d = 0; d < 32; d++) s += W2[k * 128 + hh * 32 + d] * a[hh * 32 + d];
        }
        Ff2[i] = f2bf(s);
        return;
    }
    i -= 2048;
    if (i < 2048) {  // Ff3: Kin=128, Dh=64 (layer-3 attn fold applied to x2)
        int c = i >> 7, k = i & 127;
        float s = 0.f;
        if (c < 8) {
            const float* a = (c < 4) ? al3 : ar3;
            int hh = c & 3;
            for (int d = 0; d < 64; d++) s += W3[k * 256 + hh * 64 + d] * a[hh * 64 + d];
        }
        Ff3[i] = f2bf(s);
        return;
    }
    i -= 2048;
    if (i < 48) {  // F1: layer-1 fold (fp32, K=6), pre-scaled by log2(e) so agg1 uses exp2
        int k = i >> 3, c = i & 7;
        const float* a = (c < 4) ? al1 : ar1;
        int hh = c & 3;
        float s = 0.f;
        for (int d = 0; d < 32; d++) s += W1[k * 128 + hh * 32 + d] * a[hh * 32 + d];
        F1[k * 8 + c] = s * LOG2E;
        return;
    }
    i -= 48;
    if (i < 4096) {  // W1f: [C=128][K=32], k = h*8+d; slot d==6 carries bias (pairs with 1.0)
        int c = i >> 5, k = i & 31;
        int h = c >> 5, d = k & 7;
        float v = 0.f;
        if ((k >> 3) == h) {
            if (d < 6) v = W1[d * 128 + c];
            else if (d == 6) v = b1v[c];
        }
        W1f[i] = f2bf(v);
        return;
    }
    i -= 4096;
    if (i < 131072) {  // W3bdt: block-diag W3^T [C=256][K=512]; r = h*128+k active iff h==c>>6
        int c = i >> 9, r = i & 511;
        int hr = r >> 7, k = r & 127;
        float v = (hr == (c >> 6)) ? W3[k * 256 + c] : 0.f;
        W3bdt[i] = f2bf(v);
    }
}

__global__ void f2bf_kernel(const float* __restrict__ x, bf16* __restrict__ y) {
    int i = blockIdx.x * blockDim.x + threadIdx.x;
    float4 v = ((const float4*)x)[i];
    ushort4 u;
    u.x = f2bf(v.x); u.y = f2bf(v.y); u.z = f2bf(v.z); u.w = f2bf(v.w);
    ((ushort4*)y)[i] = u;
}

__global__ void wt_kernel(const float* __restrict__ W, bf16* __restrict__ Wt, int K, int C) {
    int i = blockIdx.x * blockDim.x + threadIdx.x;
    if (i >= K * C) return;
    int c = i / K, k = i - c * K;
    Wt[i] = f2bf(W[(size_t)k * C + c]);
}

// ---------------- layer-1 front end ----------------

// Fused: pack raw feats into padded [2NN][8] fp32 rows + compute el/er (log2e-scaled F1).
__global__ void featelr_kernel(const float* __restrict__ f0, const float* __restrict__ f1,
                               const float* __restrict__ F1, float* __restrict__ fpk,
                               float* __restrict__ el, float* __restrict__ er) {
    int n = blockIdx.x * blockDim.x + threadIdx.x;  // [0, 2*NN)
    const float* x = (n < NN) ? (f0 + (size_t)n * 6) : (f1 + (size_t)(n - NN) * 6);
    float xv[6];
#pragma unroll
    for (int k = 0; k < 6; k++) xv[k] = x[k];
    float4* o = (float4*)(fpk + (size_t)n * 8);
    o[0] = make_float4(xv[0], xv[1], xv[2], xv[3]);
    o[1] = make_float4(xv[4], xv[5], 0.f, 0.f);
    float4 elv, erv;
    float* ep = (float*)&elv;
    float* rp = (float*)&erv;
#pragma unroll
    for (int c = 0; c < 4; c++) {
        float sl = 0.f, sr = 0.f;
#pragma unroll
        for (int k = 0; k < 6; k++) {
            sl += xv[k] * F1[k * 8 + c];
            sr += xv[k] * F1[k * 8 + c + 4];
        }
        ep[c] = sl;
        rp[c] = sr;
    }
    *(float4*)(el + (size_t)n * 4) = elv;
    *(float4*)(er + (size_t)n * 4) = erv;
}

// Fused layer-1: one lane per node gathers + softmax-aggregates the 6-dim feats
// (vector el float4 + packed-feat float4x2, exp2 weights), then per-wave MFMA does the
// 32->128 W1 transform (bias folded via the 1.0 slot in sagg / b1 row in W1f).
__global__ __launch_bounds__(256) void agg1mfma_kernel(
        const float* __restrict__ fpk, const float* __restrict__ el,
        const float* __restrict__ er, const int* __restrict__ deg,
        const int* __restrict__ slots, const bf16* __restrict__ W1fg,
        bf16* __restrict__ xb) {
    __shared__ bf16 sW[128 * 40];     // [128 ch][32 k] padded to 40 (bank-conflict break)
    __shared__ bf16 sagg[256 * 40];   // [256 node][32 k] padded to 40
    int t = threadIdx.x;
    // stage W1f into padded LDS (one row = 64B = 4x uint4)
    if (t < 128) {
        const uint4* src = (const uint4*)(W1fg + t * 32);
        uint4* dstp = (uint4*)(sW + t * 40);
        dstp[0] = src[0]; dstp[1] = src[1]; dstp[2] = src[2]; dstp[3] = src[3];
    }

    // ---- phase 1: per-lane gather softmax-aggregate ----
    int node = blockIdx.x * 256 + t;
    int dg = deg[node];
    dg = (dg > CAP) ? CAP : dg;
    float4 er4 = *(const float4*)(er + (size_t)node * 4);
    const int* sp = slots + (size_t)node * CAP;
    float a0[4], a1[4], a2[4], a3[4], a4[4], a5[4], ss[4];
#pragma unroll
    for (int h = 0; h < 4; h++) {
        a0[h] = a1[h] = a2[h] = a3[h] = a4[h] = a5[h] = ss[h] = 0.f;
    }
    for (int p = 0; p < dg; p += 4) {
        int4 s4 = *(const int4*)(sp + p);
        int sarr[4] = {s4.x, s4.y, s4.z, s4.w};
#pragma unroll
        for (int k = 0; k < 4; k++) {
            bool vld = (p + k) < dg;
            int g = vld ? sarr[k] : s4.x;       // clamp: unread slots may be garbage
            float4 e4 = *(const float4*)(el + (size_t)g * 4);
            float4 xa = *(const float4*)(fpk + (size_t)g * 8);
            float4 xc = *(const float4*)(fpk + (size_t)g * 8 + 4);
            float eh[4] = {e4.x, e4.y, e4.z, e4.w};
            float rh[4] = {er4.x, er4.y, er4.z, er4.w};
#pragma unroll
            for (int h = 0; h < 4; h++) {
                float z = eh[h] + rh[h];
                float w = EXP2(fmaxf(z, 0.f) + NEG_SLOPE * fminf(z, 0.f));
                w = vld ? w : 0.f;
                ss[h] += w;
                a0[h] += w * xa.x; a1[h] += w * xa.y; a2[h] += w * xa.z;
                a3[h] += w * xa.w; a4[h] += w * xc.x; a5[h] += w * xc.y;
            }
        }
    }
#pragma unroll
    for (int h = 0; h < 4; h++) {
        float rs = (dg > 0) ? 1.f / ss[h] : 0.f;
        uint4 o;
        o.x = pkbf(a0[h] * rs, a1[h] * rs);
        o.y = pkbf(a2[h] * rs, a3[h] * rs);
        o.z = pkbf(a4[h] * rs, a5[h] * rs);
        o.w = 0x00003F80u;  // (1.0bf16, 0.0): bias slot k=h*8+6
        *(uint4*)(sagg + t * 40 + h * 8) = o;
    }
    __syncthreads();

    // ---- phase 2: per-wave MFMA, 64 nodes x 128 channels ----
    int wave = t >> 6, lane = t & 63;
    int mlane = lane & 15, quad = lane >> 4;
    short8 af[8];
#pragma unroll
    for (int j = 0; j < 8; j++)
        af[j] = *(const short8*)(sW + (j * 16 + mlane) * 40 + quad * 8);
    floatx4 z4 = (floatx4){0.f, 0.f, 0.f, 0.f};
#pragma unroll
    for (int nt = 0; nt < 4; nt++) {
        int lrow = wave * 64 + nt * 16 + mlane;
        short8 bfr = *(const short8*)(sagg + lrow * 40 + quad * 8);
        floatx4 c[8];
#pragma unroll
        for (int j = 0; j < 8; j++)
            c[j] = __builtin_amdgcn_mfma_f32_16x16x32_bf16(af[j], bfr, z4, 0, 0, 0);
        // D: col = mlane -> node, row = quad*4+r -> channel j*16+quad*4+r
        bf16* op = xb + (size_t)(blockIdx.x * 256 + lrow) * 128 + quad * 4;
#pragma unroll
        for (int j = 0; j < 8; j++) {
            uint2 o;
            o.x = pkbf(fmaxf(c[j][0], 0.f), fmaxf(c[j][1], 0.f));
            o.y = pkbf(fmaxf(c[j][2], 0.f), fmaxf(c[j][3], 0.f));
            *(uint2*)(op + j * 16) = o;
        }
    }
}

// ---------------- GAT kernels (merged over 2*NN) ----------------

// Phase-A helper (agg3pool only): lane = h*16+e computes alpha[e][h] + clamped src.
__device__ __forceinline__ void softmax_phaseA(const float* __restrict__ el,
                                               const float* __restrict__ er,
                                               const int* __restrict__ slots,
                                               int wid, int dg, int lane,
                                               float* alpha_out, int* src_out) {
    int e = lane & 15, h = lane >> 4;
    int sA = slots[(size_t)wid * CAP + e];
    int sAc = (e < dg) ? sA : 0;                 // clamp: poisoned slots are unsafe addrs
    float erh = er[wid * 4 + h];
    float elv = el[sAc * 4 + h];
    float w = (e < dg) ? __expf(leaky(elv + erh)) : 0.f;
    float ssum = w;
    ssum += __shfl_xor(ssum, 1, 64);
    ssum += __shfl_xor(ssum, 2, 64);
    ssum += __shfl_xor(ssum, 4, 64);
    ssum += __shfl_xor(ssum, 8, 64);
    *alpha_out = (dg > 0) ? w * (1.f / ssum) : 0.f;   // 0 for e>=dg (w=0)
    *src_out = sAc;
}

// layer-2 agg (R13 structure): 32 lanes/node, inline per-lane-head softmax,
// 4-edge batch (4 loads in flight), 4B fp8 loads, HW cvt. R5: fp8 output (x2).
__global__ void agg2_kernel(const unsigned char* __restrict__ h8, const float* __restrict__ el,
                            const float* __restrict__ er, const int* __restrict__ deg,
                            const int* __restrict__ slots, const float* __restrict__ bias,
                            unsigned char* __restrict__ out) {
    int t = blockIdx.x * blockDim.x + threadIdx.x;
    int wid = t >> 5;                // [0, 2*NN)
    int gl = threadIdx.x & 31;
    int dg = deg[wid];
    dg = (dg > CAP) ? CAP : dg;
    int head = gl >> 3;
    int fbase = gl * 4;
    float erh = er[wid * 4 + head];
    const int* sp = slots + (size_t)wid * CAP;
    float a0 = 0.f, a1 = 0.f, a2 = 0.f, a3 = 0.f, ssum = 0.f;

    for (int p = 0; p < dg; p += 4) {
        int4 s4 = *(const int4*)(sp + p);
        int s[4]; bool v[4];
        s[0] = s4.x; v[0] = true;
        v[1] = p + 1 < dg; s[1] = v[1] ? s4.y : s4.x;
        v[2] = p + 2 < dg; s[2] = v[2] ? s4.z : s4.x;
        v[3] = p + 3 < dg; s[3] = v[3] ? s4.w : s4.x;
        float elv[4]; unsigned u1[4];
#pragma unroll
        for (int k = 0; k < 4; k++) {
            elv[k] = el[s[k] * 4 + head];
            u1[k] = *(const unsigned*)(h8 + (size_t)s[k] * 128 + fbase);
        }
#pragma unroll
        for (int k = 0; k < 4; k++) {
            float w = v[k] ? __expf(leaky(elv[k] + erh)) : 0.f;
            ssum += w;
            floatx2 lo = __builtin_amdgcn_cvt_pk_f32_fp8((int)u1[k], false);
            floatx2 hi = __builtin_amdgcn_cvt_pk_f32_fp8((int)u1[k], true);
            a0 += w * lo[0]; a1 += w * lo[1];
            a2 += w * hi[0]; a3 += w * hi[1];
        }
    }
    float rs = (dg > 0) ? 1.f / ssum : 0.f;
    float4 bbv = *(const float4*)(bias + fbase);
    float v0 = fmaxf(a0 * rs + bbv.x, 0.f), v1 = fmaxf(a1 * rs + bbv.y, 0.f);
    float v2 = fmaxf(a2 * rs + bbv.z, 0.f), v3 = fmaxf(a3 * rs + bbv.w, 0.f);
    unsigned w8 = (unsigned)__builtin_amdgcn_cvt_pk_fp8_f32(v0, v1, 0, false);
    w8 = (unsigned)__builtin_amdgcn_cvt_pk_fp8_f32(v2, v3, (int)w8, true);
    *(unsigned*)(out + (size_t)wid * 128 + fbase) = w8;
}

// layer-3 el/er from fp8 x2 via MFMA: el/er[n,h] = sum_k x2[n,k] * Ff3[c,k]
// (c<4 -> el head c, c in 4..8 -> er head c-4). 16 nodes per wave-mfma.
__global__ __launch_bounds__(256) void elr3_kernel(const unsigned char* __restrict__ x8,
                                                   const bf16* __restrict__ Ff3,
                                                   float* __restrict__ el,
                                                   float* __restrict__ er) {
    int wave = threadIdx.x >> 6, lane = threadIdx.x & 63;
    int mlane = lane & 15, quad = lane >> 4;
    int node0 = blockIdx.x * 64 + wave * 16;
    floatx4 acc = (floatx4){0.f, 0.f, 0.f, 0.f};
#pragma unroll
    for (int kb = 0; kb < 4; kb++) {
        short8 bfr = *(const short8*)(Ff3 + mlane * 128 + kb * 32 + quad * 8);
        uint2 u8 = *(const uint2*)(x8 + (size_t)(node0 + mlane) * 128 + kb * 32 + quad * 8);
        floatx2 f01 = __builtin_amdgcn_cvt_pk_f32_fp8((int)u8.x, false);
        floatx2 f23 = __builtin_amdgcn_cvt_pk_f32_fp8((int)u8.x, true);
        floatx2 f45 = __builtin_amdgcn_cvt_pk_f32_fp8((int)u8.y, false);
        floatx2 f67 = __builtin_amdgcn_cvt_pk_f32_fp8((int)u8.y, true);
        short8 af;
        unsigned* ap = (unsigned*)&af;
        ap[0] = pkbf(f01[0], f01[1]); ap[1] = pkbf(f23[0], f23[1]);
        ap[2] = pkbf(f45[0], f45[1]); ap[3] = pkbf(f67[0], f67[1]);
        acc = __builtin_amdgcn_mfma_f32_16x16x32_bf16(af, bfr, acc, 0, 0, 0);
    }
    // D: col = mlane -> c (0..3 el, 4..7 er), row = quad*4+r -> node
    if (mlane < 8) {
        float* dst = (mlane < 4) ? el : er;
        int h = mlane & 3;
#pragma unroll
        for (int r = 0; r < 4; r++) {
            int node = node0 + quad * 4 + r;
            dst[node * 4 + h] = acc[r];
        }
    }
}

// layer-3 agg + mean-pool IN x2-SPACE (W3 moved across the pooling):
// poolagg[g][h*128+c] = (1/32) sum_{n in g} sum_e alpha[e,h] x2[src[e]][c].
// Gathers 128B fp8 rows (half of the old 256B h3 rows); 64 lanes = 2 edges/load.
__global__ void agg3pool_kernel(const unsigned char* __restrict__ x8,
                                const float* __restrict__ el, const float* __restrict__ er,
                                const int* __restrict__ deg, const int* __restrict__ slots,
                                bf16* __restrict__ poolagg) {
    __shared__ float red[4][4][128];     // 8 KB [grp][h][ch]
    __shared__ float salpha[4][16][4];   // 1 KB [grp][e][h]
    __shared__ int   ssrc[4][16];        // 256 B
    int side = blockIdx.x >> 12;         // 8192 blocks: side*4096 + b
    int b = blockIdx.x & 4095;
    int nodebase = side * NN + b * 32;
    int grp = threadIdx.x >> 6, lane = threadIdx.x & 63;
    int e = lane & 15, h = lane >> 4;    // phaseA roles
    int esl = lane >> 5;                 // edge slot (0/1) for gather
    int ch4 = (lane & 31) * 4;           // channel block for gather
    float acc[4][4];                     // [h][c]
#pragma unroll
    for (int hh = 0; hh < 4; hh++)
#pragma unroll
        for (int c = 0; c < 4; c++) acc[hh][c] = 0.f;

    for (int nn = 0; nn < 8; nn++) {
        int wid = nodebase + grp * 8 + nn;
        int dg = deg[wid];
        dg = (dg > CAP) ? CAP : dg;
        float alpha; int sAc;
        softmax_phaseA(el, er, slots, wid, dg, lane, &alpha, &sAc);
        salpha[grp][e][h] = alpha;
        if (h == 0) ssrc[grp][e] = sAc;
        // same-wave LDS RAW: DS pipe is wave-ordered, no barrier needed
        for (int p = 0; p < dg; p += 4) {
            int ee0 = p + esl, ee1 = p + 2 + esl;
            int s0 = ssrc[grp][ee0];
            int s1 = ssrc[grp][ee1];
            float4 av0 = *(const float4*)&salpha[grp][ee0][0];  // broadcast per half-wave
            float4 av1 = *(const float4*)&salpha[grp][ee1][0];
            unsigned u0 = *(const unsigned*)(x8 + (size_t)s0 * 128 + ch4);
            unsigned u1 = *(const unsigned*)(x8 + (size_t)s1 * 128 + ch4);
            floatx2 lo0 = __builtin_amdgcn_cvt_pk_f32_fp8((int)u0, false);
            floatx2 hi0 = __builtin_amdgcn_cvt_pk_f32_fp8((int)u0, true);
            floatx2 lo1 = __builtin_amdgcn_cvt_pk_f32_fp8((int)u1, false);
            floatx2 hi1 = __builtin_amdgcn_cvt_pk_f32_fp8((int)u1, true);
            float xv0[4] = {lo0[0], lo0[1], hi0[0], hi0[1]};
            float xv1[4] = {lo1[0], lo1[1], hi1[0], hi1[1]};
            float aa0[4] = {av0.x, av0.y, av0.z, av0.w};
            float aa1[4] = {av1.x, av1.y, av1.z, av1.w};
#pragma unroll
            for (int hh = 0; hh < 4; hh++)
#pragma unroll
                for (int c = 0; c < 4; c++)
                    acc[hh][c] += aa0[hh] * xv0[c] + aa1[hh] * xv1[c];
        }
    }
    // sum the two edge-slots (lane and lane^32 hold the same [h][ch4] block)
#pragma unroll
    for (int hh = 0; hh < 4; hh++)
#pragma unroll
        for (int c = 0; c < 4; c++)
            acc[hh][c] += __shfl_xor(acc[hh][c], 32, 64);
    if (lane < 32) {
#pragma unroll
        for (int hh = 0; hh < 4; hh++)
            *(float4*)&red[grp][hh][ch4] =
                make_float4(acc[hh][0], acc[hh][1], acc[hh][2], acc[hh][3]);
    }
    __syncthreads();
    int t = threadIdx.x;
    int hlo = t >> 7, c = t & 127;
    float s0 = 0.f, s1 = 0.f;
#pragma unroll
    for (int g = 0; g < 4; g++) {
        s0 += red[g][hlo][c];
        s1 += red[g][2 + hlo][c];
    }
    const float inv = 1.0f / 32.0f;
    size_t gbase = (size_t)(b * 2 + side) * 512;
    poolagg[gbase + t] = f2bf(s0 * inv);
    poolagg[gbase + t + 256] = f2bf(s1 * inv);
}

// ---------------- MFMA bf16 GEMM: out[M,C] = A[M,K] @ Wt[C,K]^T (+bias)(+relu) ----------------
// PAIR: M rows are g = b*2+side; output written to pair layout [b][side*256 + c].
template <bool FOLD, bool OUT8, bool PAIR>
__global__ __launch_bounds__(256) void mgemm_kernel(const bf16* __restrict__ A,
                                                    const bf16* __restrict__ Wt,
                                                    const float* __restrict__ bias,
                                                    void* __restrict__ out,
                                                    int K, int C, int relu,
                                                    const bf16* __restrict__ Ff,
                                                    float* __restrict__ el,
                                                    float* __restrict__ er) {
    __shared__ short As[128 * 48];
    __shared__ short Bs[128 * 48];
    int t = threadIdx.x;
    int wave = t >> 6, lane = t & 63;
    int wm = (wave >> 1) * 64, wn = (wave & 1) * 64;
    int bm = blockIdx.x * 128, bn = blockIdx.y * 128;
    int m_lane = lane & 15, quad = lane >> 4;
    bool dofold = FOLD && (blockIdx.y == 0) && (wn == 0);

    floatx4 acc[4][4];
#pragma unroll
    for (int i = 0; i < 4; i++)
#pragma unroll
        for (int j = 0; j < 4; j++) acc[i][j] = (floatx4){0.f, 0.f, 0.f, 0.f};
    floatx4 facc[4];
    if (FOLD) {
#pragma unroll
        for (int i = 0; i < 4; i++) facc[i] = (floatx4){0.f, 0.f, 0.f, 0.f};
    }

    int lrow = t >> 2, lq = t & 3;
    for (int k0 = 0; k0 < K; k0 += 32) {
        __syncthreads();
#pragma unroll
        for (int pass = 0; pass < 2; pass++) {
            int row = lrow + pass * 64;
            *(short8*)&As[row * 48 + lq * 8] =
                *(const short8*)(A + (size_t)(bm + row) * K + k0 + lq * 8);
            *(short8*)&Bs[row * 48 + lq * 8] =
                *(const short8*)(Wt + (size_t)(bn + row) * K + k0 + lq * 8);
        }
        __syncthreads();
        short8 af[4], bf[4];
#pragma unroll
        for (int i = 0; i < 4; i++)
            af[i] = *(const short8*)&As[(wm + i * 16 + m_lane) * 48 + quad * 8];
#pragma unroll
        for (int j = 0; j < 4; j++)
            bf[j] = *(const short8*)&Bs[(wn + j * 16 + m_lane) * 48 + quad * 8];
        if (dofold) {
            short8 fbv = *(const short8*)(Ff + m_lane * K + k0 + quad * 8);
#pragma unroll
            for (int i = 0; i < 4; i++)
                facc[i] = __builtin_amdgcn_mfma_f32_16x16x32_bf16(af[i], fbv, facc[i], 0, 0, 0);
        }
#pragma unroll
        for (int i = 0; i < 4; i++)
#pragma unroll
            for (int j = 0; j < 4; j++)
                acc[i][j] = __builtin_amdgcn_mfma_f32_16x16x32_bf16(af[i], bf[j], acc[i][j], 0, 0, 0);
    }

#pragma unroll
    for (int i = 0; i < 4; i++) {
#pragma unroll
        for (int j = 0; j < 4; j++) {
            int gc = bn + wn + j * 16 + m_lane;
            float bbv = bias ? bias[gc] : 0.f;
#pragma unroll
            for (int r = 0; r < 4; r++) {
                int gr = bm + wm + i * 16 + quad * 4 + r;
                float v = acc[i][j][r] + bbv;
                if (relu) v = fmaxf(v, 0.f);
                if (OUT8)      ((unsigned char*)out)[(size_t)gr * C + gc] = ftofp8(v);
                else if (PAIR) ((bf16*)out)[(size_t)(gr >> 1) * 512 + (gr & 1) * 256 + gc] = f2bf(v);
                else           ((bf16*)out)[(size_t)gr * C + gc] = f2bf(v);
            }
        }
    }
    if (dofold && m_lane < 8) {
        float* dst = (m_lane < 4) ? el : er;
        int hh = m_lane & 3;
#pragma unroll
        for (int i = 0; i < 4; i++)
#pragma unroll
            for (int r = 0; r < 4; r++) {
                int gr = bm + wm + i * 16 + quad * 4 + r;
                dst[gr * 4 + hh] = facc[i][r];
            }
    }
}

// ---------------- fp32 512x512x512 GEMM (weight combine, prep-time) ----------------
__global__ __launch_bounds__(256) void fgemm512_kernel(const float* __restrict__ A,
                                                       const float* __restrict__ B,
                                                       float* __restrict__ C) {
    const int BK = 16;
    __shared__ float As[BK][68];
    __shared__ float Bs[BK][68];
    int t = threadIdx.x;
    int bm = blockIdx.x * 64, bn = blockIdx.y * 64;
    int tm0 = (t & 15) * 4, tn0 = (t >> 4) * 4;
    float acc[4][4] = {};
    int la_m = t >> 2, la_k = (t & 3) * 4;
    int lb_k = t >> 4, lb_c = (t & 15) * 4;

    for (int k0 = 0; k0 < 512; k0 += BK) {
        float4 a4 = *(const float4*)(A + (size_t)(bm + la_m) * 512 + k0 + la_k);
        float4 b4 = *(const float4*)(B + (size_t)(k0 + lb_k) * 512 + bn + lb_c);
        As[la_k + 0][la_m] = a4.x; As[la_k + 1][la_m] = a4.y;
        As[la_k + 2][la_m] = a4.z; As[la_k + 3][la_m] = a4.w;
        *(float4*)&Bs[lb_k][lb_c] = b4;
        __syncthreads();
#pragma unroll
        for (int k = 0; k < BK; k++) {
            float4 av = *(const float4*)&As[k][tm0];
            float4 bv = *(const float4*)&Bs[k][tn0];
            acc[0][0] += av.x * bv.x; acc[0][1] += av.x * bv.y; acc[0][2] += av.x * bv.z; acc[0][3] += av.x * bv.w;
            acc[1][0] += av.y * bv.x; acc[1][1] += av.y * bv.y; acc[1][2] += av.y * bv.z; acc[1][3] += av.y * bv.w;
            acc[2][0] += av.z * bv.x; acc[2][1] += av.z * bv.y; acc[2][2] += av.z * bv.z; acc[2][3] += av.z * bv.w;
            acc[3][0] += av.w * bv.x; acc[3][1] += av.w * bv.y; acc[3][2] += av.w * bv.z; acc[3][3] += av.w * bv.w;
        }
        __syncthreads();
    }
#pragma unroll
    for (int i = 0; i < 4; i++) {
        float4 o = make_float4(acc[i][0], acc[i][1], acc[i][2], acc[i][3]);
        *(float4*)(C + (size_t)(bm + tm0 + i) * 512 + bn + tn0) = o;
    }
}

__global__ void biasstep_kernel(const float* __restrict__ vin, const float* __restrict__ M,
                                const float* __restrict__ badd, float* __restrict__ vout) {
    int c = blockIdx.x * blockDim.x + threadIdx.x;
    float s = 0.f;
    for (int k = 0; k < 512; k++) s += vin[k] * M[(size_t)k * 512 + c];
    vout[c] = s + badd[c];
}

// ---------------- fusion tail ----------------

__global__ void ln_kernel(const bf16* __restrict__ attn, const bf16* __restrict__ lp,
                          const float* __restrict__ gamma, const float* __restrict__ beta,
                          bf16* __restrict__ out) {
    __shared__ float red[256];
    int b = blockIdx.x, t = threadIdx.x;
    size_t base = (size_t)b * 512;
    float x0 = bf2f(attn[base + t]) + bf2f(lp[base + t]);
    float x1 = bf2f(attn[base + 256 + t]) + bf2f(lp[base + 256 + t]);
    red[t] = x0 + x1; __syncthreads();
    for (int off = 128; off > 0; off >>= 1) { if (t < off) red[t] += red[t + off]; __syncthreads(); }
    float mu = red[0] * (1.0f / 512.0f);
    __syncthreads();
    float d0 = x0 - mu, d1 = x1 - mu;
    red[t] = d0 * d0 + d1 * d1; __syncthreads();
    for (int off = 128; off > 0; off >>= 1) { if (t < off) red[t] += red[t + off]; __syncthreads(); }
    float rstd = rsqrtf(red[0] * (1.0f / 512.0f) + LN_EPS);
    out[base + t]       = f2bf(d0 * rstd * gamma[t] + beta[t]);
    out[base + 256 + t] = f2bf(d1 * rstd * gamma[256 + t] + beta[256 + t]);
}

__global__ void cls2_kernel(const bf16* __restrict__ hc, const float* __restrict__ Wc2,
                            const float* __restrict__ bc2, float* __restrict__ out) {
    int wid = (blockIdx.x * blockDim.x + threadIdx.x) >> 6;
    int lane = threadIdx.x & 63;
    if (wid >= NB) return;
    float s = 0.f;
#pragma unroll
    for (int j = 0; j < 4; j++) {
        int k = lane + 64 * j;
        s += bf2f(hc[(size_t)wid * 256 + k]) * Wc2[k];
    }
    for (int off = 32; off > 0; off >>= 1) s += __shfl_down(s, off);
    if (lane == 0) {
        float v = s + bc2[0];
        out[wid] = 1.0f / (1.0f + __expf(-v));
    }
}

// ---------------- launch ----------------

static inline size_t alup(size_t x) { return (x + 255) & ~(size_t)255; }

extern "C" void kernel_launch(void* const* d_in, const int* in_sizes, int n_in,
                              void* d_out, int out_size, void* d_ws, size_t ws_size,
                              hipStream_t stream) {
    const float* feat0 = (const float*)d_in[0];
    const float* feat1 = (const float*)d_in[1];
    const float* llm = (const float*)d_in[2];
    const int* srcs[2] = {(const int*)d_in[3], (const int*)d_in[5]};
    const int* dsts[2] = {(const int*)d_in[4], (const int*)d_in[6]};
    const float* W1 = (const float*)d_in[8];
    const float* al[3] = {(const float*)d_in[9],  (const float*)d_in[13], (const float*)d_in[17]};
    const float* ar[3] = {(const float*)d_in[10], (const float*)d_in[14], (const float*)d_in[18]};
    const float* bb[3] = {(const float*)d_in[11], (const float*)d_in[15], (const float*)d_in[19]};
    const float* W2 = (const float*)d_in[12];
    const float* W3 = (const float*)d_in[16];
    const float* Wpg = (const float*)d_in[20]; const float* bpg = (const float*)d_in[21];
    const float* Wpl = (const float*)d_in[22]; const float* bpl = (const float*)d_in[23];
    const float* Wv  = (const float*)d_in[24]; const float* bv  = (const float*)d_in[25];
    const float* Wo  = (const float*)d_in[26]; const float* bo  = (const float*)d_in[27];
    const float* gamma = (const float*)d_in[28]; const float* beta = (const float*)d_in[29];
    const float* Wc1 = (const float*)d_in[30]; const float* bc1 = (const float*)d_in[31];
    const float* Wc2 = (const float*)d_in[32]; const float* bc2 = (const float*)d_in[33];
    float* outp = (float*)d_out;

    const size_t N2 = (size_t)2 * NN;

    // workspace carve (~138 MiB)
    char* p = (char*)d_ws;
    auto take = [&](size_t bytes) { char* r = p; p += alup(bytes); return r; };
    bf16*  xb     = (bf16*)take(N2 * 128 * 2);        // A: 64 MiB (layer-1 bf16 / x2 fp8)
    char*  regB   = (char*)take(N2 * 256);            // B: 64 MiB (cells+counts / fpk / hb2 / poolagg / tail)
    float* el     = (float*)take(N2 * 4 * 4);         // 4 MiB
    float* er     = (float*)take(N2 * 4 * 4);         // 4 MiB
    int*   deg    = (int*)take(N2 * 4);               // 1 MiB
    int*   slots  = (int*)take(N2 * CAP * 4);         // 16.8 MiB
    bf16*  pair   = (bf16*)take((size_t)NB * 512 * 2);
    bf16*  llm_bf = (bf16*)take((size_t)NB * 1024 * 2); // 8 MiB
    bf16*  W2t  = (bf16*)take(128 * 128 * 2);
    bf16*  Wplt = (bf16*)take(1024 * 512 * 2);
    bf16*  Wc1t = (bf16*)take(512 * 256 * 2);
    bf16*  Wcot = (bf16*)take(512 * 512 * 2);
    bf16*  W3bdt = (bf16*)take(256 * 512 * 2);        // block-diag W3^T [C=256][K=512]
    float* F1   = (float*)take(6 * 8 * 4);
    bf16*  Ff2  = (bf16*)take(16 * 128 * 2);
    bf16*  Ff3  = (bf16*)take(16 * 128 * 2);
    bf16*  W1fg = (bf16*)take(128 * 32 * 2);          // 8 KiB layer-1 MFMA weight
    float* c1   = (float*)take(512 * 512 * 4);
    float* c2   = (float*)take(512 * 512 * 4);
    float* bias1 = (float*)take(512 * 4);
    float* bco   = (float*)take(512 * 4);
    // region A alias: x2 fp8 (written by agg2 over dead layer-1 activations)
    unsigned char* x8 = (unsigned char*)xb;
    // region B aliases (sequential lifetimes):
    unsigned* cells = (unsigned*)regB;                // [NBKT][NBLK1][CELL_CAP] 25 MiB (pre-fpk)
    int* counts = (int*)(regB + (size_t)NBKT * NBLK1 * CELL_CAP * 4);  // 1 MiB
    float* fpk          = (float*)regB;               // packed feats [2NN][8] (8.4 MiB, pre-L2)
    unsigned char* hb2  = (unsigned char*)regB;       // layer-2 features fp8 [2NN,128] (32 MiB)
    bf16* poolagg = (bf16*)(regB + 32 * 1024 * 1024); // [8192][512] bf16 (8 MiB, after hb2 dead)
    bf16* fbb   = (bf16*)regB;                        // fusion-tail activations
    bf16* lp    = fbb + (size_t)0 * NB * 512;
    bf16* attn  = fbb + (size_t)1 * NB * 512;
    bf16* fused = fbb + (size_t)2 * NB * 512;
    bf16* hc    = fbb + (size_t)3 * NB * 512;
    (void)ws_size; (void)n_in; (void)in_sizes; (void)out_size;

    auto mgemm = [&](const bf16* A, const bf16* Wt, const float* bias, bf16* o,
                     int M, int K, int C, int relu) {
        dim3 g(M / 128, C / 128);
        mgemm_kernel<false, false, false><<<g, 256, 0, stream>>>(A, Wt, bias, o, K, C, relu,
                                                                 nullptr, nullptr, nullptr);
    };

    // ---- slot bucketing first (cells alias region B, consumed before fpk) ----
    part_edges_kernel<<<NBLK1, 256, 0, stream>>>(srcs[0], dsts[0], srcs[1], dsts[1],
                                                 cells, counts);
    build_slots_kernel<<<NBKT, 256, 0, stream>>>(cells, counts, deg, slots);

    // ---- per-call preps ----
    prep_all_kernel<<<(PREP_TOTAL + 255) / 256, 256, 0, stream>>>(
        W2, W3, Wpl, Wc1, W1, al[0], ar[0], al[1], ar[1], al[2], ar[2], bb[0],
        W2t, Wplt, Wc1t, Ff2, Ff3, F1, W1fg, W3bdt);
    f2bf_kernel<<<NB * 1024 / 4 / 256, 256, 0, stream>>>(llm, llm_bf);
    {
        dim3 g8(8, 8);
        fgemm512_kernel<<<g8, 256, 0, stream>>>(Wpg, Wv, c1);
        fgemm512_kernel<<<g8, 256, 0, stream>>>(c1, Wo, c2);
        wt_kernel<<<(512 * 512 + 255) / 256, 256, 0, stream>>>(c2, Wcot, 512, 512);
        biasstep_kernel<<<2, 256, 0, stream>>>(bpg, Wv, bv, bias1);
        biasstep_kernel<<<2, 256, 0, stream>>>(bias1, Wo, bo, bco);
    }

    // ---- GNN, both sides merged ----
    featelr_kernel<<<2 * NN / 256, 256, 0, stream>>>(feat0, feat1, F1, fpk, el, er);
    agg1mfma_kernel<<<2 * NN / 256, 256, 0, stream>>>(fpk, el, er, deg, slots, W1fg, xb);
    {
        dim3 g(2 * NN / 128, 1);
        mgemm_kernel<true, true, false><<<g, 256, 0, stream>>>(xb, W2t, nullptr, hb2,
                                                               128, 128, 0, Ff2, el, er);
    }
    agg2_kernel<<<2 * NN * 32 / 256, 256, 0, stream>>>(hb2, el, er, deg, slots, bb[1], x8);
    elr3_kernel<<<2 * NN / 64, 256, 0, stream>>>(x8, Ff3, el, er);
    agg3pool_kernel<<<2 * NB, 256, 0, stream>>>(x8, el, er, deg, slots, poolagg);
    {
        // pair = poolagg @ W3bd + bias3 (per-graph W3, PAIR output mapping)
        dim3 g(8192 / 128, 256 / 128);
        mgemm_kernel<false, false, true><<<g, 256, 0, stream>>>(poolagg, W3bdt, bb[2], pair,
                                                                512, 256, 0,
                                                                nullptr, nullptr, nullptr);
    }

    // ---- fusion tail (activations alias region B) ----
    mgemm(llm_bf, Wplt, bpl, lp, NB, 1024, 512, 0);
    mgemm(pair, Wcot, bco, attn, NB, 512, 512, 0);
    ln_kernel<<<NB, 256, 0, stream>>>(attn, lp, gamma, beta, fused);
    mgemm(fused, Wc1t, bc1, hc, NB, 512, 256, 1);
    cls2_kernel<<<NB / 4, 256, 0, stream>>>(hc, Wc2, bc2, outp);
}

// Round 7
// 555.653 us; speedup vs baseline: 1.0695x; 1.0275x over previous
//
#include <hip/hip_runtime.h>
#include <hip/hip_fp8.h>

#define NN 131072      // nodes per side
#define NE 524288      // edges per side
#define NB 4096        // graphs per side
#define CAP 16         // slot capacity = one 64B line/node
#define NEG_SLOPE 0.2f
#define LN_EPS 1e-5f
#define LOG2E 1.44269504088896f

// edge-partition geometry (atomic-free slot build)
#define NBKT 1024      // buckets of 256 nodes (2NN/256)
#define NBLK1 256      // phase-1 blocks
#define CELL_CAP 24    // per-(bucket,block) cell capacity (avg 4, Poisson tail ~1e-13)

typedef unsigned short bf16;
typedef __attribute__((ext_vector_type(8))) short short8;
typedef __attribute__((ext_vector_type(4))) float floatx4;
typedef __attribute__((ext_vector_type(2))) float floatx2;

#if __has_builtin(__builtin_amdgcn_exp2f)
#define EXP2(x) __builtin_amdgcn_exp2f(x)
#else
#define EXP2(x) exp2f(x)
#endif

__device__ __forceinline__ float bf2f(bf16 h) {
    return __uint_as_float((unsigned)h << 16);
}
__device__ __forceinline__ bf16 f2bf(float f) {
    unsigned u = __float_as_uint(f);
    unsigned r = (u + 0x7FFFu + ((u >> 16) & 1u)) >> 16;
    return (bf16)r;
}
// HW packed bf16 pair encode (RNE, same unit the compiler uses for bf16 casts)
__device__ __forceinline__ unsigned pkbf(float lo, float hi) {
    unsigned r;
    asm("v_cvt_pk_bf16_f32 %0, %1, %2" : "=v"(r) : "v"(lo), "v"(hi));
    return r;
}
// HW packed fp8(e4m3) encode
__device__ __forceinline__ unsigned char ftofp8(float f) {
    return (unsigned char)(__builtin_amdgcn_cvt_pk_fp8_f32(f, f, 0, false) & 0xFF);
}
__device__ __forceinline__ float leaky(float x) {
    return fmaxf(x, 0.f) + NEG_SLOPE * fminf(x, 0.f);
}

// ---------------- atomic-free slot build (two-phase partition) ----------------
// Phase 1: bin edges into block-private cells via LDS histogram (no global atomics;
//          cell lines are block-private -> no cross-XCD ping-pong).
__global__ __launch_bounds__(256) void part_edges_kernel(
        const int* __restrict__ s0, const int* __restrict__ d0,
        const int* __restrict__ s1, const int* __restrict__ d1,
        unsigned* __restrict__ cells, int* __restrict__ counts) {
    __shared__ int lcnt[NBKT];       // 4 KB
    int blk = blockIdx.x, t = threadIdx.x;
    for (int i = t; i < NBKT; i += 256) lcnt[i] = 0;
    __syncthreads();
    int side = blk >= (NBLK1 / 2);               // 128 blocks per side
    const int4* dp = (const int4*)(side ? d1 : d0);
    const int4* sp = (const int4*)(side ? s1 : s0);
    int base4 = (blk - side * (NBLK1 / 2)) * 1024;
    int gbase = side * NN;
#pragma unroll
    for (int it = 0; it < 4; it++) {
        int e4 = base4 + it * 256 + t;           // [0, NE/4)
        int4 dd = dp[e4];
        int4 ss = sp[e4];
        int d[4] = {gbase + dd.x, gbase + dd.y, gbase + dd.z, gbase + dd.w};
        int s[4] = {gbase + ss.x, gbase + ss.y, gbase + ss.z, gbase + ss.w};
#pragma unroll
        for (int k = 0; k < 4; k++) {
            int b = d[k] >> 8;
            int r = atomicAdd(&lcnt[b], 1);      // LDS atomic
            if (r < CELL_CAP)
                cells[((size_t)b * NBLK1 + blk) * CELL_CAP + r] =
                    ((unsigned)s[k] << 8) | (unsigned)(d[k] & 255);
        }
    }
    __syncthreads();
    for (int i = t; i < NBKT; i += 256) {
        int c = lcnt[i];
        counts[i * NBLK1 + blk] = (c > CELL_CAP) ? CELL_CAP : c;
    }
}

// Phase 2: one block per bucket; build deg/slots for 256 nodes in LDS, write coalesced.
__global__ __launch_bounds__(256) void build_slots_kernel(
        const unsigned* __restrict__ cells, const int* __restrict__ counts,
        int* __restrict__ deg, int* __restrict__ slots) {
    __shared__ int ldeg[256];                    // 1 KB
    __shared__ int lslot[256 * CAP];             // 16 KB
    int b = blockIdx.x, t = threadIdx.x;
    ldeg[t] = 0;
    for (int i = t; i < 256 * CAP; i += 256) lslot[i] = 0;
    __syncthreads();
    // thread t consumes cell t of this bucket
    int cnt = counts[b * NBLK1 + t];
    const unsigned* cp = cells + ((size_t)b * NBLK1 + t) * CELL_CAP;
    for (int i = 0; i < cnt; i++) {
        unsigned v = cp[i];
        int d = v & 255;
        int s = (int)(v >> 8);
        int p = atomicAdd(&ldeg[d], 1);          // LDS atomic
        if (p < CAP) lslot[d * CAP + p] = s;
    }
    __syncthreads();
    int node0 = b * 256;
    deg[node0 + t] = ldeg[t];
    for (int i = t; i < 256 * CAP; i += 256)
        slots[(size_t)node0 * CAP + i] = lslot[i];
}

// ---------------- merged weight prep ----------------
// W2t + Wplt + Wc1t + Ff2 + Ff3 + F1 + W1f + W3bdt
#define PREP_TOTAL (16384 + 524288 + 131072 + 2048 + 2048 + 48 + 4096 + 131072)

__global__ void prep_all_kernel(const float* __restrict__ W2, const float* __restrict__ W3,
                                const float* __restrict__ Wpl, const float* __restrict__ Wc1,
                                const float* __restrict__ W1,
                                const float* __restrict__ al1, const float* __restrict__ ar1,
                                const float* __restrict__ al2, const float* __restrict__ ar2,
                                const float* __restrict__ al3, const float* __restrict__ ar3,
                                const float* __restrict__ b1v,
                                bf16* __restrict__ W2t, bf16* __restrict__ Wplt,
                                bf16* __restrict__ Wc1t,
                                bf16* __restrict__ Ff2, bf16* __restrict__ Ff3,
                                float* __restrict__ F1, bf16* __restrict__ W1f,
                                bf16* __restrict__ W3bdt) {
    int i = blockIdx.x * blockDim.x + threadIdx.x;
    if (i < 16384) {  // W2t: K=128,C=128
        int c = i >> 7, k = i & 127;
        W2t[i] = f2bf(W2[k * 128 + c]);
        return;
    }
    i -= 16384;
    if (i < 524288) {  // Wplt: K=1024,C=512
        int c = i >> 10, k = i & 1023;
        Wplt[i] = f2bf(Wpl[k * 512 + c]);
        return;
    }
    i -= 524288;
    if (i < 131072) {  // Wc1t: K=512,C=256
        int c = i >> 9, k = i & 511;
        Wc1t[i] = f2bf(Wc1[k * 256 + c]);
        return;
    }
    i -= 131072;
    if (i < 2048) {  // Ff2: Kin=128, Dh=32
        int c = i >> 7, k = i & 127;
        float s = 0.f;
        if (c < 8) {
            const float* a = (c < 4) ? al2 : ar2;
            int hh = c & 3;
            for (int d = 0; d < 32; d++) s += W2[k * 128 + hh * 32 + d] * a[hh * 32 + d];
        }
        Ff2[i] = f2bf(s);
        return;
    }
    i -= 2048;
    if (i < 2048) {  // Ff3: Kin=128, Dh=64 (layer-3 attn fold applied to x2)
        int c = i >> 7, k = i & 127;
        float s = 0.f;
        if (c < 8) {
            const float* a = (c < 4) ? al3 : ar3;
            int hh = c & 3;
            for (int d = 0; d < 64; d++) s += W3[k * 256 + hh * 64 + d] * a[hh * 64 + d];
        }
        Ff3[i] = f2bf(s);
        return;
    }
    i -= 2048;
    if (i < 48) {  // F1: layer-1 fold (fp32, K=6), pre-scaled by log2(e) so agg1 uses exp2
        int k = i >> 3, c = i & 7;
        const float* a = (c < 4) ? al1 : ar1;
        int hh = c & 3;
        float s = 0.f;
        for (int d = 0; d < 32; d++) s += W1[k * 128 + hh * 32 + d] * a[hh * 32 + d];
        F1[k * 8 + c] = s * LOG2E;
        return;
    }
    i -= 48;
    if (i < 4096) {  // W1f: [C=128][K=32], k = h*8+d; slot d==6 carries bias (pairs with 1.0)
        int c = i >> 5, k = i & 31;
        int h = c >> 5, d = k & 7;
        float v = 0.f;
        if ((k >> 3) == h) {
            if (d < 6) v = W1[d * 128 + c];
            else if (d == 6) v = b1v[c];
        }
        W1f[i] = f2bf(v);
        return;
    }
    i -= 4096;
    if (i < 131072) {  // W3bdt: block-diag W3^T [C=256][K=512]; r = h*128+k active iff h==c>>6
        int c = i >> 9, r = i & 511;
        int hr = r >> 7, k = r & 127;
        float v = (hr == (c >> 6)) ? W3[k * 256 + c] : 0.f;
        W3bdt[i] = f2bf(v);
    }
}

__global__ void f2bf_kernel(const float* __restrict__ x, bf16* __restrict__ y) {
    int i = blockIdx.x * blockDim.x + threadIdx.x;
    float4 v = ((const float4*)x)[i];
    ushort4 u;
    u.x = f2bf(v.x); u.y = f2bf(v.y); u.z = f2bf(v.z); u.w = f2bf(v.w);
    ((ushort4*)y)[i] = u;
}

__global__ void wt_kernel(const float* __restrict__ W, bf16* __restrict__ Wt, int K, int C) {
    int i = blockIdx.x * blockDim.x + threadIdx.x;
    if (i >= K * C) return;
    int c = i / K, k = i - c * K;
    Wt[i] = f2bf(W[(size_t)k * C + c]);
}

// ---------------- layer-1 front end ----------------

// Fused: pack raw feats into padded [2NN][8] fp32 rows + compute el/er (log2e-scaled F1).
__global__ void featelr_kernel(const float* __restrict__ f0, const float* __restrict__ f1,
                               const float* __restrict__ F1, float* __restrict__ fpk,
                               float* __restrict__ el, float* __restrict__ er) {
    int n = blockIdx.x * blockDim.x + threadIdx.x;  // [0, 2*NN)
    const float* x = (n < NN) ? (f0 + (size_t)n * 6) : (f1 + (size_t)(n - NN) * 6);
    float xv[6];
#pragma unroll
    for (int k = 0; k < 6; k++) xv[k] = x[k];
    float4* o = (float4*)(fpk + (size_t)n * 8);
    o[0] = make_float4(xv[0], xv[1], xv[2], xv[3]);
    o[1] = make_float4(xv[4], xv[5], 0.f, 0.f);
    float4 elv, erv;
    float* ep = (float*)&elv;
    float* rp = (float*)&erv;
#pragma unroll
    for (int c = 0; c < 4; c++) {
        float sl = 0.f, sr = 0.f;
#pragma unroll
        for (int k = 0; k < 6; k++) {
            sl += xv[k] * F1[k * 8 + c];
            sr += xv[k] * F1[k * 8 + c + 4];
        }
        ep[c] = sl;
        rp[c] = sr;
    }
    *(float4*)(el + (size_t)n * 4) = elv;
    *(float4*)(er + (size_t)n * 4) = erv;
}

// Fused layer-1: one lane per node gathers + softmax-aggregates the 6-dim feats
// (vector el float4 + packed-feat float4x2, exp2 weights), then per-wave MFMA does the
// 32->128 W1 transform (bias folded via the 1.0 slot in sagg / b1 row in W1f).
__global__ __launch_bounds__(256) void agg1mfma_kernel(
        const float* __restrict__ fpk, const float* __restrict__ el,
        const float* __restrict__ er, const int* __restrict__ deg,
        const int* __restrict__ slots, const bf16* __restrict__ W1fg,
        bf16* __restrict__ xb) {
    __shared__ bf16 sW[128 * 40];     // [128 ch][32 k] padded to 40 (bank-conflict break)
    __shared__ bf16 sagg[256 * 40];   // [256 node][32 k] padded to 40
    int t = threadIdx.x;
    // stage W1f into padded LDS (one row = 64B = 4x uint4)
    if (t < 128) {
        const uint4* src = (const uint4*)(W1fg + t * 32);
        uint4* dstp = (uint4*)(sW + t * 40);
        dstp[0] = src[0]; dstp[1] = src[1]; dstp[2] = src[2]; dstp[3] = src[3];
    }

    // ---- phase 1: per-lane gather softmax-aggregate ----
    int node = blockIdx.x * 256 + t;
    int dg = deg[node];
    dg = (dg > CAP) ? CAP : dg;
    float4 er4 = *(const float4*)(er + (size_t)node * 4);
    const int* sp = slots + (size_t)node * CAP;
    float a0[4], a1[4], a2[4], a3[4], a4[4], a5[4], ss[4];
#pragma unroll
    for (int h = 0; h < 4; h++) {
        a0[h] = a1[h] = a2[h] = a3[h] = a4[h] = a5[h] = ss[h] = 0.f;
    }
    for (int p = 0; p < dg; p += 4) {
        int4 s4 = *(const int4*)(sp + p);
        int sarr[4] = {s4.x, s4.y, s4.z, s4.w};
#pragma unroll
        for (int k = 0; k < 4; k++) {
            bool vld = (p + k) < dg;
            int g = vld ? sarr[k] : s4.x;       // clamp: unread slots may be garbage
            float4 e4 = *(const float4*)(el + (size_t)g * 4);
            float4 xa = *(const float4*)(fpk + (size_t)g * 8);
            float4 xc = *(const float4*)(fpk + (size_t)g * 8 + 4);
            float eh[4] = {e4.x, e4.y, e4.z, e4.w};
            float rh[4] = {er4.x, er4.y, er4.z, er4.w};
#pragma unroll
            for (int h = 0; h < 4; h++) {
                float z = eh[h] + rh[h];
                float w = EXP2(fmaxf(z, 0.f) + NEG_SLOPE * fminf(z, 0.f));
                w = vld ? w : 0.f;
                ss[h] += w;
                a0[h] += w * xa.x; a1[h] += w * xa.y; a2[h] += w * xa.z;
                a3[h] += w * xa.w; a4[h] += w * xc.x; a5[h] += w * xc.y;
            }
        }
    }
#pragma unroll
    for (int h = 0; h < 4; h++) {
        float rs = (dg > 0) ? 1.f / ss[h] : 0.f;
        uint4 o;
        o.x = pkbf(a0[h] * rs, a1[h] * rs);
        o.y = pkbf(a2[h] * rs, a3[h] * rs);
        o.z = pkbf(a4[h] * rs, a5[h] * rs);
        o.w = 0x00003F80u;  // (1.0bf16, 0.0): bias slot k=h*8+6
        *(uint4*)(sagg + t * 40 + h * 8) = o;
    }
    __syncthreads();

    // ---- phase 2: per-wave MFMA, 64 nodes x 128 channels ----
    int wave = t >> 6, lane = t & 63;
    int mlane = lane & 15, quad = lane >> 4;
    short8 af[8];
#pragma unroll
    for (int j = 0; j < 8; j++)
        af[j] = *(const short8*)(sW + (j * 16 + mlane) * 40 + quad * 8);
    floatx4 z4 = (floatx4){0.f, 0.f, 0.f, 0.f};
#pragma unroll
    for (int nt = 0; nt < 4; nt++) {
        int lrow = wave * 64 + nt * 16 + mlane;
        short8 bfr = *(const short8*)(sagg + lrow * 40 + quad * 8);
        floatx4 c[8];
#pragma unroll
        for (int j = 0; j < 8; j++)
            c[j] = __builtin_amdgcn_mfma_f32_16x16x32_bf16(af[j], bfr, z4, 0, 0, 0);
        // D: col = mlane -> node, row = quad*4+r -> channel j*16+quad*4+r
        bf16* op = xb + (size_t)(blockIdx.x * 256 + lrow) * 128 + quad * 4;
#pragma unroll
        for (int j = 0; j < 8; j++) {
            uint2 o;
            o.x = pkbf(fmaxf(c[j][0], 0.f), fmaxf(c[j][1], 0.f));
            o.y = pkbf(fmaxf(c[j][2], 0.f), fmaxf(c[j][3], 0.f));
            *(uint2*)(op + j * 16) = o;
        }
    }
}

// ---------------- GAT kernels (merged over 2*NN) ----------------

// Phase-A helper (agg3pool only): lane = h*16+e computes alpha[e][h] + clamped src.
__device__ __forceinline__ void softmax_phaseA(const float* __restrict__ el,
                                               const float* __restrict__ er,
                                               const int* __restrict__ slots,
                                               int wid, int dg, int lane,
                                               float* alpha_out, int* src_out) {
    int e = lane & 15, h = lane >> 4;
    int sA = slots[(size_t)wid * CAP + e];
    int sAc = (e < dg) ? sA : 0;                 // clamp: poisoned slots are unsafe addrs
    float erh = er[wid * 4 + h];
    float elv = el[sAc * 4 + h];
    float w = (e < dg) ? __expf(leaky(elv + erh)) : 0.f;
    float ssum = w;
    ssum += __shfl_xor(ssum, 1, 64);
    ssum += __shfl_xor(ssum, 2, 64);
    ssum += __shfl_xor(ssum, 4, 64);
    ssum += __shfl_xor(ssum, 8, 64);
    *alpha_out = (dg > 0) ? w * (1.f / ssum) : 0.f;   // 0 for e>=dg (w=0)
    *src_out = sAc;
}

// layer-2 agg (R13 structure): 32 lanes/node, inline per-lane-head softmax,
// 4-edge batch (4 loads in flight), 4B fp8 loads, HW cvt. R5: fp8 output (x2).
__global__ void agg2_kernel(const unsigned char* __restrict__ h8, const float* __restrict__ el,
                            const float* __restrict__ er, const int* __restrict__ deg,
                            const int* __restrict__ slots, const float* __restrict__ bias,
                            unsigned char* __restrict__ out) {
    int t = blockIdx.x * blockDim.x + threadIdx.x;
    int wid = t >> 5;                // [0, 2*NN)
    int gl = threadIdx.x & 31;
    int dg = deg[wid];
    dg = (dg > CAP) ? CAP : dg;
    int head = gl >> 3;
    int fbase = gl * 4;
    float erh = er[wid * 4 + head];
    const int* sp = slots + (size_t)wid * CAP;
    float a0 = 0.f, a1 = 0.f, a2 = 0.f, a3 = 0.f, ssum = 0.f;

    for (int p = 0; p < dg; p += 4) {
        int4 s4 = *(const int4*)(sp + p);
        int s[4]; bool v[4];
        s[0] = s4.x; v[0] = true;
        v[1] = p + 1 < dg; s[1] = v[1] ? s4.y : s4.x;
        v[2] = p + 2 < dg; s[2] = v[2] ? s4.z : s4.x;
        v[3] = p + 3 < dg; s[3] = v[3] ? s4.w : s4.x;
        float elv[4]; unsigned u1[4];
#pragma unroll
        for (int k = 0; k < 4; k++) {
            elv[k] = el[s[k] * 4 + head];
            u1[k] = *(const unsigned*)(h8 + (size_t)s[k] * 128 + fbase);
        }
#pragma unroll
        for (int k = 0; k < 4; k++) {
            float w = v[k] ? __expf(leaky(elv[k] + erh)) : 0.f;
            ssum += w;
            floatx2 lo = __builtin_amdgcn_cvt_pk_f32_fp8((int)u1[k], false);
            floatx2 hi = __builtin_amdgcn_cvt_pk_f32_fp8((int)u1[k], true);
            a0 += w * lo[0]; a1 += w * lo[1];
            a2 += w * hi[0]; a3 += w * hi[1];
        }
    }
    float rs = (dg > 0) ? 1.f / ssum : 0.f;
    float4 bbv = *(const float4*)(bias + fbase);
    float v0 = fmaxf(a0 * rs + bbv.x, 0.f), v1 = fmaxf(a1 * rs + bbv.y, 0.f);
    float v2 = fmaxf(a2 * rs + bbv.z, 0.f), v3 = fmaxf(a3 * rs + bbv.w, 0.f);
    unsigned w8 = (unsigned)__builtin_amdgcn_cvt_pk_fp8_f32(v0, v1, 0, false);
    w8 = (unsigned)__builtin_amdgcn_cvt_pk_fp8_f32(v2, v3, (int)w8, true);
    *(unsigned*)(out + (size_t)wid * 128 + fbase) = w8;
}

// layer-3 el/er from fp8 x2 via MFMA: el/er[n,h] = sum_k x2[n,k] * Ff3[c,k]
// (c<4 -> el head c, c in 4..8 -> er head c-4). 16 nodes per wave-mfma.
__global__ __launch_bounds__(256) void elr3_kernel(const unsigned char* __restrict__ x8,
                                                   const bf16* __restrict__ Ff3,
                                                   float* __restrict__ el,
                                                   float* __restrict__ er) {
    int wave = threadIdx.x >> 6, lane = threadIdx.x & 63;
    int mlane = lane & 15, quad = lane >> 4;
    int node0 = blockIdx.x * 64 + wave * 16;
    floatx4 acc = (floatx4){0.f, 0.f, 0.f, 0.f};
#pragma unroll
    for (int kb = 0; kb < 4; kb++) {
        short8 bfr = *(const short8*)(Ff3 + mlane * 128 + kb * 32 + quad * 8);
        uint2 u8 = *(const uint2*)(x8 + (size_t)(node0 + mlane) * 128 + kb * 32 + quad * 8);
        floatx2 f01 = __builtin_amdgcn_cvt_pk_f32_fp8((int)u8.x, false);
        floatx2 f23 = __builtin_amdgcn_cvt_pk_f32_fp8((int)u8.x, true);
        floatx2 f45 = __builtin_amdgcn_cvt_pk_f32_fp8((int)u8.y, false);
        floatx2 f67 = __builtin_amdgcn_cvt_pk_f32_fp8((int)u8.y, true);
        short8 af;
        unsigned* ap = (unsigned*)&af;
        ap[0] = pkbf(f01[0], f01[1]); ap[1] = pkbf(f23[0], f23[1]);
        ap[2] = pkbf(f45[0], f45[1]); ap[3] = pkbf(f67[0], f67[1]);
        acc = __builtin_amdgcn_mfma_f32_16x16x32_bf16(af, bfr, acc, 0, 0, 0);
    }
    // D: col = mlane -> c (0..3 el, 4..7 er), row = quad*4+r -> node
    if (mlane < 8) {
        float* dst = (mlane < 4) ? el : er;
        int h = mlane & 3;
#pragma unroll
        for (int r = 0; r < 4; r++) {
            int node = node0 + quad * 4 + r;
            dst[node * 4 + h] = acc[r];
        }
    }
}

// layer-3 agg + mean-pool IN x2-SPACE. R6: phaseA for all 8 nodes upfront
// (8 independent latency chains), compacted per-group edge worklist, 8-edge
// gather iterations (4 loads in flight/lane), packed-f32 accumulation.
__global__ void agg3pool_kernel(const unsigned char* __restrict__ x8,
                                const float* __restrict__ el, const float* __restrict__ er,
                                const int* __restrict__ deg, const int* __restrict__ slots,
                                bf16* __restrict__ poolagg) {
    __shared__ float red[4][4][128];      // 8 KB   [grp][h][ch]
    __shared__ float salpha[4][136][4];   // 8.5 KB [grp][edge][h], compacted
    __shared__ int   ssrc[4][136];        // 2.2 KB
    int side = blockIdx.x >> 12;          // 8192 blocks: side*4096 + b
    int b = blockIdx.x & 4095;
    int nodebase = side * NN + b * 32;
    int grp = threadIdx.x >> 6, lane = threadIdx.x & 63;
    int e = lane & 15, h = lane >> 4;     // phaseA roles
    int esl = lane >> 5;                  // edge slot (0/1) for gather
    int ch4 = (lane & 31) * 4;            // channel block for gather

    // ---- phase A: softmax for all 8 nodes, build compact worklist ----
    int off = 0;
    for (int nn = 0; nn < 8; nn++) {
        int wid = nodebase + grp * 8 + nn;
        int dg = deg[wid];
        dg = (dg > CAP) ? CAP : dg;
        float alpha; int sAc;
        softmax_phaseA(el, er, slots, wid, dg, lane, &alpha, &sAc);
        if (e < dg) {
            salpha[grp][off + e][h] = alpha;
            if (h == 0) ssrc[grp][off + e] = sAc;
        }
        off += dg;
    }
    int padded = (off + 7) & ~7;
    if (lane < padded - off) {            // zero-pad tail edges (alpha=0, src=0)
        int j = off + lane;
        *(float4*)&salpha[grp][j][0] = make_float4(0.f, 0.f, 0.f, 0.f);
        ssrc[grp][j] = 0;
    }
    // same-wave LDS RAW: DS pipe is wave-ordered, no barrier needed

    // ---- gather: 8 edges/iter, half-wave per edge, packed-f32 accum ----
    floatx2 acc[4][2];                    // [h][lo/hi pair of 4 channels]
#pragma unroll
    for (int hh = 0; hh < 4; hh++) {
        acc[hh][0] = (floatx2){0.f, 0.f};
        acc[hh][1] = (floatx2){0.f, 0.f};
    }
    for (int j = 0; j < padded; j += 8) {
        int sc[4]; float4 av[4]; unsigned u[4];
#pragma unroll
        for (int k = 0; k < 4; k++) {
            int je = j + 2 * k + esl;
            sc[k] = ssrc[grp][je];
            av[k] = *(const float4*)&salpha[grp][je][0];
        }
#pragma unroll
        for (int k = 0; k < 4; k++)
            u[k] = *(const unsigned*)(x8 + (size_t)sc[k] * 128 + ch4);
#pragma unroll
        for (int k = 0; k < 4; k++) {
            floatx2 lo = __builtin_amdgcn_cvt_pk_f32_fp8((int)u[k], false);
            floatx2 hi = __builtin_amdgcn_cvt_pk_f32_fp8((int)u[k], true);
            float aa[4] = {av[k].x, av[k].y, av[k].z, av[k].w};
#pragma unroll
            for (int hh = 0; hh < 4; hh++) {
                floatx2 a2 = (floatx2){aa[hh], aa[hh]};
                acc[hh][0] += a2 * lo;    // v_pk_fma_f32
                acc[hh][1] += a2 * hi;
            }
        }
    }
    // sum the two edge-slots (lane and lane^32 hold the same [h][ch4] block)
#pragma unroll
    for (int hh = 0; hh < 4; hh++)
#pragma unroll
        for (int jj = 0; jj < 2; jj++) {
            acc[hh][jj][0] += __shfl_xor(acc[hh][jj][0], 32, 64);
            acc[hh][jj][1] += __shfl_xor(acc[hh][jj][1], 32, 64);
        }
    if (lane < 32) {
#pragma unroll
        for (int hh = 0; hh < 4; hh++)
            *(float4*)&red[grp][hh][ch4] =
                make_float4(acc[hh][0][0], acc[hh][0][1], acc[hh][1][0], acc[hh][1][1]);
    }
    __syncthreads();
    int t = threadIdx.x;
    int hlo = t >> 7, c = t & 127;
    float s0 = 0.f, s1 = 0.f;
#pragma unroll
    for (int g = 0; g < 4; g++) {
        s0 += red[g][hlo][c];
        s1 += red[g][2 + hlo][c];
    }
    const float inv = 1.0f / 32.0f;
    size_t gbase = (size_t)(b * 2 + side) * 512;
    poolagg[gbase + t] = f2bf(s0 * inv);
    poolagg[gbase + t + 256] = f2bf(s1 * inv);
}

// ---------------- MFMA bf16 GEMM: out[M,C] = A[M,K] @ Wt[C,K]^T (+bias)(+relu) ----------------
// PAIR: M rows are g = b*2+side; output written to pair layout [b][side*256 + c].
template <bool FOLD, bool OUT8, bool PAIR>
__global__ __launch_bounds__(256) void mgemm_kernel(const bf16* __restrict__ A,
                                                    const bf16* __restrict__ Wt,
                                                    const float* __restrict__ bias,
                                                    void* __restrict__ out,
                                                    int K, int C, int relu,
                                                    const bf16* __restrict__ Ff,
                                                    float* __restrict__ el,
                                                    float* __restrict__ er) {
    __shared__ short As[128 * 48];
    __shared__ short Bs[128 * 48];
    int t = threadIdx.x;
    int wave = t >> 6, lane = t & 63;
    int wm = (wave >> 1) * 64, wn = (wave & 1) * 64;
    int bm = blockIdx.x * 128, bn = blockIdx.y * 128;
    int m_lane = lane & 15, quad = lane >> 4;
    bool dofold = FOLD && (blockIdx.y == 0) && (wn == 0);

    floatx4 acc[4][4];
#pragma unroll
    for (int i = 0; i < 4; i++)
#pragma unroll
        for (int j = 0; j < 4; j++) acc[i][j] = (floatx4){0.f, 0.f, 0.f, 0.f};
    floatx4 facc[4];
    if (FOLD) {
#pragma unroll
        for (int i = 0; i < 4; i++) facc[i] = (floatx4){0.f, 0.f, 0.f, 0.f};
    }

    int lrow = t >> 2, lq = t & 3;
    for (int k0 = 0; k0 < K; k0 += 32) {
        __syncthreads();
#pragma unroll
        for (int pass = 0; pass < 2; pass++) {
            int row = lrow + pass * 64;
            *(short8*)&As[row * 48 + lq * 8] =
                *(const short8*)(A + (size_t)(bm + row) * K + k0 + lq * 8);
            *(short8*)&Bs[row * 48 + lq * 8] =
                *(const short8*)(Wt + (size_t)(bn + row) * K + k0 + lq * 8);
        }
        __syncthreads();
        short8 af[4], bf[4];
#pragma unroll
        for (int i = 0; i < 4; i++)
            af[i] = *(const short8*)&As[(wm + i * 16 + m_lane) * 48 + quad * 8];
#pragma unroll
        for (int j = 0; j < 4; j++)
            bf[j] = *(const short8*)&Bs[(wn + j * 16 + m_lane) * 48 + quad * 8];
        if (dofold) {
            short8 fbv = *(const short8*)(Ff + m_lane * K + k0 + quad * 8);
#pragma unroll
            for (int i = 0; i < 4; i++)
                facc[i] = __builtin_amdgcn_mfma_f32_16x16x32_bf16(af[i], fbv, facc[i], 0, 0, 0);
        }
#pragma unroll
        for (int i = 0; i < 4; i++)
#pragma unroll
            for (int j = 0; j < 4; j++)
                acc[i][j] = __builtin_amdgcn_mfma_f32_16x16x32_bf16(af[i], bf[j], acc[i][j], 0, 0, 0);
    }

#pragma unroll
    for (int i = 0; i < 4; i++) {
#pragma unroll
        for (int j = 0; j < 4; j++) {
            int gc = bn + wn + j * 16 + m_lane;
            float bbv = bias ? bias[gc] : 0.f;
#pragma unroll
            for (int r = 0; r < 4; r++) {
                int gr = bm + wm + i * 16 + quad * 4 + r;
                float v = acc[i][j][r] + bbv;
                if (relu) v = fmaxf(v, 0.f);
                if (OUT8)      ((unsigned char*)out)[(size_t)gr * C + gc] = ftofp8(v);
                else if (PAIR) ((bf16*)out)[(size_t)(gr >> 1) * 512 + (gr & 1) * 256 + gc] = f2bf(v);
                else           ((bf16*)out)[(size_t)gr * C + gc] = f2bf(v);
            }
        }
    }
    if (dofold && m_lane < 8) {
        float* dst = (m_lane < 4) ? el : er;
        int hh = m_lane & 3;
#pragma unroll
        for (int i = 0; i < 4; i++)
#pragma unroll
            for (int r = 0; r < 4; r++) {
                int gr = bm + wm + i * 16 + quad * 4 + r;
                dst[gr * 4 + hh] = facc[i][r];
            }
    }
}

// ---------------- fp32 512x512x512 GEMM (weight combine, prep-time) ----------------
__global__ __launch_bounds__(256) void fgemm512_kernel(const float* __restrict__ A,
                                                       const float* __restrict__ B,
                                                       float* __restrict__ C) {
    const int BK = 16;
    __shared__ float As[BK][68];
    __shared__ float Bs[BK][68];
    int t = threadIdx.x;
    int bm = blockIdx.x * 64, bn = blockIdx.y * 64;
    int tm0 = (t & 15) * 4, tn0 = (t >> 4) * 4;
    float acc[4][4] = {};
    int la_m = t >> 2, la_k = (t & 3) * 4;
    int lb_k = t >> 4, lb_c = (t & 15) * 4;

    for (int k0 = 0; k0 < 512; k0 += BK) {
        float4 a4 = *(const float4*)(A + (size_t)(bm + la_m) * 512 + k0 + la_k);
        float4 b4 = *(const float4*)(B + (size_t)(k0 + lb_k) * 512 + bn + lb_c);
        As[la_k + 0][la_m] = a4.x; As[la_k + 1][la_m] = a4.y;
        As[la_k + 2][la_m] = a4.z; As[la_k + 3][la_m] = a4.w;
        *(float4*)&Bs[lb_k][lb_c] = b4;
        __syncthreads();
#pragma unroll
        for (int k = 0; k < BK; k++) {
            float4 av = *(const float4*)&As[k][tm0];
            float4 bv = *(const float4*)&Bs[k][tn0];
            acc[0][0] += av.x * bv.x; acc[0][1] += av.x * bv.y; acc[0][2] += av.x * bv.z; acc[0][3] += av.x * bv.w;
            acc[1][0] += av.y * bv.x; acc[1][1] += av.y * bv.y; acc[1][2] += av.y * bv.z; acc[1][3] += av.y * bv.w;
            acc[2][0] += av.z * bv.x; acc[2][1] += av.z * bv.y; acc[2][2] += av.z * bv.z; acc[2][3] += av.z * bv.w;
            acc[3][0] += av.w * bv.x; acc[3][1] += av.w * bv.y; acc[3][2] += av.w * bv.z; acc[3][3] += av.w * bv.w;
        }
        __syncthreads();
    }
#pragma unroll
    for (int i = 0; i < 4; i++) {
        float4 o = make_float4(acc[i][0], acc[i][1], acc[i][2], acc[i][3]);
        *(float4*)(C + (size_t)(bm + tm0 + i) * 512 + bn + tn0) = o;
    }
}

__global__ void biasstep_kernel(const float* __restrict__ vin, const float* __restrict__ M,
                                const float* __restrict__ badd, float* __restrict__ vout) {
    int c = blockIdx.x * blockDim.x + threadIdx.x;
    float s = 0.f;
    for (int k = 0; k < 512; k++) s += vin[k] * M[(size_t)k * 512 + c];
    vout[c] = s + badd[c];
}

// ---------------- fusion tail ----------------

__global__ void ln_kernel(const bf16* __restrict__ attn, const bf16* __restrict__ lp,
                          const float* __restrict__ gamma, const float* __restrict__ beta,
                          bf16* __restrict__ out) {
    __shared__ float red[256];
    int b = blockIdx.x, t = threadIdx.x;
    size_t base = (size_t)b * 512;
    float x0 = bf2f(attn[base + t]) + bf2f(lp[base + t]);
    float x1 = bf2f(attn[base + 256 + t]) + bf2f(lp[base + 256 + t]);
    red[t] = x0 + x1; __syncthreads();
    for (int off = 128; off > 0; off >>= 1) { if (t < off) red[t] += red[t + off]; __syncthreads(); }
    float mu = red[0] * (1.0f / 512.0f);
    __syncthreads();
    float d0 = x0 - mu, d1 = x1 - mu;
    red[t] = d0 * d0 + d1 * d1; __syncthreads();
    for (int off = 128; off > 0; off >>= 1) { if (t < off) red[t] += red[t + off]; __syncthreads(); }
    float rstd = rsqrtf(red[0] * (1.0f / 512.0f) + LN_EPS);
    out[base + t]       = f2bf(d0 * rstd * gamma[t] + beta[t]);
    out[base + 256 + t] = f2bf(d1 * rstd * gamma[256 + t] + beta[256 + t]);
}

__global__ void cls2_kernel(const bf16* __restrict__ hc, const float* __restrict__ Wc2,
                            const float* __restrict__ bc2, float* __restrict__ out) {
    int wid = (blockIdx.x * blockDim.x + threadIdx.x) >> 6;
    int lane = threadIdx.x & 63;
    if (wid >= NB) return;
    float s = 0.f;
#pragma unroll
    for (int j = 0; j < 4; j++) {
        int k = lane + 64 * j;
        s += bf2f(hc[(size_t)wid * 256 + k]) * Wc2[k];
    }
    for (int off = 32; off > 0; off >>= 1) s += __shfl_down(s, off);
    if (lane == 0) {
        float v = s + bc2[0];
        out[wid] = 1.0f / (1.0f + __expf(-v));
    }
}

// ---------------- launch ----------------

static inline size_t alup(size_t x) { return (x + 255) & ~(size_t)255; }

extern "C" void kernel_launch(void* const* d_in, const int* in_sizes, int n_in,
                              void* d_out, int out_size, void* d_ws, size_t ws_size,
                              hipStream_t stream) {
    const float* feat0 = (const float*)d_in[0];
    const float* feat1 = (const float*)d_in[1];
    const float* llm = (const float*)d_in[2];
    const int* srcs[2] = {(const int*)d_in[3], (const int*)d_in[5]};
    const int* dsts[2] = {(const int*)d_in[4], (const int*)d_in[6]};
    const float* W1 = (const float*)d_in[8];
    const float* al[3] = {(const float*)d_in[9],  (const float*)d_in[13], (const float*)d_in[17]};
    const float* ar[3] = {(const float*)d_in[10], (const float*)d_in[14], (const float*)d_in[18]};
    const float* bb[3] = {(const float*)d_in[11], (const float*)d_in[15], (const float*)d_in[19]};
    const float* W2 = (const float*)d_in[12];
    const float* W3 = (const float*)d_in[16];
    const float* Wpg = (const float*)d_in[20]; const float* bpg = (const float*)d_in[21];
    const float* Wpl = (const float*)d_in[22]; const float* bpl = (const float*)d_in[23];
    const float* Wv  = (const float*)d_in[24]; const float* bv  = (const float*)d_in[25];
    const float* Wo  = (const float*)d_in[26]; const float* bo  = (const float*)d_in[27];
    const float* gamma = (const float*)d_in[28]; const float* beta = (const float*)d_in[29];
    const float* Wc1 = (const float*)d_in[30]; const float* bc1 = (const float*)d_in[31];
    const float* Wc2 = (const float*)d_in[32]; const float* bc2 = (const float*)d_in[33];
    float* outp = (float*)d_out;

    const size_t N2 = (size_t)2 * NN;

    // workspace carve (~138 MiB)
    char* p = (char*)d_ws;
    auto take = [&](size_t bytes) { char* r = p; p += alup(bytes); return r; };
    bf16*  xb     = (bf16*)take(N2 * 128 * 2);        // A: 64 MiB (layer-1 bf16 / x2 fp8)
    char*  regB   = (char*)take(N2 * 256);            // B: 64 MiB (cells+counts / fpk / hb2 / poolagg / tail)
    float* el     = (float*)take(N2 * 4 * 4);         // 4 MiB
    float* er     = (float*)take(N2 * 4 * 4);         // 4 MiB
    int*   deg    = (int*)take(N2 * 4);               // 1 MiB
    int*   slots  = (int*)take(N2 * CAP * 4);         // 16.8 MiB
    bf16*  pair   = (bf16*)take((size_t)NB * 512 * 2);
    bf16*  llm_bf = (bf16*)take((size_t)NB * 1024 * 2); // 8 MiB
    bf16*  W2t  = (bf16*)take(128 * 128 * 2);
    bf16*  Wplt = (bf16*)take(1024 * 512 * 2);
    bf16*  Wc1t = (bf16*)take(512 * 256 * 2);
    bf16*  Wcot = (bf16*)take(512 * 512 * 2);
    bf16*  W3bdt = (bf16*)take(256 * 512 * 2);        // block-diag W3^T [C=256][K=512]
    float* F1   = (float*)take(6 * 8 * 4);
    bf16*  Ff2  = (bf16*)take(16 * 128 * 2);
    bf16*  Ff3  = (bf16*)take(16 * 128 * 2);
    bf16*  W1fg = (bf16*)take(128 * 32 * 2);          // 8 KiB layer-1 MFMA weight
    float* c1   = (float*)take(512 * 512 * 4);
    float* c2   = (float*)take(512 * 512 * 4);
    float* bias1 = (float*)take(512 * 4);
    float* bco   = (float*)take(512 * 4);
    // region A alias: x2 fp8 (written by agg2 over dead layer-1 activations)
    unsigned char* x8 = (unsigned char*)xb;
    // region B aliases (sequential lifetimes):
    unsigned* cells = (unsigned*)regB;                // [NBKT][NBLK1][CELL_CAP] 25 MiB (pre-fpk)
    int* counts = (int*)(regB + (size_t)NBKT * NBLK1 * CELL_CAP * 4);  // 1 MiB
    float* fpk          = (float*)regB;               // packed feats [2NN][8] (8.4 MiB, pre-L2)
    unsigned char* hb2  = (unsigned char*)regB;       // layer-2 features fp8 [2NN,128] (32 MiB)
    bf16* poolagg = (bf16*)(regB + 32 * 1024 * 1024); // [8192][512] bf16 (8 MiB, after hb2 dead)
    bf16* fbb   = (bf16*)regB;                        // fusion-tail activations
    bf16* lp    = fbb + (size_t)0 * NB * 512;
    bf16* attn  = fbb + (size_t)1 * NB * 512;
    bf16* fused = fbb + (size_t)2 * NB * 512;
    bf16* hc    = fbb + (size_t)3 * NB * 512;
    (void)ws_size; (void)n_in; (void)in_sizes; (void)out_size;

    auto mgemm = [&](const bf16* A, const bf16* Wt, const float* bias, bf16* o,
                     int M, int K, int C, int relu) {
        dim3 g(M / 128, C / 128);
        mgemm_kernel<false, false, false><<<g, 256, 0, stream>>>(A, Wt, bias, o, K, C, relu,
                                                                 nullptr, nullptr, nullptr);
    };

    // ---- slot bucketing first (cells alias region B, consumed before fpk) ----
    part_edges_kernel<<<NBLK1, 256, 0, stream>>>(srcs[0], dsts[0], srcs[1], dsts[1],
                                                 cells, counts);
    build_slots_kernel<<<NBKT, 256, 0, stream>>>(cells, counts, deg, slots);

    // ---- per-call preps ----
    prep_all_kernel<<<(PREP_TOTAL + 255) / 256, 256, 0, stream>>>(
        W2, W3, Wpl, Wc1, W1, al[0], ar[0], al[1], ar[1], al[2], ar[2], bb[0],
        W2t, Wplt, Wc1t, Ff2, Ff3, F1, W1fg, W3bdt);
    f2bf_kernel<<<NB * 1024 / 4 / 256, 256, 0, stream>>>(llm, llm_bf);
    {
        dim3 g8(8, 8);
        fgemm512_kernel<<<g8, 256, 0, stream>>>(Wpg, Wv, c1);
        fgemm512_kernel<<<g8, 256, 0, stream>>>(c1, Wo, c2);
        wt_kernel<<<(512 * 512 + 255) / 256, 256, 0, stream>>>(c2, Wcot, 512, 512);
        biasstep_kernel<<<2, 256, 0, stream>>>(bpg, Wv, bv, bias1);
        biasstep_kernel<<<2, 256, 0, stream>>>(bias1, Wo, bo, bco);
    }

    // ---- GNN, both sides merged ----
    featelr_kernel<<<2 * NN / 256, 256, 0, stream>>>(feat0, feat1, F1, fpk, el, er);
    agg1mfma_kernel<<<2 * NN / 256, 256, 0, stream>>>(fpk, el, er, deg, slots, W1fg, xb);
    {
        dim3 g(2 * NN / 128, 1);
        mgemm_kernel<true, true, false><<<g, 256, 0, stream>>>(xb, W2t, nullptr, hb2,
                                                               128, 128, 0, Ff2, el, er);
    }
    agg2_kernel<<<2 * NN * 32 / 256, 256, 0, stream>>>(hb2, el, er, deg, slots, bb[1], x8);
    elr3_kernel<<<2 * NN / 64, 256, 0, stream>>>(x8, Ff3, el, er);
    agg3pool_kernel<<<2 * NB, 256, 0, stream>>>(x8, el, er, deg, slots, poolagg);
    {
        // pair = poolagg @ W3bd + bias3 (per-graph W3, PAIR output mapping)
        dim3 g(8192 / 128, 256 / 128);
        mgemm_kernel<false, false, true><<<g, 256, 0, stream>>>(poolagg, W3bdt, bb[2], pair,
                                                                512, 256, 0,
                                                                nullptr, nullptr, nullptr);
    }

    // ---- fusion tail (activations alias region B) ----
    mgemm(llm_bf, Wplt, bpl, lp, NB, 1024, 512, 0);
    mgemm(pair, Wcot, bco, attn, NB, 512, 512, 0);
    ln_kernel<<<NB, 256, 0, stream>>>(attn, lp, gamma, beta, fused);
    mgemm(fused, Wc1t, bc1, hc, NB, 512, 256, 1);
    cls2_kernel<<<NB / 4, 256, 0, stream>>>(hc, Wc2, bc2, outp);
}

// Round 9
// 548.615 us; speedup vs baseline: 1.0832x; 1.0128x over previous
//
#include <hip/hip_runtime.h>
#include <hip/hip_fp8.h>

#define NN 131072      // nodes per side
#define NE 524288      // edges per side
#define NB 4096        // graphs per side
#define CAP 16         // slot capacity = one 64B line/node
#define NEG_SLOPE 0.2f
#define LN_EPS 1e-5f
#define LOG2E 1.44269504088896f

// edge-partition geometry (atomic-free slot build)
#define NBKT 1024      // buckets of 256 nodes (2NN/256)
#define NBLK1 1024     // phase-1 blocks (R7: 4x occupancy, 1 wave/SIMD -> 4)
#define CELL_CAP 12    // per-(bucket,block) cell capacity (avg 1, Poisson tail ~1e-12)

typedef unsigned short bf16;
typedef __attribute__((ext_vector_type(8))) short short8;
typedef __attribute__((ext_vector_type(4))) float floatx4;
typedef __attribute__((ext_vector_type(2))) float floatx2;

#if __has_builtin(__builtin_amdgcn_exp2f)
#define EXP2(x) __builtin_amdgcn_exp2f(x)
#else
#define EXP2(x) exp2f(x)
#endif

__device__ __forceinline__ float bf2f(bf16 h) {
    return __uint_as_float((unsigned)h << 16);
}
__device__ __forceinline__ bf16 f2bf(float f) {
    unsigned u = __float_as_uint(f);
    unsigned r = (u + 0x7FFFu + ((u >> 16) & 1u)) >> 16;
    return (bf16)r;
}
// unpack a packed bf16 pair (lo, hi) from one u32
__device__ __forceinline__ floatx2 upk2(unsigned u) {
    floatx2 r;
    r[0] = __uint_as_float(u << 16);
    r[1] = __uint_as_float(u & 0xFFFF0000u);
    return r;
}
// HW packed bf16 pair encode (RNE, same unit the compiler uses for bf16 casts)
__device__ __forceinline__ unsigned pkbf(float lo, float hi) {
    unsigned r;
    asm("v_cvt_pk_bf16_f32 %0, %1, %2" : "=v"(r) : "v"(lo), "v"(hi));
    return r;
}
// HW packed fp8(e4m3) encode
__device__ __forceinline__ unsigned char ftofp8(float f) {
    return (unsigned char)(__builtin_amdgcn_cvt_pk_fp8_f32(f, f, 0, false) & 0xFF);
}
__device__ __forceinline__ float leaky(float x) {
    return fmaxf(x, 0.f) + NEG_SLOPE * fminf(x, 0.f);
}

// ---------------- atomic-free slot build (two-phase partition) ----------------
// Phase 1: bin edges into block-private cells via LDS histogram (no global atomics;
//          cell lines are block-private -> no cross-XCD ping-pong).
__global__ __launch_bounds__(256) void part_edges_kernel(
        const int* __restrict__ s0, const int* __restrict__ d0,
        const int* __restrict__ s1, const int* __restrict__ d1,
        unsigned* __restrict__ cells, int* __restrict__ counts) {
    __shared__ int lcnt[NBKT];       // 4 KB
    int blk = blockIdx.x, t = threadIdx.x;
    for (int i = t; i < NBKT; i += 256) lcnt[i] = 0;
    __syncthreads();
    int side = blk >= (NBLK1 / 2);               // 512 blocks per side
    const int4* dp = (const int4*)(side ? d1 : d0);
    const int4* sp = (const int4*)(side ? s1 : s0);
    int e4 = (blk - side * (NBLK1 / 2)) * 256 + t;   // [0, NE/4)
    int gbase = side * NN;
    int4 dd = dp[e4];
    int4 ss = sp[e4];
    int d[4] = {gbase + dd.x, gbase + dd.y, gbase + dd.z, gbase + dd.w};
    int s[4] = {gbase + ss.x, gbase + ss.y, gbase + ss.z, gbase + ss.w};
#pragma unroll
    for (int k = 0; k < 4; k++) {
        int b = d[k] >> 8;
        int r = atomicAdd(&lcnt[b], 1);          // LDS atomic
        if (r < CELL_CAP)
            cells[((size_t)b * NBLK1 + blk) * CELL_CAP + r] =
                ((unsigned)s[k] << 8) | (unsigned)(d[k] & 255);
    }
    __syncthreads();
    for (int i = t; i < NBKT; i += 256) {
        int c = lcnt[i];
        counts[i * NBLK1 + blk] = (c > CELL_CAP) ? CELL_CAP : c;
    }
}

// Phase 2: one block per bucket; build deg/slots for 256 nodes in LDS, write coalesced.
__global__ __launch_bounds__(256) void build_slots_kernel(
        const unsigned* __restrict__ cells, const int* __restrict__ counts,
        int* __restrict__ deg, int* __restrict__ slots) {
    __shared__ int ldeg[256];                    // 1 KB
    __shared__ int lslot[256 * CAP];             // 16 KB
    int b = blockIdx.x, t = threadIdx.x;
    ldeg[t] = 0;
    for (int i = t; i < 256 * CAP; i += 256) lslot[i] = 0;
    __syncthreads();
    // thread t consumes cells t, t+256, ... of this bucket
    for (int cc = t; cc < NBLK1; cc += 256) {
        int cnt = counts[b * NBLK1 + cc];
        const unsigned* cp = cells + ((size_t)b * NBLK1 + cc) * CELL_CAP;
        for (int i = 0; i < cnt; i++) {
            unsigned v = cp[i];
            int d = v & 255;
            int s = (int)(v >> 8);
            int p = atomicAdd(&ldeg[d], 1);      // LDS atomic
            if (p < CAP) lslot[d * CAP + p] = s;
        }
    }
    __syncthreads();
    int node0 = b * 256;
    deg[node0 + t] = ldeg[t];
    for (int i = t; i < 256 * CAP; i += 256)
        slots[(size_t)node0 * CAP + i] = lslot[i];
}

// ---------------- merged weight prep ----------------
// W2t + Wplt + Wc1t + Ff2 + Ff3 + F1 + W1f + W3bdt
#define PREP_TOTAL (16384 + 524288 + 131072 + 2048 + 2048 + 48 + 4096 + 131072)

__global__ void prep_all_kernel(const float* __restrict__ W2, const float* __restrict__ W3,
                                const float* __restrict__ Wpl, const float* __restrict__ Wc1,
                                const float* __restrict__ W1,
                                const float* __restrict__ al1, const float* __restrict__ ar1,
                                const float* __restrict__ al2, const float* __restrict__ ar2,
                                const float* __restrict__ al3, const float* __restrict__ ar3,
                                const float* __restrict__ b1v,
                                bf16* __restrict__ W2t, bf16* __restrict__ Wplt,
                                bf16* __restrict__ Wc1t,
                                bf16* __restrict__ Ff2, bf16* __restrict__ Ff3,
                                float* __restrict__ F1, bf16* __restrict__ W1f,
                                bf16* __restrict__ W3bdt) {
    int i = blockIdx.x * blockDim.x + threadIdx.x;
    if (i < 16384) {  // W2t: K=128,C=128
        int c = i >> 7, k = i & 127;
        W2t[i] = f2bf(W2[k * 128 + c]);
        return;
    }
    i -= 16384;
    if (i < 524288) {  // Wplt: K=1024,C=512
        int c = i >> 10, k = i & 1023;
        Wplt[i] = f2bf(Wpl[k * 512 + c]);
        return;
    }
    i -= 524288;
    if (i < 131072) {  // Wc1t: K=512,C=256
        int c = i >> 9, k = i & 511;
        Wc1t[i] = f2bf(Wc1[k * 256 + c]);
        return;
    }
    i -= 131072;
    if (i < 2048) {  // Ff2: Kin=128, Dh=32
        int c = i >> 7, k = i & 127;
        float s = 0.f;
        if (c < 8) {
            const float* a = (c < 4) ? al2 : ar2;
            int hh = c & 3;
            for (int d = 0; d < 32; d++) s += W2[k * 128 + hh * 32 + d] * a[hh * 32 + d];
        }
        Ff2[i] = f2bf(s);
        return;
    }
    i -= 2048;
    if (i < 2048) {  // Ff3: Kin=128, Dh=64 (layer-3 attn fold applied to x2)
        int c = i >> 7, k = i & 127;
        float s = 0.f;
        if (c < 8) {
            const float* a = (c < 4) ? al3 : ar3;
            int hh = c & 3;
            for (int d = 0; d < 64; d++) s += W3[k * 256 + hh * 64 + d] * a[hh * 64 + d];
        }
        Ff3[i] = f2bf(s);
        return;
    }
    i -= 2048;
    if (i < 48) {  // F1: layer-1 fold (fp32, K=6), pre-scaled by log2(e) so agg1 uses exp2
        int k = i >> 3, c = i & 7;
        const float* a = (c < 4) ? al1 : ar1;
        int hh = c & 3;
        float s = 0.f;
        for (int d = 0; d < 32; d++) s += W1[k * 128 + hh * 32 + d] * a[hh * 32 + d];
        F1[k * 8 + c] = s * LOG2E;
        return;
    }
    i -= 48;
    if (i < 4096) {  // W1f: [C=128][K=32], k = h*8+d; slot d==6 carries bias (pairs with 1.0)
        int c = i >> 5, k = i & 31;
        int h = c >> 5, d = k & 7;
        float v = 0.f;
        if ((k >> 3) == h) {
            if (d < 6) v = W1[d * 128 + c];
            else if (d == 6) v = b1v[c];
        }
        W1f[i] = f2bf(v);
        return;
    }
    i -= 4096;
    if (i < 131072) {  // W3bdt: block-diag W3^T [C=256][K=512]; r = h*128+k active iff h==c>>6
        int c = i >> 9, r = i & 511;
        int hr = r >> 7, k = r & 127;
        float v = (hr == (c >> 6)) ? W3[k * 256 + c] : 0.f;
        W3bdt[i] = f2bf(v);
    }
}

__global__ void f2bf_kernel(const float* __restrict__ x, bf16* __restrict__ y) {
    int i = blockIdx.x * blockDim.x + threadIdx.x;
    float4 v = ((const float4*)x)[i];
    ushort4 u;
    u.x = f2bf(v.x); u.y = f2bf(v.y); u.z = f2bf(v.z); u.w = f2bf(v.w);
    ((ushort4*)y)[i] = u;
}

__global__ void wt_kernel(const float* __restrict__ W, bf16* __restrict__ Wt, int K, int C) {
    int i = blockIdx.x * blockDim.x + threadIdx.x;
    if (i >= K * C) return;
    int c = i / K, k = i - c * K;
    Wt[i] = f2bf(W[(size_t)k * C + c]);
}

// ---------------- layer-1 front end ----------------

// Fused: pack raw feats into bf16 [2NN][8] rows + compute el/er (log2e-scaled F1),
// stored as bf16x4 (R7: halves the layer-1 gather bytes, 48->24 B/edge).
__global__ void featelr_kernel(const float* __restrict__ f0, const float* __restrict__ f1,
                               const float* __restrict__ F1, bf16* __restrict__ fpk,
                               bf16* __restrict__ el1, bf16* __restrict__ er1) {
    int n = blockIdx.x * blockDim.x + threadIdx.x;  // [0, 2*NN)
    const float* x = (n < NN) ? (f0 + (size_t)n * 6) : (f1 + (size_t)(n - NN) * 6);
    float xv[6];
#pragma unroll
    for (int k = 0; k < 6; k++) xv[k] = x[k];
    uint4 o;
    o.x = pkbf(xv[0], xv[1]);
    o.y = pkbf(xv[2], xv[3]);
    o.z = pkbf(xv[4], xv[5]);
    o.w = 0u;
    *(uint4*)(fpk + (size_t)n * 8) = o;
    float ep[4], rp[4];
#pragma unroll
    for (int c = 0; c < 4; c++) {
        float sl = 0.f, sr = 0.f;
#pragma unroll
        for (int k = 0; k < 6; k++) {
            sl += xv[k] * F1[k * 8 + c];
            sr += xv[k] * F1[k * 8 + c + 4];
        }
        ep[c] = sl;
        rp[c] = sr;
    }
    uint2 eo, ro;
    eo.x = pkbf(ep[0], ep[1]); eo.y = pkbf(ep[2], ep[3]);
    ro.x = pkbf(rp[0], rp[1]); ro.y = pkbf(rp[2], rp[3]);
    *(uint2*)(el1 + (size_t)n * 4) = eo;
    *(uint2*)(er1 + (size_t)n * 4) = ro;
}

// Fused layer-1: one lane per node gathers + softmax-aggregates the 6-dim feats
// (bf16 el uint2 + bf16 packed-feat uint4, exp2 weights), then per-wave MFMA does the
// 32->128 W1 transform (bias folded via the 1.0 slot in sagg / b1 row in W1f).
__global__ __launch_bounds__(256) void agg1mfma_kernel(
        const bf16* __restrict__ fpk, const bf16* __restrict__ el1,
        const bf16* __restrict__ er1, const int* __restrict__ deg,
        const int* __restrict__ slots, const bf16* __restrict__ W1fg,
        bf16* __restrict__ xb) {
    __shared__ bf16 sW[128 * 40];     // [128 ch][32 k] padded to 40 (bank-conflict break)
    __shared__ bf16 sagg[256 * 40];   // [256 node][32 k] padded to 40
    int t = threadIdx.x;
    // stage W1f into padded LDS (one row = 64B = 4x uint4)
    if (t < 128) {
        const uint4* src = (const uint4*)(W1fg + t * 32);
        uint4* dstp = (uint4*)(sW + t * 40);
        dstp[0] = src[0]; dstp[1] = src[1]; dstp[2] = src[2]; dstp[3] = src[3];
    }

    // ---- phase 1: per-lane gather softmax-aggregate ----
    int node = blockIdx.x * 256 + t;
    int dg = deg[node];
    dg = (dg > CAP) ? CAP : dg;
    uint2 eru = *(const uint2*)(er1 + (size_t)node * 4);
    floatx2 r01 = upk2(eru.x), r23 = upk2(eru.y);
    float rh[4] = {r01[0], r01[1], r23[0], r23[1]};
    const int* sp = slots + (size_t)node * CAP;
    float a0[4], a1[4], a2[4], a3[4], a4[4], a5[4], ss[4];
#pragma unroll
    for (int h = 0; h < 4; h++) {
        a0[h] = a1[h] = a2[h] = a3[h] = a4[h] = a5[h] = ss[h] = 0.f;
    }
    for (int p = 0; p < dg; p += 4) {
        int4 s4 = *(const int4*)(sp + p);
        int sarr[4] = {s4.x, s4.y, s4.z, s4.w};
#pragma unroll
        for (int k = 0; k < 4; k++) {
            bool vld = (p + k) < dg;
            int g = vld ? sarr[k] : s4.x;       // clamp: unread slots may be garbage
            uint2 eu = *(const uint2*)(el1 + (size_t)g * 4);
            uint4 xu = *(const uint4*)(fpk + (size_t)g * 8);
            floatx2 e01 = upk2(eu.x), e23 = upk2(eu.y);
            floatx2 x01 = upk2(xu.x), x23 = upk2(xu.y), x45 = upk2(xu.z);
            float eh[4] = {e01[0], e01[1], e23[0], e23[1]};
#pragma unroll
            for (int h = 0; h < 4; h++) {
                float z = eh[h] + rh[h];
                float w = EXP2(fmaxf(z, 0.f) + NEG_SLOPE * fminf(z, 0.f));
                w = vld ? w : 0.f;
                ss[h] += w;
                a0[h] += w * x01[0]; a1[h] += w * x01[1]; a2[h] += w * x23[0];
                a3[h] += w * x23[1]; a4[h] += w * x45[0]; a5[h] += w * x45[1];
            }
        }
    }
#pragma unroll
    for (int h = 0; h < 4; h++) {
        float rs = (dg > 0) ? 1.f / ss[h] : 0.f;
        uint4 o;
        o.x = pkbf(a0[h] * rs, a1[h] * rs);
        o.y = pkbf(a2[h] * rs, a3[h] * rs);
        o.z = pkbf(a4[h] * rs, a5[h] * rs);
        o.w = 0x00003F80u;  // (1.0bf16, 0.0): bias slot k=h*8+6
        *(uint4*)(sagg + t * 40 + h * 8) = o;
    }
    __syncthreads();

    // ---- phase 2: per-wave MFMA, 64 nodes x 128 channels ----
    int wave = t >> 6, lane = t & 63;
    int mlane = lane & 15, quad = lane >> 4;
    short8 af[8];
#pragma unroll
    for (int j = 0; j < 8; j++)
        af[j] = *(const short8*)(sW + (j * 16 + mlane) * 40 + quad * 8);
    floatx4 z4 = (floatx4){0.f, 0.f, 0.f, 0.f};
#pragma unroll
    for (int nt = 0; nt < 4; nt++) {
        int lrow = wave * 64 + nt * 16 + mlane;
        short8 bfr = *(const short8*)(sagg + lrow * 40 + quad * 8);
        floatx4 c[8];
#pragma unroll
        for (int j = 0; j < 8; j++)
            c[j] = __builtin_amdgcn_mfma_f32_16x16x32_bf16(af[j], bfr, z4, 0, 0, 0);
        // D: col = mlane -> node, row = quad*4+r -> channel j*16+quad*4+r
        bf16* op = xb + (size_t)(blockIdx.x * 256 + lrow) * 128 + quad * 4;
#pragma unroll
        for (int j = 0; j < 8; j++) {
            uint2 o;
            o.x = pkbf(fmaxf(c[j][0], 0.f), fmaxf(c[j][1], 0.f));
            o.y = pkbf(fmaxf(c[j][2], 0.f), fmaxf(c[j][3], 0.f));
            *(uint2*)(op + j * 16) = o;
        }
    }
}

// ---------------- GAT kernels (merged over 2*NN) ----------------

// Phase-A helper (agg3pool only): lane = h*16+e computes alpha[e][h] + clamped src.
__device__ __forceinline__ void softmax_phaseA(const float* __restrict__ el,
                                               const float* __restrict__ er,
                                               const int* __restrict__ slots,
                                               int wid, int dg, int lane,
                                               float* alpha_out, int* src_out) {
    int e = lane & 15, h = lane >> 4;
    int sA = slots[(size_t)wid * CAP + e];
    int sAc = (e < dg) ? sA : 0;                 // clamp: poisoned slots are unsafe addrs
    float erh = er[wid * 4 + h];
    float elv = el[sAc * 4 + h];
    float w = (e < dg) ? __expf(leaky(elv + erh)) : 0.f;
    float ssum = w;
    ssum += __shfl_xor(ssum, 1, 64);
    ssum += __shfl_xor(ssum, 2, 64);
    ssum += __shfl_xor(ssum, 4, 64);
    ssum += __shfl_xor(ssum, 8, 64);
    *alpha_out = (dg > 0) ? w * (1.f / ssum) : 0.f;   // 0 for e>=dg (w=0)
    *src_out = sAc;
}

// layer-2 agg (R13 structure): 32 lanes/node, inline per-lane-head softmax,
// 4-edge batch (4 loads in flight), 4B fp8 loads, HW cvt. R5: fp8 output (x2).
__global__ void agg2_kernel(const unsigned char* __restrict__ h8, const float* __restrict__ el,
                            const float* __restrict__ er, const int* __restrict__ deg,
                            const int* __restrict__ slots, const float* __restrict__ bias,
                            unsigned char* __restrict__ out) {
    int t = blockIdx.x * blockDim.x + threadIdx.x;
    int wid = t >> 5;                // [0, 2*NN)
    int gl = threadIdx.x & 31;
    int dg = deg[wid];
    dg = (dg > CAP) ? CAP : dg;
    int head = gl >> 3;
    int fbase = gl * 4;
    float erh = er[wid * 4 + head];
    const int* sp = slots + (size_t)wid * CAP;
    float a0 = 0.f, a1 = 0.f, a2 = 0.f, a3 = 0.f, ssum = 0.f;

    for (int p = 0; p < dg; p += 4) {
        int4 s4 = *(const int4*)(sp + p);
        int s[4]; bool v[4];
        s[0] = s4.x; v[0] = true;
        v[1] = p + 1 < dg; s[1] = v[1] ? s4.y : s4.x;
        v[2] = p + 2 < dg; s[2] = v[2] ? s4.z : s4.x;
        v[3] = p + 3 < dg; s[3] = v[3] ? s4.w : s4.x;
        float elv[4]; unsigned u1[4];
#pragma unroll
        for (int k = 0; k < 4; k++) {
            elv[k] = el[s[k] * 4 + head];
            u1[k] = *(const unsigned*)(h8 + (size_t)s[k] * 128 + fbase);
        }
#pragma unroll
        for (int k = 0; k < 4; k++) {
            float w = v[k] ? __expf(leaky(elv[k] + erh)) : 0.f;
            ssum += w;
            floatx2 lo = __builtin_amdgcn_cvt_pk_f32_fp8((int)u1[k], false);
            floatx2 hi = __builtin_amdgcn_cvt_pk_f32_fp8((int)u1[k], true);
            a0 += w * lo[0]; a1 += w * lo[1];
            a2 += w * hi[0]; a3 += w * hi[1];
        }
    }
    float rs = (dg > 0) ? 1.f / ssum : 0.f;
    float4 bbv = *(const float4*)(bias + fbase);
    float v0 = fmaxf(a0 * rs + bbv.x, 0.f), v1 = fmaxf(a1 * rs + bbv.y, 0.f);
    float v2 = fmaxf(a2 * rs + bbv.z, 0.f), v3 = fmaxf(a3 * rs + bbv.w, 0.f);
    unsigned w8 = (unsigned)__builtin_amdgcn_cvt_pk_fp8_f32(v0, v1, 0, false);
    w8 = (unsigned)__builtin_amdgcn_cvt_pk_fp8_f32(v2, v3, (int)w8, true);
    *(unsigned*)(out + (size_t)wid * 128 + fbase) = w8;
}

// layer-3 el/er from fp8 x2 via MFMA: el/er[n,h] = sum_k x2[n,k] * Ff3[c,k]
// (c<4 -> el head c, c in 4..8 -> er head c-4). 16 nodes per wave-mfma.
__global__ __launch_bounds__(256) void elr3_kernel(const unsigned char* __restrict__ x8,
                                                   const bf16* __restrict__ Ff3,
                                                   float* __restrict__ el,
                                                   float* __restrict__ er) {
    int wave = threadIdx.x >> 6, lane = threadIdx.x & 63;
    int mlane = lane & 15, quad = lane >> 4;
    int node0 = blockIdx.x * 64 + wave * 16;
    floatx4 acc = (floatx4){0.f, 0.f, 0.f, 0.f};
#pragma unroll
    for (int kb = 0; kb < 4; kb++) {
        short8 bfr = *(const short8*)(Ff3 + mlane * 128 + kb * 32 + quad * 8);
        uint2 u8 = *(const uint2*)(x8 + (size_t)(node0 + mlane) * 128 + kb * 32 + quad * 8);
        floatx2 f01 = __builtin_amdgcn_cvt_pk_f32_fp8((int)u8.x, false);
        floatx2 f23 = __builtin_amdgcn_cvt_pk_f32_fp8((int)u8.x, true);
        floatx2 f45 = __builtin_amdgcn_cvt_pk_f32_fp8((int)u8.y, false);
        floatx2 f67 = __builtin_amdgcn_cvt_pk_f32_fp8((int)u8.y, true);
        short8 af;
        unsigned* ap = (unsigned*)&af;
        ap[0] = pkbf(f01[0], f01[1]); ap[1] = pkbf(f23[0], f23[1]);
        ap[2] = pkbf(f45[0], f45[1]); ap[3] = pkbf(f67[0], f67[1]);
        acc = __builtin_amdgcn_mfma_f32_16x16x32_bf16(af, bfr, acc, 0, 0, 0);
    }
    // D: col = mlane -> c (0..3 el, 4..7 er), row = quad*4+r -> node
    if (mlane < 8) {
        float* dst = (mlane < 4) ? el : er;
        int h = mlane & 3;
#pragma unroll
        for (int r = 0; r < 4; r++) {
            int node = node0 + quad * 4 + r;
            dst[node * 4 + h] = acc[r];
        }
    }
}

// layer-3 agg + mean-pool IN x2-SPACE. R6: phaseA for all 8 nodes upfront
// (8 independent latency chains), compacted per-group edge worklist, 8-edge
// gather iterations (4 loads in flight/lane), packed-f32 accumulation.
__global__ void agg3pool_kernel(const unsigned char* __restrict__ x8,
                                const float* __restrict__ el, const float* __restrict__ er,
                                const int* __restrict__ deg, const int* __restrict__ slots,
                                bf16* __restrict__ poolagg) {
    __shared__ float red[4][4][128];      // 8 KB   [grp][h][ch]
    __shared__ float salpha[4][136][4];   // 8.5 KB [grp][edge][h], compacted
    __shared__ int   ssrc[4][136];        // 2.2 KB
    int side = blockIdx.x >> 12;          // 8192 blocks: side*4096 + b
    int b = blockIdx.x & 4095;
    int nodebase = side * NN + b * 32;
    int grp = threadIdx.x >> 6, lane = threadIdx.x & 63;
    int e = lane & 15, h = lane >> 4;     // phaseA roles
    int esl = lane >> 5;                  // edge slot (0/1) for gather
    int ch4 = (lane & 31) * 4;            // channel block for gather

    // ---- phase A: softmax for all 8 nodes, build compact worklist ----
    int off = 0;
    for (int nn = 0; nn < 8; nn++) {
        int wid = nodebase + grp * 8 + nn;
        int dg = deg[wid];
        dg = (dg > CAP) ? CAP : dg;
        float alpha; int sAc;
        softmax_phaseA(el, er, slots, wid, dg, lane, &alpha, &sAc);
        if (e < dg) {
            salpha[grp][off + e][h] = alpha;
            if (h == 0) ssrc[grp][off + e] = sAc;
        }
        off += dg;
    }
    int padded = (off + 7) & ~7;
    if (lane < padded - off) {            // zero-pad tail edges (alpha=0, src=0)
        int j = off + lane;
        *(float4*)&salpha[grp][j][0] = make_float4(0.f, 0.f, 0.f, 0.f);
        ssrc[grp][j] = 0;
    }
    // same-wave LDS RAW: DS pipe is wave-ordered, no barrier needed

    // ---- gather: 8 edges/iter, half-wave per edge, packed-f32 accum ----
    floatx2 acc[4][2];                    // [h][lo/hi pair of 4 channels]
#pragma unroll
    for (int hh = 0; hh < 4; hh++) {
        acc[hh][0] = (floatx2){0.f, 0.f};
        acc[hh][1] = (floatx2){0.f, 0.f};
    }
    for (int j = 0; j < padded; j += 8) {
        int sc[4]; float4 av[4]; unsigned u[4];
#pragma unroll
        for (int k = 0; k < 4; k++) {
            int je = j + 2 * k + esl;
            sc[k] = ssrc[grp][je];
            av[k] = *(const float4*)&salpha[grp][je][0];
        }
#pragma unroll
        for (int k = 0; k < 4; k++)
            u[k] = *(const unsigned*)(x8 + (size_t)sc[k] * 128 + ch4);
#pragma unroll
        for (int k = 0; k < 4; k++) {
            floatx2 lo = __builtin_amdgcn_cvt_pk_f32_fp8((int)u[k], false);
            floatx2 hi = __builtin_amdgcn_cvt_pk_f32_fp8((int)u[k], true);
            float aa[4] = {av[k].x, av[k].y, av[k].z, av[k].w};
#pragma unroll
            for (int hh = 0; hh < 4; hh++) {
                floatx2 a2 = (floatx2){aa[hh], aa[hh]};
                acc[hh][0] += a2 * lo;    // v_pk_fma_f32
                acc[hh][1] += a2 * hi;
            }
        }
    }
    // sum the two edge-slots (lane and lane^32 hold the same [h][ch4] block)
#pragma unroll
    for (int hh = 0; hh < 4; hh++)
#pragma unroll
        for (int jj = 0; jj < 2; jj++) {
            acc[hh][jj][0] += __shfl_xor(acc[hh][jj][0], 32, 64);
            acc[hh][jj][1] += __shfl_xor(acc[hh][jj][1], 32, 64);
        }
    if (lane < 32) {
#pragma unroll
        for (int hh = 0; hh < 4; hh++)
            *(float4*)&red[grp][hh][ch4] =
                make_float4(acc[hh][0][0], acc[hh][0][1], acc[hh][1][0], acc[hh][1][1]);
    }
    __syncthreads();
    int t = threadIdx.x;
    int hlo = t >> 7, c = t & 127;
    float s0 = 0.f, s1 = 0.f;
#pragma unroll
    for (int g = 0; g < 4; g++) {
        s0 += red[g][hlo][c];
        s1 += red[g][2 + hlo][c];
    }
    const float inv = 1.0f / 32.0f;
    size_t gbase = (size_t)(b * 2 + side) * 512;
    poolagg[gbase + t] = f2bf(s0 * inv);
    poolagg[gbase + t + 256] = f2bf(s1 * inv);
}

// ---------------- MFMA bf16 GEMM: out[M,C] = A[M,K] @ Wt[C,K]^T (+bias)(+relu) ----------------
// PAIR: M rows are g = b*2+side; output written to pair layout [b][side*256 + c].
template <bool FOLD, bool OUT8, bool PAIR>
__global__ __launch_bounds__(256) void mgemm_kernel(const bf16* __restrict__ A,
                                                    const bf16* __restrict__ Wt,
                                                    const float* __restrict__ bias,
                                                    void* __restrict__ out,
                                                    int K, int C, int relu,
                                                    const bf16* __restrict__ Ff,
                                                    float* __restrict__ el,
                                                    float* __restrict__ er) {
    __shared__ short As[128 * 48];
    __shared__ short Bs[128 * 48];
    int t = threadIdx.x;
    int wave = t >> 6, lane = t & 63;
    int wm = (wave >> 1) * 64, wn = (wave & 1) * 64;
    int bm = blockIdx.x * 128, bn = blockIdx.y * 128;
    int m_lane = lane & 15, quad = lane >> 4;
    bool dofold = FOLD && (blockIdx.y == 0) && (wn == 0);

    floatx4 acc[4][4];
#pragma unroll
    for (int i = 0; i < 4; i++)
#pragma unroll
        for (int j = 0; j < 4; j++) acc[i][j] = (floatx4){0.f, 0.f, 0.f, 0.f};
    floatx4 facc[4];
    if (FOLD) {
#pragma unroll
        for (int i = 0; i < 4; i++) facc[i] = (floatx4){0.f, 0.f, 0.f, 0.f};
    }

    int lrow = t >> 2, lq = t & 3;
    for (int k0 = 0; k0 < K; k0 += 32) {
        __syncthreads();
#pragma unroll
        for (int pass = 0; pass < 2; pass++) {
            int row = lrow + pass * 64;
            *(short8*)&As[row * 48 + lq * 8] =
                *(const short8*)(A + (size_t)(bm + row) * K + k0 + lq * 8);
            *(short8*)&Bs[row * 48 + lq * 8] =
                *(const short8*)(Wt + (size_t)(bn + row) * K + k0 + lq * 8);
        }
        __syncthreads();
        short8 af[4], bf[4];
#pragma unroll
        for (int i = 0; i < 4; i++)
            af[i] = *(const short8*)&As[(wm + i * 16 + m_lane) * 48 + quad * 8];
#pragma unroll
        for (int j = 0; j < 4; j++)
            bf[j] = *(const short8*)&Bs[(wn + j * 16 + m_lane) * 48 + quad * 8];
        if (dofold) {
            short8 fbv = *(const short8*)(Ff + m_lane * K + k0 + quad * 8);
#pragma unroll
            for (int i = 0; i < 4; i++)
                facc[i] = __builtin_amdgcn_mfma_f32_16x16x32_bf16(af[i], fbv, facc[i], 0, 0, 0);
        }
#pragma unroll
        for (int i = 0; i < 4; i++)
#pragma unroll
            for (int j = 0; j < 4; j++)
                acc[i][j] = __builtin_amdgcn_mfma_f32_16x16x32_bf16(af[i], bf[j], acc[i][j], 0, 0, 0);
    }

#pragma unroll
    for (int i = 0; i < 4; i++) {
#pragma unroll
        for (int j = 0; j < 4; j++) {
            int gc = bn + wn + j * 16 + m_lane;
            float bbv = bias ? bias[gc] : 0.f;
#pragma unroll
            for (int r = 0; r < 4; r++) {
                int gr = bm + wm + i * 16 + quad * 4 + r;
                float v = acc[i][j][r] + bbv;
                if (relu) v = fmaxf(v, 0.f);
                if (OUT8)      ((unsigned char*)out)[(size_t)gr * C + gc] = ftofp8(v);
                else if (PAIR) ((bf16*)out)[(size_t)(gr >> 1) * 512 + (gr & 1) * 256 + gc] = f2bf(v);
                else           ((bf16*)out)[(size_t)gr * C + gc] = f2bf(v);
            }
        }
    }
    if (dofold && m_lane < 8) {
        float* dst = (m_lane < 4) ? el : er;
        int hh = m_lane & 3;
#pragma unroll
        for (int i = 0; i < 4; i++)
#pragma unroll
            for (int r = 0; r < 4; r++) {
                int gr = bm + wm + i * 16 + quad * 4 + r;
                dst[gr * 4 + hh] = facc[i][r];
            }
    }
}

// ---------------- fp32 512x512x512 GEMM (weight combine, prep-time) ----------------
__global__ __launch_bounds__(256) void fgemm512_kernel(const float* __restrict__ A,
                                                       const float* __restrict__ B,
                                                       float* __restrict__ C) {
    const int BK = 16;
    __shared__ float As[BK][68];
    __shared__ float Bs[BK][68];
    int t = threadIdx.x;
    int bm = blockIdx.x * 64, bn = blockIdx.y * 64;
    int tm0 = (t & 15) * 4, tn0 = (t >> 4) * 4;
    float acc[4][4] = {};
    int la_m = t >> 2, la_k = (t & 3) * 4;
    int lb_k = t >> 4, lb_c = (t & 15) * 4;

    for (int k0 = 0; k0 < 512; k0 += BK) {
        float4 a4 = *(const float4*)(A + (size_t)(bm + la_m) * 512 + k0 + la_k);
        float4 b4 = *(const float4*)(B + (size_t)(k0 + lb_k) * 512 + bn + lb_c);
        As[la_k + 0][la_m] = a4.x; As[la_k + 1][la_m] = a4.y;
        As[la_k + 2][la_m] = a4.z; As[la_k + 3][la_m] = a4.w;
        *(float4*)&Bs[lb_k][lb_c] = b4;
        __syncthreads();
#pragma unroll
        for (int k = 0; k < BK; k++) {
            float4 av = *(const float4*)&As[k][tm0];
            float4 bv = *(const float4*)&Bs[k][tn0];
            acc[0][0] += av.x * bv.x; acc[0][1] += av.x * bv.y; acc[0][2] += av.x * bv.z; acc[0][3] += av.x * bv.w;
            acc[1][0] += av.y * bv.x; acc[1][1] += av.y * bv.y; acc[1][2] += av.y * bv.z; acc[1][3] += av.y * bv.w;
            acc[2][0] += av.z * bv.x; acc[2][1] += av.z * bv.y; acc[2][2] += av.z * bv.z; acc[2][3] += av.z * bv.w;
            acc[3][0] += av.w * bv.x; acc[3][1] += av.w * bv.y; acc[3][2] += av.w * bv.z; acc[3][3] += av.w * bv.w;
        }
        __syncthreads();
    }
#pragma unroll
    for (int i = 0; i < 4; i++) {
        float4 o = make_float4(acc[i][0], acc[i][1], acc[i][2], acc[i][3]);
        *(float4*)(C + (size_t)(bm + tm0 + i) * 512 + bn + tn0) = o;
    }
}

__global__ void biasstep_kernel(const float* __restrict__ vin, const float* __restrict__ M,
                                const float* __restrict__ badd, float* __restrict__ vout) {
    int c = blockIdx.x * blockDim.x + threadIdx.x;
    float s = 0.f;
    for (int k = 0; k < 512; k++) s += vin[k] * M[(size_t)k * 512 + c];
    vout[c] = s + badd[c];
}

// ---------------- fusion tail ----------------

__global__ void ln_kernel(const bf16* __restrict__ attn, const bf16* __restrict__ lp,
                          const float* __restrict__ gamma, const float* __restrict__ beta,
                          bf16* __restrict__ out) {
    __shared__ float red[256];
    int b = blockIdx.x, t = threadIdx.x;
    size_t base = (size_t)b * 512;
    float x0 = bf2f(attn[base + t]) + bf2f(lp[base + t]);
    float x1 = bf2f(attn[base + 256 + t]) + bf2f(lp[base + 256 + t]);
    red[t] = x0 + x1; __syncthreads();
    for (int off = 128; off > 0; off >>= 1) { if (t < off) red[t] += red[t + off]; __syncthreads(); }
    float mu = red[0] * (1.0f / 512.0f);
    __syncthreads();
    float d0 = x0 - mu, d1 = x1 - mu;
    red[t] = d0 * d0 + d1 * d1; __syncthreads();
    for (int off = 128; off > 0; off >>= 1) { if (t < off) red[t] += red[t + off]; __syncthreads(); }
    float rstd = rsqrtf(red[0] * (1.0f / 512.0f) + LN_EPS);
    out[base + t]       = f2bf(d0 * rstd * gamma[t] + beta[t]);
    out[base + 256 + t] = f2bf(d1 * rstd * gamma[256 + t] + beta[256 + t]);
}

__global__ void cls2_kernel(const bf16* __restrict__ hc, const float* __restrict__ Wc2,
                            const float* __restrict__ bc2, float* __restrict__ out) {
    int wid = (blockIdx.x * blockDim.x + threadIdx.x) >> 6;
    int lane = threadIdx.x & 63;
    if (wid >= NB) return;
    float s = 0.f;
#pragma unroll
    for (int j = 0; j < 4; j++) {
        int k = lane + 64 * j;
        s += bf2f(hc[(size_t)wid * 256 + k]) * Wc2[k];
    }
    for (int off = 32; off > 0; off >>= 1) s += __shfl_down(s, off);
    if (lane == 0) {
        float v = s + bc2[0];
        out[wid] = 1.0f / (1.0f + __expf(-v));
    }
}

// ---------------- launch ----------------

static inline size_t alup(size_t x) { return (x + 255) & ~(size_t)255; }

extern "C" void kernel_launch(void* const* d_in, const int* in_sizes, int n_in,
                              void* d_out, int out_size, void* d_ws, size_t ws_size,
                              hipStream_t stream) {
    const float* feat0 = (const float*)d_in[0];
    const float* feat1 = (const float*)d_in[1];
    const float* llm = (const float*)d_in[2];
    const int* srcs[2] = {(const int*)d_in[3], (const int*)d_in[5]};
    const int* dsts[2] = {(const int*)d_in[4], (const int*)d_in[6]};
    const float* W1 = (const float*)d_in[8];
    const float* al[3] = {(const float*)d_in[9],  (const float*)d_in[13], (const float*)d_in[17]};
    const float* ar[3] = {(const float*)d_in[10], (const float*)d_in[14], (const float*)d_in[18]};
    const float* bb[3] = {(const float*)d_in[11], (const float*)d_in[15], (const float*)d_in[19]};
    const float* W2 = (const float*)d_in[12];
    const float* W3 = (const float*)d_in[16];
    const float* Wpg = (const float*)d_in[20]; const float* bpg = (const float*)d_in[21];
    const float* Wpl = (const float*)d_in[22]; const float* bpl = (const float*)d_in[23];
    const float* Wv  = (const float*)d_in[24]; const float* bv  = (const float*)d_in[25];
    const float* Wo  = (const float*)d_in[26]; const float* bo  = (const float*)d_in[27];
    const float* gamma = (const float*)d_in[28]; const float* beta = (const float*)d_in[29];
    const float* Wc1 = (const float*)d_in[30]; const float* bc1 = (const float*)d_in[31];
    const float* Wc2 = (const float*)d_in[32]; const float* bc2 = (const float*)d_in[33];
    float* outp = (float*)d_out;

    const size_t N2 = (size_t)2 * NN;

    // workspace carve (~171 MiB)
    char* p = (char*)d_ws;
    auto take = [&](size_t bytes) { char* r = p; p += alup(bytes); return r; };
    bf16*  xb     = (bf16*)take(N2 * 128 * 2);        // A: 64 MiB (layer-1 bf16 / x2 fp8)
    char*  regB   = (char*)take(N2 * 256);            // B: 64 MiB (cells+counts / fpk / hb2 / poolagg / tail)
    float* el     = (float*)take(N2 * 4 * 4);         // 4 MiB
    float* er     = (float*)take(N2 * 4 * 4);         // 4 MiB
    int*   deg    = (int*)take(N2 * 4);               // 1 MiB
    int*   slots  = (int*)take(N2 * CAP * 4);         // 16.8 MiB
    bf16*  pair   = (bf16*)take((size_t)NB * 512 * 2);
    bf16*  llm_bf = (bf16*)take((size_t)NB * 1024 * 2); // 8 MiB
    bf16*  W2t  = (bf16*)take(128 * 128 * 2);
    bf16*  Wplt = (bf16*)take(1024 * 512 * 2);
    bf16*  Wc1t = (bf16*)take(512 * 256 * 2);
    bf16*  Wcot = (bf16*)take(512 * 512 * 2);
    bf16*  W3bdt = (bf16*)take(256 * 512 * 2);        // block-diag W3^T [C=256][K=512]
    float* F1   = (float*)take(6 * 8 * 4);
    bf16*  Ff2  = (bf16*)take(16 * 128 * 2);
    bf16*  Ff3  = (bf16*)take(16 * 128 * 2);
    bf16*  W1fg = (bf16*)take(128 * 32 * 2);          // 8 KiB layer-1 MFMA weight
    float* c1   = (float*)take(512 * 512 * 4);
    float* c2   = (float*)take(512 * 512 * 4);
    float* bias1 = (float*)take(512 * 4);
    float* bco   = (float*)take(512 * 4);
    // region A alias: x2 fp8 (written by agg2 over dead layer-1 activations)
    unsigned char* x8 = (unsigned char*)xb;
    // layer-1 bf16 el/er views (alias el/er f32 buffers; consumed by agg1 before
    // mgemm2's fold overwrites the same memory with layer-2 f32 el/er)
    bf16* el1 = (bf16*)el;
    bf16* er1 = (bf16*)er;
    // region B aliases (sequential lifetimes):
    unsigned* cells = (unsigned*)regB;                // [NBKT][NBLK1][CELL_CAP] 48 MiB (pre-fpk)
    int* counts = (int*)(regB + (size_t)NBKT * NBLK1 * CELL_CAP * 4);  // 4 MiB
    bf16* fpk           = (bf16*)regB;                // packed feats bf16 [2NN][8] (4 MiB, pre-L2)
    unsigned char* hb2  = (unsigned char*)regB;       // layer-2 features fp8 [2NN,128] (32 MiB)
    bf16* poolagg = (bf16*)(regB + 32 * 1024 * 1024); // [8192][512] bf16 (8 MiB, after hb2 dead)
    bf16* fbb   = (bf16*)regB;                        // fusion-tail activations
    bf16* lp    = fbb + (size_t)0 * NB * 512;
    bf16* attn  = fbb + (size_t)1 * NB * 512;
    bf16* fused = fbb + (size_t)2 * NB * 512;
    bf16* hc    = fbb + (size_t)3 * NB * 512;
    (void)ws_size; (void)n_in; (void)in_sizes; (void)out_size;

    auto mgemm = [&](const bf16* A, const bf16* Wt, const float* bias, bf16* o,
                     int M, int K, int C, int relu) {
        dim3 g(M / 128, C / 128);
        mgemm_kernel<false, false, false><<<g, 256, 0, stream>>>(A, Wt, bias, o, K, C, relu,
                                                                 nullptr, nullptr, nullptr);
    };

    // ---- slot bucketing first (cells alias region B, consumed before fpk) ----
    part_edges_kernel<<<NBLK1, 256, 0, stream>>>(srcs[0], dsts[0], srcs[1], dsts[1],
                                                 cells, counts);
    build_slots_kernel<<<NBKT, 256, 0, stream>>>(cells, counts, deg, slots);

    // ---- per-call preps ----
    prep_all_kernel<<<(PREP_TOTAL + 255) / 256, 256, 0, stream>>>(
        W2, W3, Wpl, Wc1, W1, al[0], ar[0], al[1], ar[1], al[2], ar[2], bb[0],
        W2t, Wplt, Wc1t, Ff2, Ff3, F1, W1fg, W3bdt);
    f2bf_kernel<<<NB * 1024 / 4 / 256, 256, 0, stream>>>(llm, llm_bf);
    {
        dim3 g8(8, 8);
        fgemm512_kernel<<<g8, 256, 0, stream>>>(Wpg, Wv, c1);
        fgemm512_kernel<<<g8, 256, 0, stream>>>(c1, Wo, c2);
        wt_kernel<<<(512 * 512 + 255) / 256, 256, 0, stream>>>(c2, Wcot, 512, 512);
        biasstep_kernel<<<2, 256, 0, stream>>>(bpg, Wv, bv, bias1);
        biasstep_kernel<<<2, 256, 0, stream>>>(bias1, Wo, bo, bco);
    }

    // ---- GNN, both sides merged ----
    featelr_kernel<<<2 * NN / 256, 256, 0, stream>>>(feat0, feat1, F1, fpk, el1, er1);
    agg1mfma_kernel<<<2 * NN / 256, 256, 0, stream>>>(fpk, el1, er1, deg, slots, W1fg, xb);
    {
        dim3 g(2 * NN / 128, 1);
        mgemm_kernel<true, true, false><<<g, 256, 0, stream>>>(xb, W2t, nullptr, hb2,
                                                               128, 128, 0, Ff2, el, er);
    }
    agg2_kernel<<<2 * NN * 32 / 256, 256, 0, stream>>>(hb2, el, er, deg, slots, bb[1], x8);
    elr3_kernel<<<2 * NN / 64, 256, 0, stream>>>(x8, Ff3, el, er);
    agg3pool_kernel<<<2 * NB, 256, 0, stream>>>(x8, el, er, deg, slots, poolagg);
    {
        // pair = poolagg @ W3bd + bias3 (per-graph W3, PAIR output mapping)
        dim3 g(8192 / 128, 256 / 128);
        mgemm_kernel<false, false, true><<<g, 256, 0, stream>>>(poolagg, W3bdt, bb[2], pair,
                                                                512, 256, 0,
                                                                nullptr, nullptr, nullptr);
    }

    // ---- fusion tail (activations alias region B) ----
    mgemm(llm_bf, Wplt, bpl, lp, NB, 1024, 512, 0);
    mgemm(pair, Wcot, bco, attn, NB, 512, 512, 0);
    ln_kernel<<<NB, 256, 0, stream>>>(attn, lp, gamma, beta, fused);
    mgemm(fused, Wc1t, bc1, hc, NB, 512, 256, 1);
    cls2_kernel<<<NB / 4, 256, 0, stream>>>(hc, Wc2, bc2, outp);
}